// Round 9
// baseline (408.114 us; speedup 1.0000x reference)
//
#include <hip/hip_runtime.h>

typedef __attribute__((ext_vector_type(8))) short bfx8;
typedef __attribute__((ext_vector_type(4))) float fx4;

static __device__ __forceinline__ unsigned short f2bf(float f) {
    union { float f; unsigned int u; } v; v.f = f;
    unsigned int i = v.u;
    return (unsigned short)((i + 0x7FFFu + ((i >> 16) & 1u)) >> 16);
}
static __device__ __forceinline__ float bf2f(unsigned short u) {
    union { unsigned int ui; float f; } cv;
    cv.ui = ((unsigned int)u) << 16;
    return cv.f;
}

// async global->LDS, 16B per lane; l is the WAVE-UNIFORM base (HW adds lane*16)
static __device__ __forceinline__ void gl2lds16(const unsigned short* g, unsigned short* l) {
    unsigned long long gu = (unsigned long long)g;
    unsigned int lu = (unsigned int)(unsigned long long)l;
    __builtin_amdgcn_global_load_lds(
        (const __attribute__((address_space(1))) void*)gu,
        (__attribute__((address_space(3))) void*)lu,
        16, 0, 0);
}

// ---------------- single-launch weight prep: 72 slices of [512K x 512N] f32 -> bf16 [N,K] ----------------
struct TrGroup {
    const float* src;
    unsigned short* dst;
    int srcRowStride;
    int dstRowStride;
    long srcSliceOff;
    long dstSliceOff;
};
struct TrTable {
    TrGroup g[18];
    int zStart[19];
};

__global__ __launch_bounds__(256) void trall_kernel(TrTable tt)
{
    __shared__ unsigned short tile[32][33];
    int z = blockIdx.z;
    int gi = 0;
#pragma unroll 1
    while (z >= tt.zStart[gi + 1]) ++gi;
    int zi = z - tt.zStart[gi];
    const float* s = tt.g[gi].src + (size_t)zi * tt.g[gi].srcSliceOff;
    unsigned short* d = tt.g[gi].dst + (size_t)zi * tt.g[gi].dstSliceOff;
    int srs = tt.g[gi].srcRowStride, drs = tt.g[gi].dstRowStride;
    int n0 = blockIdx.x * 32, k0 = blockIdx.y * 32;
    int tx = threadIdx.x & 31, ty = threadIdx.x >> 5;
#pragma unroll
    for (int i = 0; i < 32; i += 8)
        tile[ty + i][tx] = f2bf(s[(size_t)(k0 + ty + i) * srs + (n0 + tx)]);
    __syncthreads();
#pragma unroll
    for (int i = 0; i < 32; i += 8)
        d[(size_t)(n0 + ty + i) * drs + (k0 + tx)] = tile[tx][ty + i];
}

// ---------------- fused embeddings + PE + first LN (src & tgt in one launch) ----------------
__global__ __launch_bounds__(256) void embedln_kernel(
    const int* __restrict__ tokA, const int* __restrict__ tokB,
    const float* __restrict__ embA, const float* __restrict__ embB,
    float* __restrict__ outA, float* __restrict__ outB,
    const float* __restrict__ gA, const float* __restrict__ bA,
    const float* __restrict__ gB, const float* __restrict__ bB,
    unsigned short* __restrict__ nxA, unsigned short* __restrict__ nxB)
{
    __shared__ float red[4];
    int idx = blockIdx.x;
    int row = idx & 2047;
    bool e = idx < 2048;
    const int* tok = e ? tokA : tokB;
    const float* emb = e ? embA : embB;
    float* out = e ? outA : outB;
    const float* g = e ? gA : gB;
    const float* bb = e ? bA : bB;
    unsigned short* nx = e ? nxA : nxB;
    int pos = row & 127;
    int t = tok[row];
    int d0 = threadIdx.x, d1 = threadIdx.x + 256;
    auto pe = [&](int d) {
        float ang = (float)pos * expf((float)(d & ~1) * (-9.210340371976184f / 512.0f));
        return (d & 1) ? cosf(ang) : sinf(ang);
    };
    float v0 = emb[(size_t)t * 512 + d0] * 22.627416997969522f + pe(d0);
    float v1 = emb[(size_t)t * 512 + d1] * 22.627416997969522f + pe(d1);
    out[(size_t)row * 512 + d0] = v0;
    out[(size_t)row * 512 + d1] = v1;
    int lane = threadIdx.x & 63, wv = threadIdx.x >> 6;
    float s = v0 + v1;
#pragma unroll
    for (int off = 32; off; off >>= 1) s += __shfl_xor(s, off);
    if (lane == 0) red[wv] = s;
    __syncthreads();
    float mu = (red[0] + red[1] + red[2] + red[3]) * (1.0f / 512.0f);
    __syncthreads();
    float q = (v0 - mu) * (v0 - mu) + (v1 - mu) * (v1 - mu);
#pragma unroll
    for (int off = 32; off; off >>= 1) q += __shfl_xor(q, off);
    if (lane == 0) red[wv] = q;
    __syncthreads();
    float rs = rsqrtf((red[0] + red[1] + red[2] + red[3]) * (1.0f / 512.0f) + 1e-5f);
    nx[(size_t)row * 512 + d0] = f2bf(g[d0] * (v0 - mu) * rs + bb[d0]);
    nx[(size_t)row * 512 + d1] = f2bf(g[d1] * (v1 - mu) * rs + bb[d1]);
}

// ---------------- layernorm row body (D=512, one wave) ----------------
static __device__ __forceinline__ void ln_row(
    const float* __restrict__ xrow, const float* __restrict__ g,
    const float* __restrict__ b, int lane, fx4& o0, fx4& o1)
{
    const fx4* xr = (const fx4*)xrow;
    fx4 a = xr[lane * 2], c = xr[lane * 2 + 1];
    float s = a[0] + a[1] + a[2] + a[3] + c[0] + c[1] + c[2] + c[3];
#pragma unroll
    for (int off = 32; off; off >>= 1) s += __shfl_xor(s, off);
    float mu = s * (1.0f / 512.0f);
    float qv = 0.f;
#pragma unroll
    for (int j = 0; j < 4; ++j) {
        float d0 = a[j] - mu; qv += d0 * d0;
        float d1 = c[j] - mu; qv += d1 * d1;
    }
#pragma unroll
    for (int off = 32; off; off >>= 1) qv += __shfl_xor(qv, off);
    float rs = rsqrtf(qv * (1.0f / 512.0f) + 1e-5f);
    const fx4* gr = (const fx4*)g;
    const fx4* br = (const fx4*)b;
    fx4 g0 = gr[lane * 2], g1 = gr[lane * 2 + 1];
    fx4 b0 = br[lane * 2], b1 = br[lane * 2 + 1];
#pragma unroll
    for (int j = 0; j < 4; ++j) {
        o0[j] = g0[j] * (a[j] - mu) * rs + b0[j];
        o1[j] = g1[j] * (c[j] - mu) * rs + b1[j];
    }
}

template<bool OUTBF>
__global__ __launch_bounds__(256) void ln_kernel(
    const float* __restrict__ x, const float* __restrict__ g,
    const float* __restrict__ b, void* __restrict__ out)
{
    int row = blockIdx.x * 4 + (threadIdx.x >> 6);
    int lane = threadIdx.x & 63;
    fx4 o0, o1;
    ln_row(x + (size_t)row * 512, g, b, lane, o0, o1);
    if (OUTBF) {
        unsigned short* orow = (unsigned short*)out + (size_t)row * 512 + lane * 8;
        ushort4 u0 = {f2bf(o0[0]), f2bf(o0[1]), f2bf(o0[2]), f2bf(o0[3])};
        ushort4 u1 = {f2bf(o1[0]), f2bf(o1[1]), f2bf(o1[2]), f2bf(o1[3])};
        *(ushort4*)orow = u0;
        *(ushort4*)(orow + 4) = u1;
    } else {
        fx4* orow = (fx4*)out + (size_t)row * 128;
        orow[lane * 2] = o0;
        orow[lane * 2 + 1] = o1;
    }
}

// fused: xe = LN(xe, enc_norm); nk0 = LN(xe', dec l0); nk1 = LN(xe', dec l1)
__global__ __launch_bounds__(256) void ln3_kernel(
    float* __restrict__ xe, const float* __restrict__ eg, const float* __restrict__ eb,
    const float* __restrict__ g0, const float* __restrict__ b0,
    const float* __restrict__ g1, const float* __restrict__ b1,
    unsigned short* __restrict__ nk0, unsigned short* __restrict__ nk1)
{
    int row = blockIdx.x * 4 + (threadIdx.x >> 6);
    int lane = threadIdx.x & 63;
    fx4 t0, t1;
    ln_row(xe + (size_t)row * 512, eg, eb, lane, t0, t1);
    fx4* orow = (fx4*)(xe + (size_t)row * 512);
    orow[lane * 2] = t0;
    orow[lane * 2 + 1] = t1;
    float s = t0[0] + t0[1] + t0[2] + t0[3] + t1[0] + t1[1] + t1[2] + t1[3];
#pragma unroll
    for (int off = 32; off; off >>= 1) s += __shfl_xor(s, off);
    float mu = s * (1.0f / 512.0f);
    float q = 0.f;
#pragma unroll
    for (int j = 0; j < 4; ++j) {
        float a = t0[j] - mu; q += a * a;
        float c = t1[j] - mu; q += c * c;
    }
#pragma unroll
    for (int off = 32; off; off >>= 1) q += __shfl_xor(q, off);
    float rs = rsqrtf(q * (1.0f / 512.0f) + 1e-5f);
    const fx4* g0r = (const fx4*)g0; const fx4* b0r = (const fx4*)b0;
    const fx4* g1r = (const fx4*)g1; const fx4* b1r = (const fx4*)b1;
    fx4 ga0 = g0r[lane * 2], ga1 = g0r[lane * 2 + 1];
    fx4 bb0 = b0r[lane * 2], bb1 = b0r[lane * 2 + 1];
    fx4 gc0 = g1r[lane * 2], gc1 = g1r[lane * 2 + 1];
    fx4 bc0 = b1r[lane * 2], bc1 = b1r[lane * 2 + 1];
    unsigned short* o0 = nk0 + (size_t)row * 512 + lane * 8;
    unsigned short* o1 = nk1 + (size_t)row * 512 + lane * 8;
    ushort4 ua0, ua1, uc0, uc1;
#pragma unroll
    for (int j = 0; j < 4; ++j) {
        float n0 = (t0[j] - mu) * rs, n1 = (t1[j] - mu) * rs;
        ((unsigned short*)&ua0)[j] = f2bf(ga0[j] * n0 + bb0[j]);
        ((unsigned short*)&ua1)[j] = f2bf(ga1[j] * n1 + bb1[j]);
        ((unsigned short*)&uc0)[j] = f2bf(gc0[j] * n0 + bc0[j]);
        ((unsigned short*)&uc1)[j] = f2bf(gc1[j] * n1 + bc1[j]);
    }
    *(ushort4*)o0 = ua0; *(ushort4*)(o0 + 4) = ua1;
    *(ushort4*)o1 = uc0; *(ushort4*)(o1 + 4) = uc1;
}

// ---------------- bf16 MFMA GEMM, 64x64 tile, BK=128 ----------------
template<bool RELU, bool RESID, bool OUTBF>
__global__ __launch_bounds__(256) void gemm_bk128_kernel(
    const unsigned short* __restrict__ A, const unsigned short* __restrict__ Wt,
    const float* __restrict__ bias, const float* __restrict__ res,
    void* __restrict__ Cv, int K, int ldc, int gx)
{
    __shared__ unsigned short smem[2][2][8192];  // [buf][A/B][64*128]
    const int tid = threadIdx.x;
    const int nwg = gridDim.x;
    const int cpx = nwg >> 3;
    const int phys = blockIdx.x;
    const int logical = (phys & 7) * cpx + (phys >> 3);
    const int bm = (logical / gx) * 64;
    const int bn = (logical % gx) * 64;
    const int lane = tid & 63;
    const int wv = tid >> 6;
    const int wr = (wv >> 1) * 32;
    const int wc = (wv & 1) * 32;
    const int lr = lane & 15;
    const int lrow4 = lane >> 4;
    const int lchk16 = lane & 15;
    fx4 acc00 = {0.f, 0.f, 0.f, 0.f}, acc01 = {0.f, 0.f, 0.f, 0.f};
    fx4 acc10 = {0.f, 0.f, 0.f, 0.f}, acc11 = {0.f, 0.f, 0.f, 0.f};

    auto stage = [&](int buf, int k0) {
#pragma unroll
        for (int j = 0; j < 4; ++j) {
            int row = wv * 16 + j * 4 + lrow4;
            int sc = (lchk16 ^ (row & 15)) * 8;
            gl2lds16(A + (size_t)(bm + row) * K + k0 + sc,
                     &smem[buf][0][(wv * 16 + j * 4) * 128]);
            gl2lds16(Wt + (size_t)(bn + row) * K + k0 + sc,
                     &smem[buf][1][(wv * 16 + j * 4) * 128]);
        }
    };

    const int nt = K >> 7;
    int cur = 0;
    stage(0, 0);
    for (int t = 0; t < nt; ++t) {
        __syncthreads();
        if (t + 1 < nt) stage(cur ^ 1, (t + 1) << 7);
        const unsigned short* bufA = &smem[cur][0][0];
        const unsigned short* bufB = &smem[cur][1][0];
        const int ra0 = wr + lr, ra1 = wr + 16 + lr;
        const int rb0 = wc + lr, rb1 = wc + 16 + lr;
        __builtin_amdgcn_s_setprio(1);
#pragma unroll
        for (int kk = 0; kk < 4; ++kk) {
            int ca = kk * 4 + (lane >> 4);
            bfx8 a0 = *(const bfx8*)&bufA[ra0 * 128 + ((ca ^ (ra0 & 15)) * 8)];
            bfx8 a1 = *(const bfx8*)&bufA[ra1 * 128 + ((ca ^ (ra1 & 15)) * 8)];
            bfx8 b0 = *(const bfx8*)&bufB[rb0 * 128 + ((ca ^ (rb0 & 15)) * 8)];
            bfx8 b1 = *(const bfx8*)&bufB[rb1 * 128 + ((ca ^ (rb1 & 15)) * 8)];
            acc00 = __builtin_amdgcn_mfma_f32_16x16x32_bf16(a0, b0, acc00, 0, 0, 0);
            acc01 = __builtin_amdgcn_mfma_f32_16x16x32_bf16(a0, b1, acc01, 0, 0, 0);
            acc10 = __builtin_amdgcn_mfma_f32_16x16x32_bf16(a1, b0, acc10, 0, 0, 0);
            acc11 = __builtin_amdgcn_mfma_f32_16x16x32_bf16(a1, b1, acc11, 0, 0, 0);
        }
        __builtin_amdgcn_s_setprio(0);
        cur ^= 1;
    }
    int rbase = bm + wr + ((lane >> 4) * 4);
    int cbase = bn + wc + lr;
#pragma unroll
    for (int m = 0; m < 2; ++m) {
        fx4 am0 = m ? acc10 : acc00;
        fx4 am1 = m ? acc11 : acc01;
#pragma unroll
        for (int r = 0; r < 4; ++r) {
            int row = rbase + m * 16 + r;
#pragma unroll
            for (int half = 0; half < 2; ++half) {
                int col = cbase + half * 16;
                float v = (half ? am1[r] : am0[r]) + bias[col];
                if (RESID) v += res[(size_t)row * ldc + col];
                if (RELU) v = fmaxf(v, 0.f);
                if (OUTBF) ((unsigned short*)Cv)[(size_t)row * ldc + col] = f2bf(v);
                else       ((float*)Cv)[(size_t)row * ldc + col] = v;
            }
        }
    }
}

// ---------------- fused GEMM (64x512 full-row tile, K=512) + bias + residual + LayerNorm ----------------
// A bf16 [2048,512]; Wt bf16 [512,512]; res f32 [2048,512] (updated in place);
// lnout bf16 [2048,512] = LN(res_new) with (lgam, lbet).
__global__ __launch_bounds__(256) void gemm_ln_kernel(
    const unsigned short* __restrict__ A, const unsigned short* __restrict__ Wt,
    const float* __restrict__ bias, float* __restrict__ res,
    const float* __restrict__ lgam, const float* __restrict__ lbet,
    unsigned short* __restrict__ lnout)
{
    __shared__ unsigned short sA[2][4096];    // 64 x 64 per buf
    __shared__ unsigned short sB[2][32768];   // 512 x 64 per buf
    __shared__ float redS[64][4];
    __shared__ float redQ[64][4];
    __shared__ float murs[64][2];
    const int tid = threadIdx.x;
    const int bm = blockIdx.x * 64;
    const int lane = tid & 63;
    const int wv = tid >> 6;
    const int lr = lane & 15;
    const int g4 = (lane >> 4) * 4;
    const int lrow = lane >> 3;
    const int lchk = lane & 7;

    fx4 acc[4][8];
#pragma unroll
    for (int m = 0; m < 4; ++m)
#pragma unroll
        for (int n = 0; n < 8; ++n) acc[m][n] = fx4{0.f, 0.f, 0.f, 0.f};

    float bias_c[8], gam_c[8], bet_c[8];
#pragma unroll
    for (int n = 0; n < 8; ++n) {
        int col = wv * 128 + n * 16 + lr;
        bias_c[n] = bias[col];
        gam_c[n] = lgam[col];
        bet_c[n] = lbet[col];
    }

    auto stage = [&](int buf, int k0) {
#pragma unroll
        for (int j = 0; j < 2; ++j) {
            int row = wv * 16 + j * 8 + lrow;
            int sc = lchk ^ (row & 7);
            gl2lds16(A + (size_t)(bm + row) * 512 + k0 + sc * 8,
                     &sA[buf][(wv * 16 + j * 8) * 64]);
        }
#pragma unroll
        for (int j = 0; j < 16; ++j) {
            int row = wv * 128 + j * 8 + lrow;
            int sc = lchk ^ (row & 7);
            gl2lds16(Wt + (size_t)row * 512 + k0 + sc * 8,
                     &sB[buf][(wv * 128 + j * 8) * 64]);
        }
    };

    stage(0, 0);
#pragma unroll 1
    for (int t = 0; t < 8; ++t) {
        __syncthreads();
        if (t < 7) stage((t + 1) & 1, (t + 1) * 64);
        const unsigned short* bA = sA[t & 1];
        const unsigned short* bB = sB[t & 1];
        __builtin_amdgcn_s_setprio(1);
#pragma unroll
        for (int kk = 0; kk < 2; ++kk) {
            int ca = kk * 4 + (lane >> 4);
            bfx8 af[4], bf_[8];
#pragma unroll
            for (int m = 0; m < 4; ++m) {
                int r = m * 16 + lr;
                af[m] = *(const bfx8*)&bA[r * 64 + ((ca ^ (r & 7)) * 8)];
            }
#pragma unroll
            for (int n = 0; n < 8; ++n) {
                int r = wv * 128 + n * 16 + lr;
                bf_[n] = *(const bfx8*)&bB[r * 64 + ((ca ^ (r & 7)) * 8)];
            }
#pragma unroll
            for (int m = 0; m < 4; ++m)
#pragma unroll
                for (int n = 0; n < 8; ++n)
                    acc[m][n] = __builtin_amdgcn_mfma_f32_16x16x32_bf16(af[m], bf_[n], acc[m][n], 0, 0, 0);
        }
        __builtin_amdgcn_s_setprio(0);
    }
    // fold bias + residual into acc
#pragma unroll
    for (int m = 0; m < 4; ++m)
#pragma unroll
        for (int n = 0; n < 8; ++n) {
            int col = wv * 128 + n * 16 + lr;
#pragma unroll
            for (int r = 0; r < 4; ++r) {
                size_t grow = bm + m * 16 + g4 + r;
                acc[m][n][r] += bias_c[n] + res[grow * 512 + col];
            }
        }
    // per-row stats (rows are shared across waves: each wave holds 128 of 512 cols)
#pragma unroll
    for (int m = 0; m < 4; ++m)
#pragma unroll
        for (int r = 0; r < 4; ++r) {
            float s1 = 0.f, s2 = 0.f;
#pragma unroll
            for (int n = 0; n < 8; ++n) {
                float x = acc[m][n][r];
                s1 += x; s2 += x * x;
            }
#pragma unroll
            for (int off = 8; off; off >>= 1) {
                s1 += __shfl_xor(s1, off);
                s2 += __shfl_xor(s2, off);
            }
            if (lr == 0) {
                redS[m * 16 + g4 + r][wv] = s1;
                redQ[m * 16 + g4 + r][wv] = s2;
            }
        }
    __syncthreads();
    if (tid < 64) {
        float s1 = redS[tid][0] + redS[tid][1] + redS[tid][2] + redS[tid][3];
        float s2 = redQ[tid][0] + redQ[tid][1] + redQ[tid][2] + redQ[tid][3];
        float mu = s1 * (1.0f / 512.0f);
        float var = s2 * (1.0f / 512.0f) - mu * mu;
        murs[tid][0] = mu;
        murs[tid][1] = rsqrtf(var + 1e-5f);
    }
    __syncthreads();
#pragma unroll
    for (int m = 0; m < 4; ++m)
#pragma unroll
        for (int r = 0; r < 4; ++r) {
            int rl = m * 16 + g4 + r;
            float mu = murs[rl][0], rs = murs[rl][1];
            size_t grow = bm + rl;
#pragma unroll
            for (int n = 0; n < 8; ++n) {
                int col = wv * 128 + n * 16 + lr;
                float x = acc[m][n][r];
                res[grow * 512 + col] = x;
                lnout[grow * 512 + col] = f2bf(gam_c[n] * (x - mu) * rs + bet_c[n]);
            }
        }
}

// ---------------- bf16 MFMA GEMM, 128x128 tile (4 waves x 64x64), bf16 out ----------------
template<bool RELU>
__global__ __launch_bounds__(256) void gemm128_kernel(
    const unsigned short* __restrict__ A, const unsigned short* __restrict__ Wt,
    const float* __restrict__ bias, unsigned short* __restrict__ C,
    int K, int ldc)
{
    __shared__ unsigned short smem[2][2][8192];  // [buf][A/B][128*64]
    const int tid = threadIdx.x;
    const int nwg = gridDim.x;
    const int cpx = nwg >> 3;
    const int phys = blockIdx.x;
    const int logical = (phys & 7) * cpx + (phys >> 3);
    const int bm = (logical & 15) * 128;     // M = 2048 always
    const int bn = (logical >> 4) * 128;
    const int lane = tid & 63;
    const int wv = tid >> 6;
    const int wr = (wv >> 1) * 64;
    const int wc = (wv & 1) * 64;
    const int lr = lane & 15;
    const int lrow = lane >> 3;
    const int lchk = lane & 7;
    fx4 acc[4][4];
#pragma unroll
    for (int mi = 0; mi < 4; ++mi)
#pragma unroll
        for (int ni = 0; ni < 4; ++ni) acc[mi][ni] = fx4{0.f, 0.f, 0.f, 0.f};

    auto stage = [&](int buf, int k0) {
#pragma unroll
        for (int j = 0; j < 4; ++j) {
            int row = wv * 32 + j * 8 + lrow;
            int sc = lchk ^ (row & 7);
            gl2lds16(A + (size_t)(bm + row) * K + k0 + sc * 8,
                     &smem[buf][0][(wv * 32 + j * 8) * 64]);
            gl2lds16(Wt + (size_t)(bn + row) * K + k0 + sc * 8,
                     &smem[buf][1][(wv * 32 + j * 8) * 64]);
        }
    };

    const int nt = K >> 6;
    int cur = 0;
    stage(0, 0);
    for (int t = 0; t < nt; ++t) {
        __syncthreads();
        if (t + 1 < nt) stage(cur ^ 1, (t + 1) << 6);
        const unsigned short* bufA = &smem[cur][0][0];
        const unsigned short* bufB = &smem[cur][1][0];
        __builtin_amdgcn_s_setprio(1);
#pragma unroll
        for (int kk = 0; kk < 2; ++kk) {
            int ca = kk * 4 + (lane >> 4);
            bfx8 af[4], bg[4];
#pragma unroll
            for (int i = 0; i < 4; ++i) {
                int ra = wr + i * 16 + lr;
                int rb = wc + i * 16 + lr;
                af[i] = *(const bfx8*)&bufA[ra * 64 + ((ca ^ (ra & 7)) * 8)];
                bg[i] = *(const bfx8*)&bufB[rb * 64 + ((ca ^ (rb & 7)) * 8)];
            }
#pragma unroll
            for (int mi = 0; mi < 4; ++mi)
#pragma unroll
                for (int ni = 0; ni < 4; ++ni)
                    acc[mi][ni] = __builtin_amdgcn_mfma_f32_16x16x32_bf16(af[mi], bg[ni], acc[mi][ni], 0, 0, 0);
        }
        __builtin_amdgcn_s_setprio(0);
        cur ^= 1;
    }
    int rbase = bm + wr + ((lane >> 4) * 4);
    int cbase = bn + wc + lr;
#pragma unroll
    for (int mi = 0; mi < 4; ++mi)
#pragma unroll
        for (int ni = 0; ni < 4; ++ni) {
            int col = cbase + ni * 16;
            float bv = bias[col];
#pragma unroll
            for (int r = 0; r < 4; ++r) {
                int row = rbase + mi * 16 + r;
                float v = acc[mi][ni][r] + bv;
                if (RELU) v = fmaxf(v, 0.f);
                C[(size_t)row * ldc + col] = f2bf(v);
            }
        }
}

// ---------------- fused QKV-projection + attention (8 waves) ----------------
template<bool CAUSAL, bool SELF>
__global__ __launch_bounds__(512) void fattn_kernel(
    const unsigned short* __restrict__ xq, const unsigned short* __restrict__ xkv,
    const unsigned short* __restrict__ Wt, const float* __restrict__ bias,
    unsigned short* __restrict__ out)
{
    constexpr int XROWS = SELF ? 128 : 192;
    constexpr int BUFB  = (XROWS + 192) * 64 * 2;
    __shared__ __align__(16) unsigned char lds[2 * BUFB + 9216 + 18432 + 17408 + 512];
    const int blk = blockIdx.x;
    const int half = blk & 1;
    const int h = (blk >> 1) & 7;
    const int b = blk >> 4;
    const int q0 = half * 64;
    const int tid = threadIdx.x;
    const int lane = tid & 63;
    const int wv = tid >> 6;
    const int lr = lane & 15;
    const int hg8 = (lane >> 4) * 8;
    const int rloc = (lane >> 4) * 4;
    const int lrow = lane >> 3;
    const int lchk = lane & 7;

    const unsigned short* gxq = xq + (size_t)(b * 128 + q0) * 512;
    const unsigned short* gkv = xkv + (size_t)(b * 128) * 512;
    const unsigned short* gw  = Wt + (size_t)(h * 64) * 512;

    auto stage = [&](int buf, int k0) {
        unsigned short* dst = (unsigned short*)(lds + buf * BUFB);
        if constexpr (SELF) {
#pragma unroll
            for (int j = 0; j < 5; ++j) {
                int start = wv * 40 + j * 8;
                int row = start + lrow;
                int sc = (lchk ^ (row & 7)) * 8;
                const unsigned short* src;
                if (start < 128) {
                    src = gkv + (size_t)row * 512 + k0 + sc;
                } else {
                    int wr_ = row - 128;
                    src = gw + ((size_t)(wr_ & 63) + (size_t)(wr_ >> 6) * 512) * 512 + k0 + sc;
                }
                gl2lds16(src, dst + start * 64);
            }
        } else {
            unsigned short* dstW = dst + XROWS * 64;
#pragma unroll
            for (int j = 0; j < 3; ++j) {
                int row = wv * 24 + j * 8 + lrow;
                int sc = (lchk ^ (row & 7)) * 8;
                const unsigned short* xs = (row < 64)
                    ? gxq + (size_t)row * 512
                    : gkv + (size_t)(row - 64) * 512;
                gl2lds16(xs + k0 + sc, dst + (wv * 24 + j * 8) * 64);
                const unsigned short* ws = gw + ((size_t)(row & 63) + (size_t)(row >> 6) * 512) * 512;
                gl2lds16(ws + k0 + sc, dstW + (wv * 24 + j * 8) * 64);
            }
        }
    };

    fx4 accQ[4], accK[4], accV[4];
#pragma unroll
    for (int c = 0; c < 4; ++c) {
        accQ[c] = fx4{0.f, 0.f, 0.f, 0.f};
        accK[c] = fx4{0.f, 0.f, 0.f, 0.f};
        accV[c] = fx4{0.f, 0.f, 0.f, 0.f};
    }
    stage(0, 0);
#pragma unroll 1
    for (int t = 0; t < 8; ++t) {
        __syncthreads();
        if (t < 7) stage((t + 1) & 1, (t + 1) * 64);
        const unsigned short* stX = (const unsigned short*)(lds + (t & 1) * BUFB);
        const unsigned short* stW = stX + XROWS * 64;
#pragma unroll
        for (int kk = 0; kk < 2; ++kk) {
            const int ca = kk * 4 + (lane >> 4);
            auto rd = [&](const unsigned short* base, int row) -> bfx8 {
                return *(const bfx8*)(base + row * 64 + ((ca ^ (row & 7)) * 8));
            };
            const int kvbase = SELF ? 0 : 64;
            bfx8 aKV = rd(stX, kvbase + wv * 16 + lr);
            bfx8 aQ = aKV;
            if (wv >= 4) aQ = rd(stX, (SELF ? q0 : 0) + (wv - 4) * 16 + lr);
            __builtin_amdgcn_s_setprio(1);
#pragma unroll
            for (int c = 0; c < 4; ++c) {
                bfx8 bk = rd(stW, 64 + c * 16 + lr);
                accK[c] = __builtin_amdgcn_mfma_f32_16x16x32_bf16(aKV, bk, accK[c], 0, 0, 0);
                bfx8 bv = rd(stW, 128 + c * 16 + lr);
                accV[c] = __builtin_amdgcn_mfma_f32_16x16x32_bf16(aKV, bv, accV[c], 0, 0, 0);
                if (wv >= 4) {
                    bfx8 bq = rd(stW, c * 16 + lr);
                    accQ[c] = __builtin_amdgcn_mfma_f32_16x16x32_bf16(aQ, bq, accQ[c], 0, 0, 0);
                }
            }
            __builtin_amdgcn_s_setprio(0);
        }
    }
    unsigned short* sQ  = (unsigned short*)(lds + 2 * BUFB);
    unsigned short* sK  = (unsigned short*)(lds + 2 * BUFB + 9216);
    unsigned short* sVt = (unsigned short*)(lds + 2 * BUFB + 9216 + 18432);
    float* zp = (float*)(lds + 2 * BUFB + 9216 + 18432 + 17408);
    unsigned short* sP  = (unsigned short*)lds;
#pragma unroll
    for (int c = 0; c < 4; ++c) {
        int col = c * 16 + lr;
        float bk_ = bias[512 + h * 64 + col];
        float bv_ = bias[1024 + h * 64 + col];
#pragma unroll
        for (int r = 0; r < 4; ++r) {
            sK[(wv * 16 + rloc + r) * 72 + col] = f2bf(accK[c][r] + bk_);
            sVt[col * 136 + (wv * 16 + rloc + r)] = f2bf(accV[c][r] + bv_);
        }
        if (wv >= 4) {
            float bq_ = bias[h * 64 + col];
#pragma unroll
            for (int r = 0; r < 4; ++r)
                sQ[((wv - 4) * 16 + rloc + r) * 72 + col] = f2bf(accQ[c][r] + bq_);
        }
    }
    __syncthreads();
    const int qb = wv >> 1;
    const int kh = wv & 1;
    fx4 acc[4];
#pragma unroll
    for (int n = 0; n < 4; ++n) acc[n] = fx4{0.f, 0.f, 0.f, 0.f};
#pragma unroll
    for (int kk = 0; kk < 2; ++kk) {
        bfx8 a = *(const bfx8*)(sQ + (qb * 16 + lr) * 72 + kk * 32 + hg8);
#pragma unroll
        for (int n = 0; n < 4; ++n) {
            bfx8 bb = *(const bfx8*)(sK + ((kh * 4 + n) * 16 + lr) * 72 + kk * 32 + hg8);
            acc[n] = __builtin_amdgcn_mfma_f32_16x16x32_bf16(a, bb, acc[n], 0, 0, 0);
        }
    }
    const int qg = q0 + qb * 16 + rloc;
#pragma unroll
    for (int r = 0; r < 4; ++r) {
        float zs = 0.f;
#pragma unroll
        for (int n = 0; n < 4; ++n) {
            float s = acc[n][r] * 0.125f;
            s = __expf(fminf(fmaxf(s, -5.f), 5.f));
            if (CAUSAL && (kh * 64 + n * 16 + lr) > (qg + r)) s = 0.f;
            zs += s;
            sP[(qb * 16 + rloc + r) * 136 + kh * 64 + n * 16 + lr] = f2bf(s);
        }
#pragma unroll
        for (int off = 8; off; off >>= 1) zs += __shfl_xor(zs, off);
        if (lr == 0) zp[(qb * 2 + kh) * 16 + rloc + r] = zs;
    }
    __syncthreads();
    float zinv[4];
#pragma unroll
    for (int r = 0; r < 4; ++r)
        zinv[r] = 1.f / (zp[(qb * 2 + 0) * 16 + rloc + r] + zp[(qb * 2 + 1) * 16 + rloc + r]);
    const int dh = wv & 1;
    fx4 acc2[2];
    acc2[0] = fx4{0.f, 0.f, 0.f, 0.f};
    acc2[1] = fx4{0.f, 0.f, 0.f, 0.f};
#pragma unroll
    for (int kk = 0; kk < 4; ++kk) {
        bfx8 a = *(const bfx8*)(sP + (qb * 16 + lr) * 136 + kk * 32 + hg8);
#pragma unroll
        for (int dn = 0; dn < 2; ++dn) {
            bfx8 bb = *(const bfx8*)(sVt + (dh * 32 + dn * 16 + lr) * 136 + kk * 32 + hg8);
            acc2[dn] = __builtin_amdgcn_mfma_f32_16x16x32_bf16(a, bb, acc2[dn], 0, 0, 0);
        }
    }
#pragma unroll
    for (int dn = 0; dn < 2; ++dn)
#pragma unroll
        for (int r = 0; r < 4; ++r) {
            size_t row = (size_t)(b * 128 + qg + r);
            out[row * 512 + h * 64 + dh * 32 + dn * 16 + lr] = f2bf(acc2[dn][r] * zinv[r]);
        }
}

// ---------------- log_softmax: bf16 logits [2048,8192] -> f32 out ----------------
__global__ __launch_bounds__(256) void logsoftmax_bf16_kernel(
    const unsigned short* __restrict__ logits, float* __restrict__ out)
{
    __shared__ float red[4];
    int tid = threadIdx.x;
    const bfx8* lrow = (const bfx8*)(logits + (size_t)blockIdx.x * 8192);
    float* orow = out + (size_t)blockIdx.x * 8192;
    float vals[32];
    float mx = -1e30f;
#pragma unroll
    for (int i = 0; i < 4; ++i) {
        bfx8 u = lrow[i * 256 + tid];
#pragma unroll
        for (int j = 0; j < 8; ++j) {
            float f = bf2f((unsigned short)u[j]);
            vals[i * 8 + j] = f;
            mx = fmaxf(mx, f);
        }
    }
#pragma unroll
    for (int off = 32; off; off >>= 1) mx = fmaxf(mx, __shfl_xor(mx, off));
    int wid = tid >> 6;
    if ((tid & 63) == 0) red[wid] = mx;
    __syncthreads();
    mx = fmaxf(fmaxf(red[0], red[1]), fmaxf(red[2], red[3]));
    __syncthreads();
    float sum = 0.f;
#pragma unroll
    for (int i = 0; i < 32; ++i) sum += __expf(vals[i] - mx);
#pragma unroll
    for (int off = 32; off; off >>= 1) sum += __shfl_xor(sum, off);
    if ((tid & 63) == 0) red[wid] = sum;
    __syncthreads();
    sum = red[0] + red[1] + red[2] + red[3];
    float lsub = mx + logf(sum);
#pragma unroll
    for (int i = 0; i < 4; ++i) {
        fx4 o0, o1;
#pragma unroll
        for (int j = 0; j < 4; ++j) {
            o0[j] = vals[i * 8 + j] - lsub;
            o1[j] = vals[i * 8 + 4 + j] - lsub;
        }
        ((fx4*)orow)[(i * 256 + tid) * 2] = o0;
        ((fx4*)orow)[(i * 256 + tid) * 2 + 1] = o1;
    }
}

extern "C" void kernel_launch(void* const* d_in, const int* in_sizes, int n_in,
                              void* d_out, int out_size, void* d_ws, size_t ws_size,
                              hipStream_t stream) {
    (void)in_sizes; (void)n_in; (void)out_size; (void)ws_size;
    const int* src_tokens = (const int*)d_in[0];
    const int* tgt_tokens = (const int*)d_in[1];
    const float* src_emb    = (const float*)d_in[8];
    const float* tgt_emb    = (const float*)d_in[9];
    const float* enc_attn_W = (const float*)d_in[10];
    const float* enc_attn_b = (const float*)d_in[11];
    const float* enc_ln_g   = (const float*)d_in[12];
    const float* enc_ln_b   = (const float*)d_in[13];
    const float* enc_ff_W1  = (const float*)d_in[14];
    const float* enc_ff_b1  = (const float*)d_in[15];
    const float* enc_ff_W2  = (const float*)d_in[16];
    const float* enc_ff_b2  = (const float*)d_in[17];
    const float* enc_norm_g = (const float*)d_in[18];
    const float* enc_norm_b = (const float*)d_in[19];
    const float* dec_self_W = (const float*)d_in[20];
    const float* dec_self_b = (const float*)d_in[21];
    const float* dec_cross_W= (const float*)d_in[22];
    const float* dec_cross_b= (const float*)d_in[23];
    const float* dec_ln_g   = (const float*)d_in[24];
    const float* dec_ln_b   = (const float*)d_in[25];
    const float* dec_ff_W1  = (const float*)d_in[26];
    const float* dec_ff_b1  = (const float*)d_in[27];
    const float* dec_ff_W2  = (const float*)d_in[28];
    const float* dec_ff_b2  = (const float*)d_in[29];
    const float* dec_norm_g = (const float*)d_in[30];
    const float* dec_norm_b = (const float*)d_in[31];
    const float* gen_W      = (const float*)d_in[32];
    const float* gen_b      = (const float*)d_in[33];
    float* dout = (float*)d_out;

    // ---- workspace layout ----
    unsigned short* wt = (unsigned short*)d_ws;
    const size_t OFF_ENCQKV = 0;
    const size_t OFF_ENCO   = 1572864;
    const size_t OFF_ENCW1  = 2097152;
    const size_t OFF_ENCW2  = 4194304;
    const size_t OFF_DECSQKV= 6291456;
    const size_t OFF_DECSO  = 7864320;
    const size_t OFF_DECCQKV= 8388608;
    const size_t OFF_DECCO  = 9961472;
    const size_t OFF_DECW1  = 10485760;
    const size_t OFF_DECW2  = 12582912;
    const size_t OFF_GENW   = 14680064;
    const size_t WT_ELEMS   = 18874368;
    float* fb  = (float*)(wt + WT_ELEMS);
    float* xe  = fb;
    float* xd  = fb + 1048576;
    unsigned short* nxb   = (unsigned short*)(fb + 2097152);
    unsigned short* nxd0  = (unsigned short*)(fb + 3145728);
    unsigned short* ffb   = (unsigned short*)(fb + 4194304);  // [2048,2048] bf16 -> ends at fb+6291456
    unsigned short* nkvb0 = (unsigned short*)(fb + 6291456);  // [2048,512] bf16
    unsigned short* nkvb1 = (unsigned short*)(fb + 6815744);  // [2048,512] bf16
    unsigned short* attb  = (unsigned short*)(fb + 7340032);  // [2048,512] bf16
    unsigned short* genin   = (unsigned short*)fb;             // aliases xe (dead)
    unsigned short* logitsb = (unsigned short*)(fb + 1048576); // aliases xd.. (dead)

    // ---- single-launch weight prep ----
    TrTable tt;
    {
        int z = 0, gi = 0;
        auto addg = [&](const float* s, unsigned short* d, int srs, int drs,
                        long so, long dof, int zc) {
            tt.zStart[gi] = z;
            tt.g[gi].src = s; tt.g[gi].dst = d;
            tt.g[gi].srcRowStride = srs; tt.g[gi].dstRowStride = drs;
            tt.g[gi].srcSliceOff = so; tt.g[gi].dstSliceOff = dof;
            ++gi; z += zc;
        };
        addg(enc_attn_W,              wt + OFF_ENCQKV,               512,  512,  262144,    262144, 3);
        addg(enc_attn_W + 4L*262144,  wt + OFF_ENCQKV + 3L*262144,   512,  512,  262144,    262144, 3);
        addg(enc_attn_W + 3L*262144,  wt + OFF_ENCO,                 512,  512,  4L*262144, 262144, 2);
        addg(enc_ff_W1,               wt + OFF_ENCW1,                2048, 512,  512,       262144, 4);
        addg(enc_ff_W1 + 1048576,     wt + OFF_ENCW1 + 1048576,      2048, 512,  512,       262144, 4);
        addg(enc_ff_W2,               wt + OFF_ENCW2,                512,  2048, 262144,    512,    4);
        addg(enc_ff_W2 + 1048576,     wt + OFF_ENCW2 + 1048576,      512,  2048, 262144,    512,    4);
        addg(dec_self_W,              wt + OFF_DECSQKV,              512,  512,  262144,    262144, 3);
        addg(dec_self_W + 4L*262144,  wt + OFF_DECSQKV + 3L*262144,  512,  512,  262144,    262144, 3);
        addg(dec_self_W + 3L*262144,  wt + OFF_DECSO,                512,  512,  4L*262144, 262144, 2);
        addg(dec_cross_W,             wt + OFF_DECCQKV,              512,  512,  262144,    262144, 3);
        addg(dec_cross_W + 4L*262144, wt + OFF_DECCQKV + 3L*262144,  512,  512,  262144,    262144, 3);
        addg(dec_cross_W + 3L*262144, wt + OFF_DECCO,                512,  512,  4L*262144, 262144, 2);
        addg(dec_ff_W1,               wt + OFF_DECW1,                2048, 512,  512,       262144, 4);
        addg(dec_ff_W1 + 1048576,     wt + OFF_DECW1 + 1048576,      2048, 512,  512,       262144, 4);
        addg(dec_ff_W2,               wt + OFF_DECW2,                512,  2048, 262144,    512,    4);
        addg(dec_ff_W2 + 1048576,     wt + OFF_DECW2 + 1048576,      512,  2048, 262144,    512,    4);
        addg(gen_W,                   wt + OFF_GENW,                 8192, 512,  512,       262144, 16);
        tt.zStart[18] = z;  // 72
    }
    trall_kernel<<<dim3(16, 16, 72), 256, 0, stream>>>(tt);

    // ---- embeddings + first LN (enc layer-0 -> nxb, dec layer-0 -> nxd0) ----
    embedln_kernel<<<4096, 256, 0, stream>>>(
        src_tokens, tgt_tokens, src_emb, tgt_emb, xe, xd,
        enc_ln_g, enc_ln_b, dec_ln_g, dec_ln_b, nxb, nxd0);

    auto gemmK = [&](const unsigned short* A, const unsigned short* W, const float* bias,
                     const float* res, void* C, int N, int K, int ldc, bool relu, bool outbf) {
        int gx = N / 64;
        dim3 g(gx * 32);
        if (res)        gemm_bk128_kernel<false, true,  false><<<g, 256, 0, stream>>>(A, W, bias, res, C, K, ldc, gx);
        else if (relu)  gemm_bk128_kernel<true,  false, true ><<<g, 256, 0, stream>>>(A, W, bias, res, C, K, ldc, gx);
        else if (outbf) gemm_bk128_kernel<false, false, true ><<<g, 256, 0, stream>>>(A, W, bias, res, C, K, ldc, gx);
        else            gemm_bk128_kernel<false, false, false><<<g, 256, 0, stream>>>(A, W, bias, res, C, K, ldc, gx);
    };
    auto gemmLN = [&](const unsigned short* A, const unsigned short* W, const float* bias,
                      float* res, const float* lg, const float* lb, unsigned short* lnout) {
        gemm_ln_kernel<<<32, 256, 0, stream>>>(A, W, bias, res, lg, lb, lnout);
    };
    auto gemm128 = [&](const unsigned short* A, const unsigned short* W, const float* bias,
                       unsigned short* C, int N, int K, int ldc, bool relu) {
        dim3 g((N / 128) * 16);
        if (relu) gemm128_kernel<true ><<<g, 256, 0, stream>>>(A, W, bias, C, K, ldc);
        else      gemm128_kernel<false><<<g, 256, 0, stream>>>(A, W, bias, C, K, ldc);
    };
    auto lnb = [&](const float* x, const float* g, const float* b, unsigned short* o) {
        ln_kernel<true><<<512, 256, 0, stream>>>(x, g, b, o);
    };

    // ---- encoder ----
    for (int i = 0; i < 2; ++i) {
        if (i) lnb(xe, enc_ln_g + (size_t)(i * 2) * 512, enc_ln_b + (size_t)(i * 2) * 512, nxb);
        fattn_kernel<false, true><<<256, 512, 0, stream>>>(
            nxb, nxb, wt + OFF_ENCQKV + (size_t)i * 3 * 262144,
            enc_attn_b + (size_t)i * 4 * 512, attb);
        gemmLN(attb, wt + OFF_ENCO + (size_t)i * 262144, enc_attn_b + (size_t)i * 4 * 512 + 1536,
               xe, enc_ln_g + (size_t)(i * 2 + 1) * 512, enc_ln_b + (size_t)(i * 2 + 1) * 512, nxb);
        gemm128(nxb, wt + OFF_ENCW1 + (size_t)i * 1048576, enc_ff_b1 + (size_t)i * 2048,
                ffb, 2048, 512, 2048, true);
        gemmK(ffb, wt + OFF_ENCW2 + (size_t)i * 1048576, enc_ff_b2 + (size_t)i * 512,
              xe, xe, 512, 2048, 512, false, false);
    }
    // final enc norm + both decoder cross-LN(xe) precomputed
    ln3_kernel<<<512, 256, 0, stream>>>(
        xe, enc_norm_g, enc_norm_b,
        dec_ln_g + 512, dec_ln_b + 512,          // (0*3+1)
        dec_ln_g + 4 * 512, dec_ln_b + 4 * 512,  // (1*3+1)
        nkvb0, nkvb1);

    // ---- decoder ----
    for (int i = 0; i < 2; ++i) {
        const unsigned short* qsrc = (i == 0) ? nxd0 : nxb;
        if (i) lnb(xd, dec_ln_g + (size_t)(i * 3) * 512, dec_ln_b + (size_t)(i * 3) * 512, nxb);
        fattn_kernel<true, true><<<256, 512, 0, stream>>>(
            qsrc, qsrc, wt + OFF_DECSQKV + (size_t)i * 3 * 262144,
            dec_self_b + (size_t)i * 4 * 512, attb);
        gemmLN(attb, wt + OFF_DECSO + (size_t)i * 262144, dec_self_b + (size_t)i * 4 * 512 + 1536,
               xd, dec_ln_g + (size_t)(i * 3 + 1) * 512, dec_ln_b + (size_t)(i * 3 + 1) * 512, nxb);
        fattn_kernel<false, false><<<256, 512, 0, stream>>>(
            nxb, i ? nkvb1 : nkvb0, wt + OFF_DECCQKV + (size_t)i * 3 * 262144,
            dec_cross_b + (size_t)i * 4 * 512, attb);
        gemmLN(attb, wt + OFF_DECCO + (size_t)i * 262144, dec_cross_b + (size_t)i * 4 * 512 + 1536,
               xd, dec_ln_g + (size_t)(i * 3 + 2) * 512, dec_ln_b + (size_t)(i * 3 + 2) * 512, nxb);
        gemm128(nxb, wt + OFF_DECW1 + (size_t)i * 1048576, dec_ff_b1 + (size_t)i * 2048,
                ffb, 2048, 512, 2048, true);
        gemmK(ffb, wt + OFF_DECW2 + (size_t)i * 1048576, dec_ff_b2 + (size_t)i * 512,
              xd, xd, 512, 2048, 512, false, false);
    }
    lnb(xd, dec_norm_g, dec_norm_b, genin);

    // ---- generator + log_softmax ----
    gemm128(genin, wt + OFF_GENW, gen_b, logitsb, 8192, 512, 8192, false);
    logsoftmax_bf16_kernel<<<2048, 256, 0, stream>>>(logitsb, dout);
}

// Round 10
// 329.962 us; speedup vs baseline: 1.2369x; 1.2369x over previous
//
#include <hip/hip_runtime.h>

typedef __attribute__((ext_vector_type(8))) short bfx8;
typedef __attribute__((ext_vector_type(4))) float fx4;

static __device__ __forceinline__ unsigned short f2bf(float f) {
    union { float f; unsigned int u; } v; v.f = f;
    unsigned int i = v.u;
    return (unsigned short)((i + 0x7FFFu + ((i >> 16) & 1u)) >> 16);
}
static __device__ __forceinline__ float bf2f(unsigned short u) {
    union { unsigned int ui; float f; } cv;
    cv.ui = ((unsigned int)u) << 16;
    return cv.f;
}

// async global->LDS, 16B per lane; l is the WAVE-UNIFORM base (HW adds lane*16)
static __device__ __forceinline__ void gl2lds16(const unsigned short* g, unsigned short* l) {
    unsigned long long gu = (unsigned long long)g;
    unsigned int lu = (unsigned int)(unsigned long long)l;
    __builtin_amdgcn_global_load_lds(
        (const __attribute__((address_space(1))) void*)gu,
        (__attribute__((address_space(3))) void*)lu,
        16, 0, 0);
}

// ---------------- single-launch weight prep: 72 slices of [512K x 512N] f32 -> bf16 [N,K] ----------------
struct TrGroup {
    const float* src;
    unsigned short* dst;
    int srcRowStride;
    int dstRowStride;
    long srcSliceOff;
    long dstSliceOff;
};
struct TrTable {
    TrGroup g[18];
    int zStart[19];
};

__global__ __launch_bounds__(256) void trall_kernel(TrTable tt)
{
    __shared__ unsigned short tile[32][33];
    int z = blockIdx.z;
    int gi = 0;
#pragma unroll 1
    while (z >= tt.zStart[gi + 1]) ++gi;
    int zi = z - tt.zStart[gi];
    const float* s = tt.g[gi].src + (size_t)zi * tt.g[gi].srcSliceOff;
    unsigned short* d = tt.g[gi].dst + (size_t)zi * tt.g[gi].dstSliceOff;
    int srs = tt.g[gi].srcRowStride, drs = tt.g[gi].dstRowStride;
    int n0 = blockIdx.x * 32, k0 = blockIdx.y * 32;
    int tx = threadIdx.x & 31, ty = threadIdx.x >> 5;
#pragma unroll
    for (int i = 0; i < 32; i += 8)
        tile[ty + i][tx] = f2bf(s[(size_t)(k0 + ty + i) * srs + (n0 + tx)]);
    __syncthreads();
#pragma unroll
    for (int i = 0; i < 32; i += 8)
        d[(size_t)(n0 + ty + i) * drs + (k0 + tx)] = tile[tx][ty + i];
}

// ---------------- fused embeddings + PE + first LN (src & tgt in one launch) ----------------
__global__ __launch_bounds__(256) void embedln_kernel(
    const int* __restrict__ tokA, const int* __restrict__ tokB,
    const float* __restrict__ embA, const float* __restrict__ embB,
    float* __restrict__ outA, float* __restrict__ outB,
    const float* __restrict__ gA, const float* __restrict__ bA,
    const float* __restrict__ gB, const float* __restrict__ bB,
    unsigned short* __restrict__ nxA, unsigned short* __restrict__ nxB)
{
    __shared__ float red[4];
    int idx = blockIdx.x;
    int row = idx & 2047;
    bool e = idx < 2048;
    const int* tok = e ? tokA : tokB;
    const float* emb = e ? embA : embB;
    float* out = e ? outA : outB;
    const float* g = e ? gA : gB;
    const float* bb = e ? bA : bB;
    unsigned short* nx = e ? nxA : nxB;
    int pos = row & 127;
    int t = tok[row];
    int d0 = threadIdx.x, d1 = threadIdx.x + 256;
    auto pe = [&](int d) {
        float ang = (float)pos * expf((float)(d & ~1) * (-9.210340371976184f / 512.0f));
        return (d & 1) ? cosf(ang) : sinf(ang);
    };
    float v0 = emb[(size_t)t * 512 + d0] * 22.627416997969522f + pe(d0);
    float v1 = emb[(size_t)t * 512 + d1] * 22.627416997969522f + pe(d1);
    out[(size_t)row * 512 + d0] = v0;
    out[(size_t)row * 512 + d1] = v1;
    int lane = threadIdx.x & 63, wv = threadIdx.x >> 6;
    float s = v0 + v1;
#pragma unroll
    for (int off = 32; off; off >>= 1) s += __shfl_xor(s, off);
    if (lane == 0) red[wv] = s;
    __syncthreads();
    float mu = (red[0] + red[1] + red[2] + red[3]) * (1.0f / 512.0f);
    __syncthreads();
    float q = (v0 - mu) * (v0 - mu) + (v1 - mu) * (v1 - mu);
#pragma unroll
    for (int off = 32; off; off >>= 1) q += __shfl_xor(q, off);
    if (lane == 0) red[wv] = q;
    __syncthreads();
    float rs = rsqrtf((red[0] + red[1] + red[2] + red[3]) * (1.0f / 512.0f) + 1e-5f);
    nx[(size_t)row * 512 + d0] = f2bf(g[d0] * (v0 - mu) * rs + bb[d0]);
    nx[(size_t)row * 512 + d1] = f2bf(g[d1] * (v1 - mu) * rs + bb[d1]);
}

// ---------------- layernorm row body (D=512, one wave) ----------------
static __device__ __forceinline__ void ln_row(
    const float* __restrict__ xrow, const float* __restrict__ g,
    const float* __restrict__ b, int lane, fx4& o0, fx4& o1)
{
    const fx4* xr = (const fx4*)xrow;
    fx4 a = xr[lane * 2], c = xr[lane * 2 + 1];
    float s = a[0] + a[1] + a[2] + a[3] + c[0] + c[1] + c[2] + c[3];
#pragma unroll
    for (int off = 32; off; off >>= 1) s += __shfl_xor(s, off);
    float mu = s * (1.0f / 512.0f);
    float qv = 0.f;
#pragma unroll
    for (int j = 0; j < 4; ++j) {
        float d0 = a[j] - mu; qv += d0 * d0;
        float d1 = c[j] - mu; qv += d1 * d1;
    }
#pragma unroll
    for (int off = 32; off; off >>= 1) qv += __shfl_xor(qv, off);
    float rs = rsqrtf(qv * (1.0f / 512.0f) + 1e-5f);
    const fx4* gr = (const fx4*)g;
    const fx4* br = (const fx4*)b;
    fx4 g0 = gr[lane * 2], g1 = gr[lane * 2 + 1];
    fx4 b0 = br[lane * 2], b1 = br[lane * 2 + 1];
#pragma unroll
    for (int j = 0; j < 4; ++j) {
        o0[j] = g0[j] * (a[j] - mu) * rs + b0[j];
        o1[j] = g1[j] * (c[j] - mu) * rs + b1[j];
    }
}

template<bool OUTBF>
__global__ __launch_bounds__(256) void ln_kernel(
    const float* __restrict__ x, const float* __restrict__ g,
    const float* __restrict__ b, void* __restrict__ out)
{
    int row = blockIdx.x * 4 + (threadIdx.x >> 6);
    int lane = threadIdx.x & 63;
    fx4 o0, o1;
    ln_row(x + (size_t)row * 512, g, b, lane, o0, o1);
    if (OUTBF) {
        unsigned short* orow = (unsigned short*)out + (size_t)row * 512 + lane * 8;
        ushort4 u0 = {f2bf(o0[0]), f2bf(o0[1]), f2bf(o0[2]), f2bf(o0[3])};
        ushort4 u1 = {f2bf(o1[0]), f2bf(o1[1]), f2bf(o1[2]), f2bf(o1[3])};
        *(ushort4*)orow = u0;
        *(ushort4*)(orow + 4) = u1;
    } else {
        fx4* orow = (fx4*)out + (size_t)row * 128;
        orow[lane * 2] = o0;
        orow[lane * 2 + 1] = o1;
    }
}

// fused: xe = LN(xe, enc_norm); nk0 = LN(xe', dec l0); nk1 = LN(xe', dec l1)
__global__ __launch_bounds__(256) void ln3_kernel(
    float* __restrict__ xe, const float* __restrict__ eg, const float* __restrict__ eb,
    const float* __restrict__ g0, const float* __restrict__ b0,
    const float* __restrict__ g1, const float* __restrict__ b1,
    unsigned short* __restrict__ nk0, unsigned short* __restrict__ nk1)
{
    int row = blockIdx.x * 4 + (threadIdx.x >> 6);
    int lane = threadIdx.x & 63;
    fx4 t0, t1;
    ln_row(xe + (size_t)row * 512, eg, eb, lane, t0, t1);
    fx4* orow = (fx4*)(xe + (size_t)row * 512);
    orow[lane * 2] = t0;
    orow[lane * 2 + 1] = t1;
    float s = t0[0] + t0[1] + t0[2] + t0[3] + t1[0] + t1[1] + t1[2] + t1[3];
#pragma unroll
    for (int off = 32; off; off >>= 1) s += __shfl_xor(s, off);
    float mu = s * (1.0f / 512.0f);
    float q = 0.f;
#pragma unroll
    for (int j = 0; j < 4; ++j) {
        float a = t0[j] - mu; q += a * a;
        float c = t1[j] - mu; q += c * c;
    }
#pragma unroll
    for (int off = 32; off; off >>= 1) q += __shfl_xor(q, off);
    float rs = rsqrtf(q * (1.0f / 512.0f) + 1e-5f);
    const fx4* g0r = (const fx4*)g0; const fx4* b0r = (const fx4*)b0;
    const fx4* g1r = (const fx4*)g1; const fx4* b1r = (const fx4*)b1;
    fx4 ga0 = g0r[lane * 2], ga1 = g0r[lane * 2 + 1];
    fx4 bb0 = b0r[lane * 2], bb1 = b0r[lane * 2 + 1];
    fx4 gc0 = g1r[lane * 2], gc1 = g1r[lane * 2 + 1];
    fx4 bc0 = b1r[lane * 2], bc1 = b1r[lane * 2 + 1];
    unsigned short* o0 = nk0 + (size_t)row * 512 + lane * 8;
    unsigned short* o1 = nk1 + (size_t)row * 512 + lane * 8;
    ushort4 ua0, ua1, uc0, uc1;
#pragma unroll
    for (int j = 0; j < 4; ++j) {
        float n0 = (t0[j] - mu) * rs, n1 = (t1[j] - mu) * rs;
        ((unsigned short*)&ua0)[j] = f2bf(ga0[j] * n0 + bb0[j]);
        ((unsigned short*)&ua1)[j] = f2bf(ga1[j] * n1 + bb1[j]);
        ((unsigned short*)&uc0)[j] = f2bf(gc0[j] * n0 + bc0[j]);
        ((unsigned short*)&uc1)[j] = f2bf(gc1[j] * n1 + bc1[j]);
    }
    *(ushort4*)o0 = ua0; *(ushort4*)(o0 + 4) = ua1;
    *(ushort4*)o1 = uc0; *(ushort4*)(o1 + 4) = uc1;
}

// ---------------- bf16 MFMA GEMM, 64x64 tile, BK=128 ----------------
template<bool RELU, bool RESID, bool OUTBF>
__global__ __launch_bounds__(256) void gemm_bk128_kernel(
    const unsigned short* __restrict__ A, const unsigned short* __restrict__ Wt,
    const float* __restrict__ bias, const float* __restrict__ res,
    void* __restrict__ Cv, int K, int ldc, int gx)
{
    __shared__ unsigned short smem[2][2][8192];  // [buf][A/B][64*128]
    const int tid = threadIdx.x;
    const int nwg = gridDim.x;
    const int cpx = nwg >> 3;
    const int phys = blockIdx.x;
    const int logical = (phys & 7) * cpx + (phys >> 3);
    const int bm = (logical / gx) * 64;
    const int bn = (logical % gx) * 64;
    const int lane = tid & 63;
    const int wv = tid >> 6;
    const int wr = (wv >> 1) * 32;
    const int wc = (wv & 1) * 32;
    const int lr = lane & 15;
    const int lrow4 = lane >> 4;
    const int lchk16 = lane & 15;
    fx4 acc00 = {0.f, 0.f, 0.f, 0.f}, acc01 = {0.f, 0.f, 0.f, 0.f};
    fx4 acc10 = {0.f, 0.f, 0.f, 0.f}, acc11 = {0.f, 0.f, 0.f, 0.f};

    auto stage = [&](int buf, int k0) {
#pragma unroll
        for (int j = 0; j < 4; ++j) {
            int row = wv * 16 + j * 4 + lrow4;
            int sc = (lchk16 ^ (row & 15)) * 8;
            gl2lds16(A + (size_t)(bm + row) * K + k0 + sc,
                     &smem[buf][0][(wv * 16 + j * 4) * 128]);
            gl2lds16(Wt + (size_t)(bn + row) * K + k0 + sc,
                     &smem[buf][1][(wv * 16 + j * 4) * 128]);
        }
    };

    const int nt = K >> 7;
    int cur = 0;
    stage(0, 0);
    for (int t = 0; t < nt; ++t) {
        __syncthreads();
        if (t + 1 < nt) stage(cur ^ 1, (t + 1) << 7);
        const unsigned short* bufA = &smem[cur][0][0];
        const unsigned short* bufB = &smem[cur][1][0];
        const int ra0 = wr + lr, ra1 = wr + 16 + lr;
        const int rb0 = wc + lr, rb1 = wc + 16 + lr;
        __builtin_amdgcn_s_setprio(1);
#pragma unroll
        for (int kk = 0; kk < 4; ++kk) {
            int ca = kk * 4 + (lane >> 4);
            bfx8 a0 = *(const bfx8*)&bufA[ra0 * 128 + ((ca ^ (ra0 & 15)) * 8)];
            bfx8 a1 = *(const bfx8*)&bufA[ra1 * 128 + ((ca ^ (ra1 & 15)) * 8)];
            bfx8 b0 = *(const bfx8*)&bufB[rb0 * 128 + ((ca ^ (rb0 & 15)) * 8)];
            bfx8 b1 = *(const bfx8*)&bufB[rb1 * 128 + ((ca ^ (rb1 & 15)) * 8)];
            acc00 = __builtin_amdgcn_mfma_f32_16x16x32_bf16(a0, b0, acc00, 0, 0, 0);
            acc01 = __builtin_amdgcn_mfma_f32_16x16x32_bf16(a0, b1, acc01, 0, 0, 0);
            acc10 = __builtin_amdgcn_mfma_f32_16x16x32_bf16(a1, b0, acc10, 0, 0, 0);
            acc11 = __builtin_amdgcn_mfma_f32_16x16x32_bf16(a1, b1, acc11, 0, 0, 0);
        }
        __builtin_amdgcn_s_setprio(0);
        cur ^= 1;
    }
    int rbase = bm + wr + ((lane >> 4) * 4);
    int cbase = bn + wc + lr;
#pragma unroll
    for (int m = 0; m < 2; ++m) {
        fx4 am0 = m ? acc10 : acc00;
        fx4 am1 = m ? acc11 : acc01;
#pragma unroll
        for (int r = 0; r < 4; ++r) {
            int row = rbase + m * 16 + r;
#pragma unroll
            for (int half = 0; half < 2; ++half) {
                int col = cbase + half * 16;
                float v = (half ? am1[r] : am0[r]) + bias[col];
                if (RESID) v += res[(size_t)row * ldc + col];
                if (RELU) v = fmaxf(v, 0.f);
                if (OUTBF) ((unsigned short*)Cv)[(size_t)row * ldc + col] = f2bf(v);
                else       ((float*)Cv)[(size_t)row * ldc + col] = v;
            }
        }
    }
}

// ---------------- bf16 MFMA GEMM, 128x128 tile (4 waves x 64x64), bf16 out ----------------
template<bool RELU>
__global__ __launch_bounds__(256) void gemm128_kernel(
    const unsigned short* __restrict__ A, const unsigned short* __restrict__ Wt,
    const float* __restrict__ bias, unsigned short* __restrict__ C,
    int K, int ldc)
{
    __shared__ unsigned short smem[2][2][8192];  // [buf][A/B][128*64]
    const int tid = threadIdx.x;
    const int nwg = gridDim.x;
    const int cpx = nwg >> 3;
    const int phys = blockIdx.x;
    const int logical = (phys & 7) * cpx + (phys >> 3);
    const int bm = (logical & 15) * 128;     // M = 2048 always
    const int bn = (logical >> 4) * 128;
    const int lane = tid & 63;
    const int wv = tid >> 6;
    const int wr = (wv >> 1) * 64;
    const int wc = (wv & 1) * 64;
    const int lr = lane & 15;
    const int lrow = lane >> 3;
    const int lchk = lane & 7;
    fx4 acc[4][4];
#pragma unroll
    for (int mi = 0; mi < 4; ++mi)
#pragma unroll
        for (int ni = 0; ni < 4; ++ni) acc[mi][ni] = fx4{0.f, 0.f, 0.f, 0.f};

    auto stage = [&](int buf, int k0) {
#pragma unroll
        for (int j = 0; j < 4; ++j) {
            int row = wv * 32 + j * 8 + lrow;
            int sc = lchk ^ (row & 7);
            gl2lds16(A + (size_t)(bm + row) * K + k0 + sc * 8,
                     &smem[buf][0][(wv * 32 + j * 8) * 64]);
            gl2lds16(Wt + (size_t)(bn + row) * K + k0 + sc * 8,
                     &smem[buf][1][(wv * 32 + j * 8) * 64]);
        }
    };

    const int nt = K >> 6;
    int cur = 0;
    stage(0, 0);
    for (int t = 0; t < nt; ++t) {
        __syncthreads();
        if (t + 1 < nt) stage(cur ^ 1, (t + 1) << 6);
        const unsigned short* bufA = &smem[cur][0][0];
        const unsigned short* bufB = &smem[cur][1][0];
        __builtin_amdgcn_s_setprio(1);
#pragma unroll
        for (int kk = 0; kk < 2; ++kk) {
            int ca = kk * 4 + (lane >> 4);
            bfx8 af[4], bg[4];
#pragma unroll
            for (int i = 0; i < 4; ++i) {
                int ra = wr + i * 16 + lr;
                int rb = wc + i * 16 + lr;
                af[i] = *(const bfx8*)&bufA[ra * 64 + ((ca ^ (ra & 7)) * 8)];
                bg[i] = *(const bfx8*)&bufB[rb * 64 + ((ca ^ (rb & 7)) * 8)];
            }
#pragma unroll
            for (int mi = 0; mi < 4; ++mi)
#pragma unroll
                for (int ni = 0; ni < 4; ++ni)
                    acc[mi][ni] = __builtin_amdgcn_mfma_f32_16x16x32_bf16(af[mi], bg[ni], acc[mi][ni], 0, 0, 0);
        }
        __builtin_amdgcn_s_setprio(0);
        cur ^= 1;
    }
    int rbase = bm + wr + ((lane >> 4) * 4);
    int cbase = bn + wc + lr;
#pragma unroll
    for (int mi = 0; mi < 4; ++mi)
#pragma unroll
        for (int ni = 0; ni < 4; ++ni) {
            int col = cbase + ni * 16;
            float bv = bias[col];
#pragma unroll
            for (int r = 0; r < 4; ++r) {
                int row = rbase + mi * 16 + r;
                float v = acc[mi][ni][r] + bv;
                if (RELU) v = fmaxf(v, 0.f);
                C[(size_t)row * ldc + col] = f2bf(v);
            }
        }
}

// ---------------- fused QKV-projection + attention (8 waves) ----------------
template<bool CAUSAL, bool SELF>
__global__ __launch_bounds__(512) void fattn_kernel(
    const unsigned short* __restrict__ xq, const unsigned short* __restrict__ xkv,
    const unsigned short* __restrict__ Wt, const float* __restrict__ bias,
    unsigned short* __restrict__ out)
{
    constexpr int XROWS = SELF ? 128 : 192;
    constexpr int BUFB  = (XROWS + 192) * 64 * 2;
    __shared__ __align__(16) unsigned char lds[2 * BUFB + 9216 + 18432 + 17408 + 512];
    const int blk = blockIdx.x;
    const int half = blk & 1;
    const int h = (blk >> 1) & 7;
    const int b = blk >> 4;
    const int q0 = half * 64;
    const int tid = threadIdx.x;
    const int lane = tid & 63;
    const int wv = tid >> 6;
    const int lr = lane & 15;
    const int hg8 = (lane >> 4) * 8;
    const int rloc = (lane >> 4) * 4;
    const int lrow = lane >> 3;
    const int lchk = lane & 7;

    const unsigned short* gxq = xq + (size_t)(b * 128 + q0) * 512;
    const unsigned short* gkv = xkv + (size_t)(b * 128) * 512;
    const unsigned short* gw  = Wt + (size_t)(h * 64) * 512;

    auto stage = [&](int buf, int k0) {
        unsigned short* dst = (unsigned short*)(lds + buf * BUFB);
        if constexpr (SELF) {
#pragma unroll
            for (int j = 0; j < 5; ++j) {
                int start = wv * 40 + j * 8;
                int row = start + lrow;
                int sc = (lchk ^ (row & 7)) * 8;
                const unsigned short* src;
                if (start < 128) {
                    src = gkv + (size_t)row * 512 + k0 + sc;
                } else {
                    int wr_ = row - 128;
                    src = gw + ((size_t)(wr_ & 63) + (size_t)(wr_ >> 6) * 512) * 512 + k0 + sc;
                }
                gl2lds16(src, dst + start * 64);
            }
        } else {
            unsigned short* dstW = dst + XROWS * 64;
#pragma unroll
            for (int j = 0; j < 3; ++j) {
                int row = wv * 24 + j * 8 + lrow;
                int sc = (lchk ^ (row & 7)) * 8;
                const unsigned short* xs = (row < 64)
                    ? gxq + (size_t)row * 512
                    : gkv + (size_t)(row - 64) * 512;
                gl2lds16(xs + k0 + sc, dst + (wv * 24 + j * 8) * 64);
                const unsigned short* ws = gw + ((size_t)(row & 63) + (size_t)(row >> 6) * 512) * 512;
                gl2lds16(ws + k0 + sc, dstW + (wv * 24 + j * 8) * 64);
            }
        }
    };

    fx4 accQ[4], accK[4], accV[4];
#pragma unroll
    for (int c = 0; c < 4; ++c) {
        accQ[c] = fx4{0.f, 0.f, 0.f, 0.f};
        accK[c] = fx4{0.f, 0.f, 0.f, 0.f};
        accV[c] = fx4{0.f, 0.f, 0.f, 0.f};
    }
    stage(0, 0);
#pragma unroll 1
    for (int t = 0; t < 8; ++t) {
        __syncthreads();
        if (t < 7) stage((t + 1) & 1, (t + 1) * 64);
        const unsigned short* stX = (const unsigned short*)(lds + (t & 1) * BUFB);
        const unsigned short* stW = stX + XROWS * 64;
#pragma unroll
        for (int kk = 0; kk < 2; ++kk) {
            const int ca = kk * 4 + (lane >> 4);
            auto rd = [&](const unsigned short* base, int row) -> bfx8 {
                return *(const bfx8*)(base + row * 64 + ((ca ^ (row & 7)) * 8));
            };
            const int kvbase = SELF ? 0 : 64;
            bfx8 aKV = rd(stX, kvbase + wv * 16 + lr);
            bfx8 aQ = aKV;
            if (wv >= 4) aQ = rd(stX, (SELF ? q0 : 0) + (wv - 4) * 16 + lr);
            __builtin_amdgcn_s_setprio(1);
#pragma unroll
            for (int c = 0; c < 4; ++c) {
                bfx8 bk = rd(stW, 64 + c * 16 + lr);
                accK[c] = __builtin_amdgcn_mfma_f32_16x16x32_bf16(aKV, bk, accK[c], 0, 0, 0);
                bfx8 bv = rd(stW, 128 + c * 16 + lr);
                accV[c] = __builtin_amdgcn_mfma_f32_16x16x32_bf16(aKV, bv, accV[c], 0, 0, 0);
                if (wv >= 4) {
                    bfx8 bq = rd(stW, c * 16 + lr);
                    accQ[c] = __builtin_amdgcn_mfma_f32_16x16x32_bf16(aQ, bq, accQ[c], 0, 0, 0);
                }
            }
            __builtin_amdgcn_s_setprio(0);
        }
    }
    unsigned short* sQ  = (unsigned short*)(lds + 2 * BUFB);
    unsigned short* sK  = (unsigned short*)(lds + 2 * BUFB + 9216);
    unsigned short* sVt = (unsigned short*)(lds + 2 * BUFB + 9216 + 18432);
    float* zp = (float*)(lds + 2 * BUFB + 9216 + 18432 + 17408);
    unsigned short* sP  = (unsigned short*)lds;
#pragma unroll
    for (int c = 0; c < 4; ++c) {
        int col = c * 16 + lr;
        float bk_ = bias[512 + h * 64 + col];
        float bv_ = bias[1024 + h * 64 + col];
#pragma unroll
        for (int r = 0; r < 4; ++r) {
            sK[(wv * 16 + rloc + r) * 72 + col] = f2bf(accK[c][r] + bk_);
            sVt[col * 136 + (wv * 16 + rloc + r)] = f2bf(accV[c][r] + bv_);
        }
        if (wv >= 4) {
            float bq_ = bias[h * 64 + col];
#pragma unroll
            for (int r = 0; r < 4; ++r)
                sQ[((wv - 4) * 16 + rloc + r) * 72 + col] = f2bf(accQ[c][r] + bq_);
        }
    }
    __syncthreads();
    const int qb = wv >> 1;
    const int kh = wv & 1;
    fx4 acc[4];
#pragma unroll
    for (int n = 0; n < 4; ++n) acc[n] = fx4{0.f, 0.f, 0.f, 0.f};
#pragma unroll
    for (int kk = 0; kk < 2; ++kk) {
        bfx8 a = *(const bfx8*)(sQ + (qb * 16 + lr) * 72 + kk * 32 + hg8);
#pragma unroll
        for (int n = 0; n < 4; ++n) {
            bfx8 bb = *(const bfx8*)(sK + ((kh * 4 + n) * 16 + lr) * 72 + kk * 32 + hg8);
            acc[n] = __builtin_amdgcn_mfma_f32_16x16x32_bf16(a, bb, acc[n], 0, 0, 0);
        }
    }
    const int qg = q0 + qb * 16 + rloc;
#pragma unroll
    for (int r = 0; r < 4; ++r) {
        float zs = 0.f;
#pragma unroll
        for (int n = 0; n < 4; ++n) {
            float s = acc[n][r] * 0.125f;
            s = __expf(fminf(fmaxf(s, -5.f), 5.f));
            if (CAUSAL && (kh * 64 + n * 16 + lr) > (qg + r)) s = 0.f;
            zs += s;
            sP[(qb * 16 + rloc + r) * 136 + kh * 64 + n * 16 + lr] = f2bf(s);
        }
#pragma unroll
        for (int off = 8; off; off >>= 1) zs += __shfl_xor(zs, off);
        if (lr == 0) zp[(qb * 2 + kh) * 16 + rloc + r] = zs;
    }
    __syncthreads();
    float zinv[4];
#pragma unroll
    for (int r = 0; r < 4; ++r)
        zinv[r] = 1.f / (zp[(qb * 2 + 0) * 16 + rloc + r] + zp[(qb * 2 + 1) * 16 + rloc + r]);
    const int dh = wv & 1;
    fx4 acc2[2];
    acc2[0] = fx4{0.f, 0.f, 0.f, 0.f};
    acc2[1] = fx4{0.f, 0.f, 0.f, 0.f};
#pragma unroll
    for (int kk = 0; kk < 4; ++kk) {
        bfx8 a = *(const bfx8*)(sP + (qb * 16 + lr) * 136 + kk * 32 + hg8);
#pragma unroll
        for (int dn = 0; dn < 2; ++dn) {
            bfx8 bb = *(const bfx8*)(sVt + (dh * 32 + dn * 16 + lr) * 136 + kk * 32 + hg8);
            acc2[dn] = __builtin_amdgcn_mfma_f32_16x16x32_bf16(a, bb, acc2[dn], 0, 0, 0);
        }
    }
#pragma unroll
    for (int dn = 0; dn < 2; ++dn)
#pragma unroll
        for (int r = 0; r < 4; ++r) {
            size_t row = (size_t)(b * 128 + qg + r);
            out[row * 512 + h * 64 + dh * 32 + dn * 16 + lr] = f2bf(acc2[dn][r] * zinv[r]);
        }
}

// ---------------- log_softmax: bf16 logits [2048,8192] -> f32 out ----------------
__global__ __launch_bounds__(256) void logsoftmax_bf16_kernel(
    const unsigned short* __restrict__ logits, float* __restrict__ out)
{
    __shared__ float red[4];
    int tid = threadIdx.x;
    const bfx8* lrow = (const bfx8*)(logits + (size_t)blockIdx.x * 8192);
    float* orow = out + (size_t)blockIdx.x * 8192;
    float vals[32];
    float mx = -1e30f;
#pragma unroll
    for (int i = 0; i < 4; ++i) {
        bfx8 u = lrow[i * 256 + tid];
#pragma unroll
        for (int j = 0; j < 8; ++j) {
            float f = bf2f((unsigned short)u[j]);
            vals[i * 8 + j] = f;
            mx = fmaxf(mx, f);
        }
    }
#pragma unroll
    for (int off = 32; off; off >>= 1) mx = fmaxf(mx, __shfl_xor(mx, off));
    int wid = tid >> 6;
    if ((tid & 63) == 0) red[wid] = mx;
    __syncthreads();
    mx = fmaxf(fmaxf(red[0], red[1]), fmaxf(red[2], red[3]));
    __syncthreads();
    float sum = 0.f;
#pragma unroll
    for (int i = 0; i < 32; ++i) sum += __expf(vals[i] - mx);
#pragma unroll
    for (int off = 32; off; off >>= 1) sum += __shfl_xor(sum, off);
    if ((tid & 63) == 0) red[wid] = sum;
    __syncthreads();
    sum = red[0] + red[1] + red[2] + red[3];
    float lsub = mx + logf(sum);
#pragma unroll
    for (int i = 0; i < 4; ++i) {
        fx4 o0, o1;
#pragma unroll
        for (int j = 0; j < 4; ++j) {
            o0[j] = vals[i * 8 + j] - lsub;
            o1[j] = vals[i * 8 + 4 + j] - lsub;
        }
        ((fx4*)orow)[(i * 256 + tid) * 2] = o0;
        ((fx4*)orow)[(i * 256 + tid) * 2 + 1] = o1;
    }
}

extern "C" void kernel_launch(void* const* d_in, const int* in_sizes, int n_in,
                              void* d_out, int out_size, void* d_ws, size_t ws_size,
                              hipStream_t stream) {
    (void)in_sizes; (void)n_in; (void)out_size; (void)ws_size;
    const int* src_tokens = (const int*)d_in[0];
    const int* tgt_tokens = (const int*)d_in[1];
    const float* src_emb    = (const float*)d_in[8];
    const float* tgt_emb    = (const float*)d_in[9];
    const float* enc_attn_W = (const float*)d_in[10];
    const float* enc_attn_b = (const float*)d_in[11];
    const float* enc_ln_g   = (const float*)d_in[12];
    const float* enc_ln_b   = (const float*)d_in[13];
    const float* enc_ff_W1  = (const float*)d_in[14];
    const float* enc_ff_b1  = (const float*)d_in[15];
    const float* enc_ff_W2  = (const float*)d_in[16];
    const float* enc_ff_b2  = (const float*)d_in[17];
    const float* enc_norm_g = (const float*)d_in[18];
    const float* enc_norm_b = (const float*)d_in[19];
    const float* dec_self_W = (const float*)d_in[20];
    const float* dec_self_b = (const float*)d_in[21];
    const float* dec_cross_W= (const float*)d_in[22];
    const float* dec_cross_b= (const float*)d_in[23];
    const float* dec_ln_g   = (const float*)d_in[24];
    const float* dec_ln_b   = (const float*)d_in[25];
    const float* dec_ff_W1  = (const float*)d_in[26];
    const float* dec_ff_b1  = (const float*)d_in[27];
    const float* dec_ff_W2  = (const float*)d_in[28];
    const float* dec_ff_b2  = (const float*)d_in[29];
    const float* dec_norm_g = (const float*)d_in[30];
    const float* dec_norm_b = (const float*)d_in[31];
    const float* gen_W      = (const float*)d_in[32];
    const float* gen_b      = (const float*)d_in[33];
    float* dout = (float*)d_out;

    // ---- workspace layout ----
    unsigned short* wt = (unsigned short*)d_ws;
    const size_t OFF_ENCQKV = 0;
    const size_t OFF_ENCO   = 1572864;
    const size_t OFF_ENCW1  = 2097152;
    const size_t OFF_ENCW2  = 4194304;
    const size_t OFF_DECSQKV= 6291456;
    const size_t OFF_DECSO  = 7864320;
    const size_t OFF_DECCQKV= 8388608;
    const size_t OFF_DECCO  = 9961472;
    const size_t OFF_DECW1  = 10485760;
    const size_t OFF_DECW2  = 12582912;
    const size_t OFF_GENW   = 14680064;
    const size_t WT_ELEMS   = 18874368;
    float* fb  = (float*)(wt + WT_ELEMS);
    float* xe  = fb;
    float* xd  = fb + 1048576;
    unsigned short* nxb   = (unsigned short*)(fb + 2097152);
    unsigned short* nxd0  = (unsigned short*)(fb + 3145728);
    unsigned short* ffb   = (unsigned short*)(fb + 4194304);  // [2048,2048] bf16
    unsigned short* nkvb0 = (unsigned short*)(fb + 6291456);  // [2048,512] bf16
    unsigned short* nkvb1 = (unsigned short*)(fb + 6815744);  // [2048,512] bf16
    unsigned short* attb  = (unsigned short*)(fb + 7340032);  // [2048,512] bf16
    unsigned short* genin   = (unsigned short*)fb;             // aliases xe (dead)
    unsigned short* logitsb = (unsigned short*)(fb + 1048576); // aliases xd.. (dead)

    // ---- single-launch weight prep ----
    TrTable tt;
    {
        int z = 0, gi = 0;
        auto addg = [&](const float* s, unsigned short* d, int srs, int drs,
                        long so, long dof, int zc) {
            tt.zStart[gi] = z;
            tt.g[gi].src = s; tt.g[gi].dst = d;
            tt.g[gi].srcRowStride = srs; tt.g[gi].dstRowStride = drs;
            tt.g[gi].srcSliceOff = so; tt.g[gi].dstSliceOff = dof;
            ++gi; z += zc;
        };
        addg(enc_attn_W,              wt + OFF_ENCQKV,               512,  512,  262144,    262144, 3);
        addg(enc_attn_W + 4L*262144,  wt + OFF_ENCQKV + 3L*262144,   512,  512,  262144,    262144, 3);
        addg(enc_attn_W + 3L*262144,  wt + OFF_ENCO,                 512,  512,  4L*262144, 262144, 2);
        addg(enc_ff_W1,               wt + OFF_ENCW1,                2048, 512,  512,       262144, 4);
        addg(enc_ff_W1 + 1048576,     wt + OFF_ENCW1 + 1048576,      2048, 512,  512,       262144, 4);
        addg(enc_ff_W2,               wt + OFF_ENCW2,                512,  2048, 262144,    512,    4);
        addg(enc_ff_W2 + 1048576,     wt + OFF_ENCW2 + 1048576,      512,  2048, 262144,    512,    4);
        addg(dec_self_W,              wt + OFF_DECSQKV,              512,  512,  262144,    262144, 3);
        addg(dec_self_W + 4L*262144,  wt + OFF_DECSQKV + 3L*262144,  512,  512,  262144,    262144, 3);
        addg(dec_self_W + 3L*262144,  wt + OFF_DECSO,                512,  512,  4L*262144, 262144, 2);
        addg(dec_cross_W,             wt + OFF_DECCQKV,              512,  512,  262144,    262144, 3);
        addg(dec_cross_W + 4L*262144, wt + OFF_DECCQKV + 3L*262144,  512,  512,  262144,    262144, 3);
        addg(dec_cross_W + 3L*262144, wt + OFF_DECCO,                512,  512,  4L*262144, 262144, 2);
        addg(dec_ff_W1,               wt + OFF_DECW1,                2048, 512,  512,       262144, 4);
        addg(dec_ff_W1 + 1048576,     wt + OFF_DECW1 + 1048576,      2048, 512,  512,       262144, 4);
        addg(dec_ff_W2,               wt + OFF_DECW2,                512,  2048, 262144,    512,    4);
        addg(dec_ff_W2 + 1048576,     wt + OFF_DECW2 + 1048576,      512,  2048, 262144,    512,    4);
        addg(gen_W,                   wt + OFF_GENW,                 8192, 512,  512,       262144, 16);
        tt.zStart[18] = z;  // 72
    }
    trall_kernel<<<dim3(16, 16, 72), 256, 0, stream>>>(tt);

    // ---- embeddings + first LN (enc layer-0 -> nxb, dec layer-0 -> nxd0) ----
    embedln_kernel<<<4096, 256, 0, stream>>>(
        src_tokens, tgt_tokens, src_emb, tgt_emb, xe, xd,
        enc_ln_g, enc_ln_b, dec_ln_g, dec_ln_b, nxb, nxd0);

    auto gemmK = [&](const unsigned short* A, const unsigned short* W, const float* bias,
                     const float* res, void* C, int N, int K, int ldc, bool relu, bool outbf) {
        int gx = N / 64;
        dim3 g(gx * 32);
        if (res)        gemm_bk128_kernel<false, true,  false><<<g, 256, 0, stream>>>(A, W, bias, res, C, K, ldc, gx);
        else if (relu)  gemm_bk128_kernel<true,  false, true ><<<g, 256, 0, stream>>>(A, W, bias, res, C, K, ldc, gx);
        else if (outbf) gemm_bk128_kernel<false, false, true ><<<g, 256, 0, stream>>>(A, W, bias, res, C, K, ldc, gx);
        else            gemm_bk128_kernel<false, false, false><<<g, 256, 0, stream>>>(A, W, bias, res, C, K, ldc, gx);
    };
    auto gemm128 = [&](const unsigned short* A, const unsigned short* W, const float* bias,
                       unsigned short* C, int N, int K, int ldc, bool relu) {
        dim3 g((N / 128) * 16);
        if (relu) gemm128_kernel<true ><<<g, 256, 0, stream>>>(A, W, bias, C, K, ldc);
        else      gemm128_kernel<false><<<g, 256, 0, stream>>>(A, W, bias, C, K, ldc);
    };
    auto lnb = [&](const float* x, const float* g, const float* b, unsigned short* o) {
        ln_kernel<true><<<512, 256, 0, stream>>>(x, g, b, o);
    };

    // ---- encoder ----
    for (int i = 0; i < 2; ++i) {
        if (i) lnb(xe, enc_ln_g + (size_t)(i * 2) * 512, enc_ln_b + (size_t)(i * 2) * 512, nxb);
        fattn_kernel<false, true><<<256, 512, 0, stream>>>(
            nxb, nxb, wt + OFF_ENCQKV + (size_t)i * 3 * 262144,
            enc_attn_b + (size_t)i * 4 * 512, attb);
        gemmK(attb, wt + OFF_ENCO + (size_t)i * 262144, enc_attn_b + (size_t)i * 4 * 512 + 1536,
              xe, xe, 512, 512, 512, false, false);
        lnb(xe, enc_ln_g + (size_t)(i * 2 + 1) * 512, enc_ln_b + (size_t)(i * 2 + 1) * 512, nxb);
        gemm128(nxb, wt + OFF_ENCW1 + (size_t)i * 1048576, enc_ff_b1 + (size_t)i * 2048,
                ffb, 2048, 512, 2048, true);
        gemmK(ffb, wt + OFF_ENCW2 + (size_t)i * 1048576, enc_ff_b2 + (size_t)i * 512,
              xe, xe, 512, 2048, 512, false, false);
    }
    // final enc norm + both decoder cross-LN(xe) precomputed
    ln3_kernel<<<512, 256, 0, stream>>>(
        xe, enc_norm_g, enc_norm_b,
        dec_ln_g + 512, dec_ln_b + 512,          // (0*3+1)
        dec_ln_g + 4 * 512, dec_ln_b + 4 * 512,  // (1*3+1)
        nkvb0, nkvb1);

    // ---- decoder ----
    for (int i = 0; i < 2; ++i) {
        const unsigned short* qsrc = (i == 0) ? nxd0 : nxb;
        if (i) lnb(xd, dec_ln_g + (size_t)(i * 3) * 512, dec_ln_b + (size_t)(i * 3) * 512, nxb);
        fattn_kernel<true, true><<<256, 512, 0, stream>>>(
            qsrc, qsrc, wt + OFF_DECSQKV + (size_t)i * 3 * 262144,
            dec_self_b + (size_t)i * 4 * 512, attb);
        gemmK(attb, wt + OFF_DECSO + (size_t)i * 262144, dec_self_b + (size_t)i * 4 * 512 + 1536,
              xd, xd, 512, 512, 512, false, false);
        lnb(xd, dec_ln_g + (size_t)(i * 3 + 1) * 512, dec_ln_b + (size_t)(i * 3 + 1) * 512, nxb);
        fattn_kernel<false, false><<<256, 512, 0, stream>>>(
            nxb, i ? nkvb1 : nkvb0, wt + OFF_DECCQKV + (size_t)i * 3 * 262144,
            dec_cross_b + (size_t)i * 4 * 512, attb);
        gemmK(attb, wt + OFF_DECCO + (size_t)i * 262144, dec_cross_b + (size_t)i * 4 * 512 + 1536,
              xd, xd, 512, 512, 512, false, false);
        lnb(xd, dec_ln_g + (size_t)(i * 3 + 2) * 512, dec_ln_b + (size_t)(i * 3 + 2) * 512, nxb);
        gemm128(nxb, wt + OFF_DECW1 + (size_t)i * 1048576, dec_ff_b1 + (size_t)i * 2048,
                ffb, 2048, 512, 2048, true);
        gemmK(ffb, wt + OFF_DECW2 + (size_t)i * 1048576, dec_ff_b2 + (size_t)i * 512,
              xd, xd, 512, 2048, 512, false, false);
    }
    lnb(xd, dec_norm_g, dec_norm_b, genin);

    // ---- generator + log_softmax ----
    gemm128(genin, wt + OFF_GENW, gen_b, logitsb, 8192, 512, 8192, false);
    logsoftmax_bf16_kernel<<<2048, 256, 0, stream>>>(logitsb, dout);
}

// Round 11
// 307.059 us; speedup vs baseline: 1.3291x; 1.0746x over previous
//
#include <hip/hip_runtime.h>

typedef __attribute__((ext_vector_type(8))) short bfx8;
typedef __attribute__((ext_vector_type(4))) float fx4;

static __device__ __forceinline__ unsigned short f2bf(float f) {
    union { float f; unsigned int u; } v; v.f = f;
    unsigned int i = v.u;
    return (unsigned short)((i + 0x7FFFu + ((i >> 16) & 1u)) >> 16);
}
static __device__ __forceinline__ float bf2f(unsigned short u) {
    union { unsigned int ui; float f; } cv;
    cv.ui = ((unsigned int)u) << 16;
    return cv.f;
}

// async global->LDS, 16B per lane; l is the WAVE-UNIFORM base (HW adds lane*16)
static __device__ __forceinline__ void gl2lds16(const unsigned short* g, unsigned short* l) {
    unsigned long long gu = (unsigned long long)g;
    unsigned int lu = (unsigned int)(unsigned long long)l;
    __builtin_amdgcn_global_load_lds(
        (const __attribute__((address_space(1))) void*)gu,
        (__attribute__((address_space(3))) void*)lu,
        16, 0, 0);
}

// ---------------- fused prep: 72 transpose slices + 16 embed slices ----------------
struct TrGroup {
    const float* src;
    unsigned short* dst;
    int srcRowStride;
    int dstRowStride;
    long srcSliceOff;
    long dstSliceOff;
};
struct TrTable {
    TrGroup g[18];
    int zStart[19];
};

__global__ __launch_bounds__(256) void prep_kernel(
    TrTable tt,
    const int* __restrict__ tokA, const int* __restrict__ tokB,
    const float* __restrict__ embA, const float* __restrict__ embB,
    float* __restrict__ outA, float* __restrict__ outB,
    const float* __restrict__ gA, const float* __restrict__ bA,
    const float* __restrict__ gB, const float* __restrict__ bB,
    unsigned short* __restrict__ nxA, unsigned short* __restrict__ nxB)
{
    __shared__ unsigned short tile[32][33];
    __shared__ float red[4];
    int z = blockIdx.z;
    if (z < 72) {
        // ---- weight transpose f32 [K,N] -> bf16 [N,K] ----
        int gi = 0;
#pragma unroll 1
        while (z >= tt.zStart[gi + 1]) ++gi;
        int zi = z - tt.zStart[gi];
        const float* s = tt.g[gi].src + (size_t)zi * tt.g[gi].srcSliceOff;
        unsigned short* d = tt.g[gi].dst + (size_t)zi * tt.g[gi].dstSliceOff;
        int srs = tt.g[gi].srcRowStride, drs = tt.g[gi].dstRowStride;
        int n0 = blockIdx.x * 32, k0 = blockIdx.y * 32;
        int tx = threadIdx.x & 31, ty = threadIdx.x >> 5;
#pragma unroll
        for (int i = 0; i < 32; i += 8)
            tile[ty + i][tx] = f2bf(s[(size_t)(k0 + ty + i) * srs + (n0 + tx)]);
        __syncthreads();
#pragma unroll
        for (int i = 0; i < 32; i += 8)
            d[(size_t)(n0 + ty + i) * drs + (k0 + tx)] = tile[tx][ty + i];
        return;
    }
    // ---- embeddings + PE + first LN ----
    int e = (z - 72) * 256 + blockIdx.y * 16 + blockIdx.x;   // 0..4095
    int row = e & 2047;
    bool isA = e < 2048;
    const int* tok = isA ? tokA : tokB;
    const float* emb = isA ? embA : embB;
    float* out = isA ? outA : outB;
    const float* g = isA ? gA : gB;
    const float* bb = isA ? bA : bB;
    unsigned short* nx = isA ? nxA : nxB;
    int pos = row & 127;
    int t = tok[row];
    int d0 = threadIdx.x, d1 = threadIdx.x + 256;
    auto pe = [&](int d) {
        float ang = (float)pos * expf((float)(d & ~1) * (-9.210340371976184f / 512.0f));
        return (d & 1) ? cosf(ang) : sinf(ang);
    };
    float v0 = emb[(size_t)t * 512 + d0] * 22.627416997969522f + pe(d0);
    float v1 = emb[(size_t)t * 512 + d1] * 22.627416997969522f + pe(d1);
    out[(size_t)row * 512 + d0] = v0;
    out[(size_t)row * 512 + d1] = v1;
    int lane = threadIdx.x & 63, wv = threadIdx.x >> 6;
    float s = v0 + v1;
#pragma unroll
    for (int off = 32; off; off >>= 1) s += __shfl_xor(s, off);
    if (lane == 0) red[wv] = s;
    __syncthreads();
    float mu = (red[0] + red[1] + red[2] + red[3]) * (1.0f / 512.0f);
    __syncthreads();
    float q = (v0 - mu) * (v0 - mu) + (v1 - mu) * (v1 - mu);
#pragma unroll
    for (int off = 32; off; off >>= 1) q += __shfl_xor(q, off);
    if (lane == 0) red[wv] = q;
    __syncthreads();
    float rs = rsqrtf((red[0] + red[1] + red[2] + red[3]) * (1.0f / 512.0f) + 1e-5f);
    nx[(size_t)row * 512 + d0] = f2bf(g[d0] * (v0 - mu) * rs + bb[d0]);
    nx[(size_t)row * 512 + d1] = f2bf(g[d1] * (v1 - mu) * rs + bb[d1]);
}

// ---------------- layernorm row body (D=512, one wave) ----------------
static __device__ __forceinline__ void ln_row(
    const float* __restrict__ xrow, const float* __restrict__ g,
    const float* __restrict__ b, int lane, fx4& o0, fx4& o1)
{
    const fx4* xr = (const fx4*)xrow;
    fx4 a = xr[lane * 2], c = xr[lane * 2 + 1];
    float s = a[0] + a[1] + a[2] + a[3] + c[0] + c[1] + c[2] + c[3];
#pragma unroll
    for (int off = 32; off; off >>= 1) s += __shfl_xor(s, off);
    float mu = s * (1.0f / 512.0f);
    float qv = 0.f;
#pragma unroll
    for (int j = 0; j < 4; ++j) {
        float d0 = a[j] - mu; qv += d0 * d0;
        float d1 = c[j] - mu; qv += d1 * d1;
    }
#pragma unroll
    for (int off = 32; off; off >>= 1) qv += __shfl_xor(qv, off);
    float rs = rsqrtf(qv * (1.0f / 512.0f) + 1e-5f);
    const fx4* gr = (const fx4*)g;
    const fx4* br = (const fx4*)b;
    fx4 g0 = gr[lane * 2], g1 = gr[lane * 2 + 1];
    fx4 b0 = br[lane * 2], b1 = br[lane * 2 + 1];
#pragma unroll
    for (int j = 0; j < 4; ++j) {
        o0[j] = g0[j] * (a[j] - mu) * rs + b0[j];
        o1[j] = g1[j] * (c[j] - mu) * rs + b1[j];
    }
}

template<bool OUTBF>
__global__ __launch_bounds__(256) void ln_kernel(
    const float* __restrict__ x, const float* __restrict__ g,
    const float* __restrict__ b, void* __restrict__ out)
{
    int row = blockIdx.x * 4 + (threadIdx.x >> 6);
    int lane = threadIdx.x & 63;
    fx4 o0, o1;
    ln_row(x + (size_t)row * 512, g, b, lane, o0, o1);
    if (OUTBF) {
        unsigned short* orow = (unsigned short*)out + (size_t)row * 512 + lane * 8;
        ushort4 u0 = {f2bf(o0[0]), f2bf(o0[1]), f2bf(o0[2]), f2bf(o0[3])};
        ushort4 u1 = {f2bf(o1[0]), f2bf(o1[1]), f2bf(o1[2]), f2bf(o1[3])};
        *(ushort4*)orow = u0;
        *(ushort4*)(orow + 4) = u1;
    } else {
        fx4* orow = (fx4*)out + (size_t)row * 128;
        orow[lane * 2] = o0;
        orow[lane * 2 + 1] = o1;
    }
}

// fused: xe = LN(xe, enc_norm); nk0 = LN(xe', dec l0); nk1 = LN(xe', dec l1)
__global__ __launch_bounds__(256) void ln3_kernel(
    float* __restrict__ xe, const float* __restrict__ eg, const float* __restrict__ eb,
    const float* __restrict__ g0, const float* __restrict__ b0,
    const float* __restrict__ g1, const float* __restrict__ b1,
    unsigned short* __restrict__ nk0, unsigned short* __restrict__ nk1)
{
    int row = blockIdx.x * 4 + (threadIdx.x >> 6);
    int lane = threadIdx.x & 63;
    fx4 t0, t1;
    ln_row(xe + (size_t)row * 512, eg, eb, lane, t0, t1);
    fx4* orow = (fx4*)(xe + (size_t)row * 512);
    orow[lane * 2] = t0;
    orow[lane * 2 + 1] = t1;
    float s = t0[0] + t0[1] + t0[2] + t0[3] + t1[0] + t1[1] + t1[2] + t1[3];
#pragma unroll
    for (int off = 32; off; off >>= 1) s += __shfl_xor(s, off);
    float mu = s * (1.0f / 512.0f);
    float q = 0.f;
#pragma unroll
    for (int j = 0; j < 4; ++j) {
        float a = t0[j] - mu; q += a * a;
        float c = t1[j] - mu; q += c * c;
    }
#pragma unroll
    for (int off = 32; off; off >>= 1) q += __shfl_xor(q, off);
    float rs = rsqrtf(q * (1.0f / 512.0f) + 1e-5f);
    const fx4* g0r = (const fx4*)g0; const fx4* b0r = (const fx4*)b0;
    const fx4* g1r = (const fx4*)g1; const fx4* b1r = (const fx4*)b1;
    fx4 ga0 = g0r[lane * 2], ga1 = g0r[lane * 2 + 1];
    fx4 bb0 = b0r[lane * 2], bb1 = b0r[lane * 2 + 1];
    fx4 gc0 = g1r[lane * 2], gc1 = g1r[lane * 2 + 1];
    fx4 bc0 = b1r[lane * 2], bc1 = b1r[lane * 2 + 1];
    unsigned short* o0 = nk0 + (size_t)row * 512 + lane * 8;
    unsigned short* o1 = nk1 + (size_t)row * 512 + lane * 8;
    ushort4 ua0, ua1, uc0, uc1;
#pragma unroll
    for (int j = 0; j < 4; ++j) {
        float n0 = (t0[j] - mu) * rs, n1 = (t1[j] - mu) * rs;
        ((unsigned short*)&ua0)[j] = f2bf(ga0[j] * n0 + bb0[j]);
        ((unsigned short*)&ua1)[j] = f2bf(ga1[j] * n1 + bb1[j]);
        ((unsigned short*)&uc0)[j] = f2bf(gc0[j] * n0 + bc0[j]);
        ((unsigned short*)&uc1)[j] = f2bf(gc1[j] * n1 + bc1[j]);
    }
    *(ushort4*)o0 = ua0; *(ushort4*)(o0 + 4) = ua1;
    *(ushort4*)o1 = uc0; *(ushort4*)(o1 + 4) = uc1;
}

// ---------------- bf16 MFMA GEMM, 64x64 tile, BK=128 ----------------
template<bool RELU, bool RESID, bool OUTBF>
__global__ __launch_bounds__(256) void gemm_bk128_kernel(
    const unsigned short* __restrict__ A, const unsigned short* __restrict__ Wt,
    const float* __restrict__ bias, const float* __restrict__ res,
    void* __restrict__ Cv, int K, int ldc, int gx)
{
    __shared__ unsigned short smem[2][2][8192];  // [buf][A/B][64*128]
    const int tid = threadIdx.x;
    const int nwg = gridDim.x;
    const int cpx = nwg >> 3;
    const int phys = blockIdx.x;
    const int logical = (phys & 7) * cpx + (phys >> 3);
    const int bm = (logical / gx) * 64;
    const int bn = (logical % gx) * 64;
    const int lane = tid & 63;
    const int wv = tid >> 6;
    const int wr = (wv >> 1) * 32;
    const int wc = (wv & 1) * 32;
    const int lr = lane & 15;
    const int lrow4 = lane >> 4;
    const int lchk16 = lane & 15;
    fx4 acc00 = {0.f, 0.f, 0.f, 0.f}, acc01 = {0.f, 0.f, 0.f, 0.f};
    fx4 acc10 = {0.f, 0.f, 0.f, 0.f}, acc11 = {0.f, 0.f, 0.f, 0.f};

    auto stage = [&](int buf, int k0) {
#pragma unroll
        for (int j = 0; j < 4; ++j) {
            int row = wv * 16 + j * 4 + lrow4;
            int sc = (lchk16 ^ (row & 15)) * 8;
            gl2lds16(A + (size_t)(bm + row) * K + k0 + sc,
                     &smem[buf][0][(wv * 16 + j * 4) * 128]);
            gl2lds16(Wt + (size_t)(bn + row) * K + k0 + sc,
                     &smem[buf][1][(wv * 16 + j * 4) * 128]);
        }
    };

    const int nt = K >> 7;
    int cur = 0;
    stage(0, 0);
    for (int t = 0; t < nt; ++t) {
        __syncthreads();
        if (t + 1 < nt) stage(cur ^ 1, (t + 1) << 7);
        const unsigned short* bufA = &smem[cur][0][0];
        const unsigned short* bufB = &smem[cur][1][0];
        const int ra0 = wr + lr, ra1 = wr + 16 + lr;
        const int rb0 = wc + lr, rb1 = wc + 16 + lr;
        __builtin_amdgcn_s_setprio(1);
#pragma unroll
        for (int kk = 0; kk < 4; ++kk) {
            int ca = kk * 4 + (lane >> 4);
            bfx8 a0 = *(const bfx8*)&bufA[ra0 * 128 + ((ca ^ (ra0 & 15)) * 8)];
            bfx8 a1 = *(const bfx8*)&bufA[ra1 * 128 + ((ca ^ (ra1 & 15)) * 8)];
            bfx8 b0 = *(const bfx8*)&bufB[rb0 * 128 + ((ca ^ (rb0 & 15)) * 8)];
            bfx8 b1 = *(const bfx8*)&bufB[rb1 * 128 + ((ca ^ (rb1 & 15)) * 8)];
            acc00 = __builtin_amdgcn_mfma_f32_16x16x32_bf16(a0, b0, acc00, 0, 0, 0);
            acc01 = __builtin_amdgcn_mfma_f32_16x16x32_bf16(a0, b1, acc01, 0, 0, 0);
            acc10 = __builtin_amdgcn_mfma_f32_16x16x32_bf16(a1, b0, acc10, 0, 0, 0);
            acc11 = __builtin_amdgcn_mfma_f32_16x16x32_bf16(a1, b1, acc11, 0, 0, 0);
        }
        __builtin_amdgcn_s_setprio(0);
        cur ^= 1;
    }
    int rbase = bm + wr + ((lane >> 4) * 4);
    int cbase = bn + wc + lr;
#pragma unroll
    for (int m = 0; m < 2; ++m) {
        fx4 am0 = m ? acc10 : acc00;
        fx4 am1 = m ? acc11 : acc01;
#pragma unroll
        for (int r = 0; r < 4; ++r) {
            int row = rbase + m * 16 + r;
#pragma unroll
            for (int half = 0; half < 2; ++half) {
                int col = cbase + half * 16;
                float v = (half ? am1[r] : am0[r]) + bias[col];
                if (RESID) v += res[(size_t)row * ldc + col];
                if (RELU) v = fmaxf(v, 0.f);
                if (OUTBF) ((unsigned short*)Cv)[(size_t)row * ldc + col] = f2bf(v);
                else       ((float*)Cv)[(size_t)row * ldc + col] = v;
            }
        }
    }
}

// ---------------- bf16 MFMA GEMM, 128x128 tile (4 waves x 64x64), bf16 out ----------------
template<bool RELU>
__global__ __launch_bounds__(256) void gemm128_kernel(
    const unsigned short* __restrict__ A, const unsigned short* __restrict__ Wt,
    const float* __restrict__ bias, unsigned short* __restrict__ C,
    int K, int ldc)
{
    __shared__ unsigned short smem[2][2][8192];  // [buf][A/B][128*64]
    const int tid = threadIdx.x;
    const int nwg = gridDim.x;
    const int cpx = nwg >> 3;
    const int phys = blockIdx.x;
    const int logical = (phys & 7) * cpx + (phys >> 3);
    const int bm = (logical & 15) * 128;     // M = 2048 always
    const int bn = (logical >> 4) * 128;
    const int lane = tid & 63;
    const int wv = tid >> 6;
    const int wr = (wv >> 1) * 64;
    const int wc = (wv & 1) * 64;
    const int lr = lane & 15;
    const int lrow = lane >> 3;
    const int lchk = lane & 7;
    fx4 acc[4][4];
#pragma unroll
    for (int mi = 0; mi < 4; ++mi)
#pragma unroll
        for (int ni = 0; ni < 4; ++ni) acc[mi][ni] = fx4{0.f, 0.f, 0.f, 0.f};

    auto stage = [&](int buf, int k0) {
#pragma unroll
        for (int j = 0; j < 4; ++j) {
            int row = wv * 32 + j * 8 + lrow;
            int sc = lchk ^ (row & 7);
            gl2lds16(A + (size_t)(bm + row) * K + k0 + sc * 8,
                     &smem[buf][0][(wv * 32 + j * 8) * 64]);
            gl2lds16(Wt + (size_t)(bn + row) * K + k0 + sc * 8,
                     &smem[buf][1][(wv * 32 + j * 8) * 64]);
        }
    };

    const int nt = K >> 6;
    int cur = 0;
    stage(0, 0);
    for (int t = 0; t < nt; ++t) {
        __syncthreads();
        if (t + 1 < nt) stage(cur ^ 1, (t + 1) << 6);
        const unsigned short* bufA = &smem[cur][0][0];
        const unsigned short* bufB = &smem[cur][1][0];
        __builtin_amdgcn_s_setprio(1);
#pragma unroll
        for (int kk = 0; kk < 2; ++kk) {
            int ca = kk * 4 + (lane >> 4);
            bfx8 af[4], bg[4];
#pragma unroll
            for (int i = 0; i < 4; ++i) {
                int ra = wr + i * 16 + lr;
                int rb = wc + i * 16 + lr;
                af[i] = *(const bfx8*)&bufA[ra * 64 + ((ca ^ (ra & 7)) * 8)];
                bg[i] = *(const bfx8*)&bufB[rb * 64 + ((ca ^ (rb & 7)) * 8)];
            }
#pragma unroll
            for (int mi = 0; mi < 4; ++mi)
#pragma unroll
                for (int ni = 0; ni < 4; ++ni)
                    acc[mi][ni] = __builtin_amdgcn_mfma_f32_16x16x32_bf16(af[mi], bg[ni], acc[mi][ni], 0, 0, 0);
        }
        __builtin_amdgcn_s_setprio(0);
        cur ^= 1;
    }
    int rbase = bm + wr + ((lane >> 4) * 4);
    int cbase = bn + wc + lr;
#pragma unroll
    for (int mi = 0; mi < 4; ++mi)
#pragma unroll
        for (int ni = 0; ni < 4; ++ni) {
            int col = cbase + ni * 16;
            float bv = bias[col];
#pragma unroll
            for (int r = 0; r < 4; ++r) {
                int row = rbase + mi * 16 + r;
                float v = acc[mi][ni][r] + bv;
                if (RELU) v = fmaxf(v, 0.f);
                C[(size_t)row * ldc + col] = f2bf(v);
            }
        }
}

// ---------------- fused QKV-projection + attention (8 waves, region-pure proj) ----------------
// Proj wave roles: wv0: K rows 0-63, wv1: K 64-127, wv2: V 0-63, wv3: V 64-127, wv4: Q 0-63,
// wv5-7: stage-only. Each busy wave: 4 row-blocks x 4 col-blocks -> 8 ds_reads : 16 MFMA per kk.
template<bool CAUSAL, bool SELF>
__global__ __launch_bounds__(512) void fattn_kernel(
    const unsigned short* __restrict__ xq, const unsigned short* __restrict__ xkv,
    const unsigned short* __restrict__ Wt, const float* __restrict__ bias,
    unsigned short* __restrict__ out)
{
    constexpr int XROWS = SELF ? 128 : 192;
    constexpr int BUFB  = (XROWS + 192) * 64 * 2;
    __shared__ __align__(16) unsigned char lds[2 * BUFB + 9216 + 18432 + 17408 + 512];
    const int blk = blockIdx.x;
    const int half = blk & 1;
    const int h = (blk >> 1) & 7;
    const int b = blk >> 4;
    const int q0 = half * 64;
    const int tid = threadIdx.x;
    const int lane = tid & 63;
    const int wv = tid >> 6;
    const int lr = lane & 15;
    const int hg8 = (lane >> 4) * 8;
    const int rloc = (lane >> 4) * 4;
    const int lrow = lane >> 3;
    const int lchk = lane & 7;

    const unsigned short* gxq = xq + (size_t)(b * 128 + q0) * 512;
    const unsigned short* gkv = xkv + (size_t)(b * 128) * 512;
    const unsigned short* gw  = Wt + (size_t)(h * 64) * 512;

    auto stage = [&](int buf, int k0) {
        unsigned short* dst = (unsigned short*)(lds + buf * BUFB);
        if constexpr (SELF) {
#pragma unroll
            for (int j = 0; j < 5; ++j) {
                int start = wv * 40 + j * 8;
                int row = start + lrow;
                int sc = (lchk ^ (row & 7)) * 8;
                const unsigned short* src;
                if (start < 128) {
                    src = gkv + (size_t)row * 512 + k0 + sc;
                } else {
                    int wr_ = row - 128;
                    src = gw + ((size_t)(wr_ & 63) + (size_t)(wr_ >> 6) * 512) * 512 + k0 + sc;
                }
                gl2lds16(src, dst + start * 64);
            }
        } else {
            unsigned short* dstW = dst + XROWS * 64;
#pragma unroll
            for (int j = 0; j < 3; ++j) {
                int row = wv * 24 + j * 8 + lrow;
                int sc = (lchk ^ (row & 7)) * 8;
                const unsigned short* xs = (row < 64)
                    ? gxq + (size_t)row * 512
                    : gkv + (size_t)(row - 64) * 512;
                gl2lds16(xs + k0 + sc, dst + (wv * 24 + j * 8) * 64);
                const unsigned short* ws = gw + ((size_t)(row & 63) + (size_t)(row >> 6) * 512) * 512;
                gl2lds16(ws + k0 + sc, dstW + (wv * 24 + j * 8) * 64);
            }
        }
    };

    fx4 acc[4][4];
#pragma unroll
    for (int i = 0; i < 4; ++i)
#pragma unroll
        for (int c = 0; c < 4; ++c) acc[i][c] = fx4{0.f, 0.f, 0.f, 0.f};

    // proj A-row base and W-region base (wave-uniform)
    const int arowbase = (wv == 4) ? (SELF ? q0 : 0)
                                   : (SELF ? 0 : 64) + ((wv & 1) * 64);
    const int wbase = (wv == 4) ? 0 : (wv < 2 ? 64 : 128);

    stage(0, 0);
#pragma unroll 1
    for (int t = 0; t < 8; ++t) {
        __syncthreads();
        if (t < 7) stage((t + 1) & 1, (t + 1) * 64);
        const unsigned short* stX = (const unsigned short*)(lds + (t & 1) * BUFB);
        const unsigned short* stW = stX + XROWS * 64;
        if (wv < 5) {
#pragma unroll
            for (int kk = 0; kk < 2; ++kk) {
                const int ca = kk * 4 + (lane >> 4);
                auto rd = [&](const unsigned short* base, int row) -> bfx8 {
                    return *(const bfx8*)(base + row * 64 + ((ca ^ (row & 7)) * 8));
                };
                bfx8 af[4];
#pragma unroll
                for (int i = 0; i < 4; ++i) af[i] = rd(stX, arowbase + i * 16 + lr);
                __builtin_amdgcn_s_setprio(1);
#pragma unroll
                for (int c = 0; c < 4; ++c) {
                    bfx8 bf = rd(stW, wbase + c * 16 + lr);
#pragma unroll
                    for (int i = 0; i < 4; ++i)
                        acc[i][c] = __builtin_amdgcn_mfma_f32_16x16x32_bf16(af[i], bf, acc[i][c], 0, 0, 0);
                }
                __builtin_amdgcn_s_setprio(0);
            }
        }
    }
    unsigned short* sQ  = (unsigned short*)(lds + 2 * BUFB);
    unsigned short* sK  = (unsigned short*)(lds + 2 * BUFB + 9216);
    unsigned short* sVt = (unsigned short*)(lds + 2 * BUFB + 9216 + 18432);
    float* zp = (float*)(lds + 2 * BUFB + 9216 + 18432 + 17408);
    unsigned short* sP  = (unsigned short*)lds;
    // epilogue: D row = rowblock*16 + rloc + r, col = c*16 + lr
    if (wv == 4) {          // Q -> sQ
#pragma unroll
        for (int c = 0; c < 4; ++c) {
            int col = c * 16 + lr;
            float bq_ = bias[h * 64 + col];
#pragma unroll
            for (int i = 0; i < 4; ++i)
#pragma unroll
                for (int r = 0; r < 4; ++r)
                    sQ[(i * 16 + rloc + r) * 72 + col] = f2bf(acc[i][c][r] + bq_);
        }
    } else if (wv < 2) {    // K -> sK
        int rb = wv * 64;
#pragma unroll
        for (int c = 0; c < 4; ++c) {
            int col = c * 16 + lr;
            float bk_ = bias[512 + h * 64 + col];
#pragma unroll
            for (int i = 0; i < 4; ++i)
#pragma unroll
                for (int r = 0; r < 4; ++r)
                    sK[(rb + i * 16 + rloc + r) * 72 + col] = f2bf(acc[i][c][r] + bk_);
        }
    } else if (wv < 4) {    // V -> sVt (transposed)
        int rb = (wv - 2) * 64;
#pragma unroll
        for (int c = 0; c < 4; ++c) {
            int col = c * 16 + lr;
            float bv_ = bias[1024 + h * 64 + col];
#pragma unroll
            for (int i = 0; i < 4; ++i)
#pragma unroll
                for (int r = 0; r < 4; ++r)
                    sVt[col * 136 + (rb + i * 16 + rloc + r)] = f2bf(acc[i][c][r] + bv_);
        }
    }
    __syncthreads();
    const int qb = wv >> 1;
    const int kh = wv & 1;
    fx4 sacc[4];
#pragma unroll
    for (int n = 0; n < 4; ++n) sacc[n] = fx4{0.f, 0.f, 0.f, 0.f};
#pragma unroll
    for (int kk = 0; kk < 2; ++kk) {
        bfx8 a = *(const bfx8*)(sQ + (qb * 16 + lr) * 72 + kk * 32 + hg8);
#pragma unroll
        for (int n = 0; n < 4; ++n) {
            bfx8 bb = *(const bfx8*)(sK + ((kh * 4 + n) * 16 + lr) * 72 + kk * 32 + hg8);
            sacc[n] = __builtin_amdgcn_mfma_f32_16x16x32_bf16(a, bb, sacc[n], 0, 0, 0);
        }
    }
    const int qg = q0 + qb * 16 + rloc;
#pragma unroll
    for (int r = 0; r < 4; ++r) {
        float zs = 0.f;
#pragma unroll
        for (int n = 0; n < 4; ++n) {
            float s = sacc[n][r] * 0.125f;
            s = __expf(fminf(fmaxf(s, -5.f), 5.f));
            if (CAUSAL && (kh * 64 + n * 16 + lr) > (qg + r)) s = 0.f;
            zs += s;
            sP[(qb * 16 + rloc + r) * 136 + kh * 64 + n * 16 + lr] = f2bf(s);
        }
#pragma unroll
        for (int off = 8; off; off >>= 1) zs += __shfl_xor(zs, off);
        if (lr == 0) zp[(qb * 2 + kh) * 16 + rloc + r] = zs;
    }
    __syncthreads();
    float zinv[4];
#pragma unroll
    for (int r = 0; r < 4; ++r)
        zinv[r] = 1.f / (zp[(qb * 2 + 0) * 16 + rloc + r] + zp[(qb * 2 + 1) * 16 + rloc + r]);
    const int dh = wv & 1;
    fx4 acc2[2];
    acc2[0] = fx4{0.f, 0.f, 0.f, 0.f};
    acc2[1] = fx4{0.f, 0.f, 0.f, 0.f};
#pragma unroll
    for (int kk = 0; kk < 4; ++kk) {
        bfx8 a = *(const bfx8*)(sP + (qb * 16 + lr) * 136 + kk * 32 + hg8);
#pragma unroll
        for (int dn = 0; dn < 2; ++dn) {
            bfx8 bb = *(const bfx8*)(sVt + (dh * 32 + dn * 16 + lr) * 136 + kk * 32 + hg8);
            acc2[dn] = __builtin_amdgcn_mfma_f32_16x16x32_bf16(a, bb, acc2[dn], 0, 0, 0);
        }
    }
#pragma unroll
    for (int dn = 0; dn < 2; ++dn)
#pragma unroll
        for (int r = 0; r < 4; ++r) {
            size_t row = (size_t)(b * 128 + qg + r);
            out[row * 512 + h * 64 + dh * 32 + dn * 16 + lr] = f2bf(acc2[dn][r] * zinv[r]);
        }
}

// ---------------- log_softmax: bf16 logits [2048,8192] -> f32 out ----------------
__global__ __launch_bounds__(256) void logsoftmax_bf16_kernel(
    const unsigned short* __restrict__ logits, float* __restrict__ out)
{
    __shared__ float red[4];
    int tid = threadIdx.x;
    const bfx8* lrow = (const bfx8*)(logits + (size_t)blockIdx.x * 8192);
    float* orow = out + (size_t)blockIdx.x * 8192;
    float vals[32];
    float mx = -1e30f;
#pragma unroll
    for (int i = 0; i < 4; ++i) {
        bfx8 u = lrow[i * 256 + tid];
#pragma unroll
        for (int j = 0; j < 8; ++j) {
            float f = bf2f((unsigned short)u[j]);
            vals[i * 8 + j] = f;
            mx = fmaxf(mx, f);
        }
    }
#pragma unroll
    for (int off = 32; off; off >>= 1) mx = fmaxf(mx, __shfl_xor(mx, off));
    int wid = tid >> 6;
    if ((tid & 63) == 0) red[wid] = mx;
    __syncthreads();
    mx = fmaxf(fmaxf(red[0], red[1]), fmaxf(red[2], red[3]));
    __syncthreads();
    float sum = 0.f;
#pragma unroll
    for (int i = 0; i < 32; ++i) sum += __expf(vals[i] - mx);
#pragma unroll
    for (int off = 32; off; off >>= 1) sum += __shfl_xor(sum, off);
    if ((tid & 63) == 0) red[wid] = sum;
    __syncthreads();
    sum = red[0] + red[1] + red[2] + red[3];
    float lsub = mx + logf(sum);
#pragma unroll
    for (int i = 0; i < 4; ++i) {
        fx4 o0, o1;
#pragma unroll
        for (int j = 0; j < 4; ++j) {
            o0[j] = vals[i * 8 + j] - lsub;
            o1[j] = vals[i * 8 + 4 + j] - lsub;
        }
        ((fx4*)orow)[(i * 256 + tid) * 2] = o0;
        ((fx4*)orow)[(i * 256 + tid) * 2 + 1] = o1;
    }
}

extern "C" void kernel_launch(void* const* d_in, const int* in_sizes, int n_in,
                              void* d_out, int out_size, void* d_ws, size_t ws_size,
                              hipStream_t stream) {
    (void)in_sizes; (void)n_in; (void)out_size; (void)ws_size;
    const int* src_tokens = (const int*)d_in[0];
    const int* tgt_tokens = (const int*)d_in[1];
    const float* src_emb    = (const float*)d_in[8];
    const float* tgt_emb    = (const float*)d_in[9];
    const float* enc_attn_W = (const float*)d_in[10];
    const float* enc_attn_b = (const float*)d_in[11];
    const float* enc_ln_g   = (const float*)d_in[12];
    const float* enc_ln_b   = (const float*)d_in[13];
    const float* enc_ff_W1  = (const float*)d_in[14];
    const float* enc_ff_b1  = (const float*)d_in[15];
    const float* enc_ff_W2  = (const float*)d_in[16];
    const float* enc_ff_b2  = (const float*)d_in[17];
    const float* enc_norm_g = (const float*)d_in[18];
    const float* enc_norm_b = (const float*)d_in[19];
    const float* dec_self_W = (const float*)d_in[20];
    const float* dec_self_b = (const float*)d_in[21];
    const float* dec_cross_W= (const float*)d_in[22];
    const float* dec_cross_b= (const float*)d_in[23];
    const float* dec_ln_g   = (const float*)d_in[24];
    const float* dec_ln_b   = (const float*)d_in[25];
    const float* dec_ff_W1  = (const float*)d_in[26];
    const float* dec_ff_b1  = (const float*)d_in[27];
    const float* dec_ff_W2  = (const float*)d_in[28];
    const float* dec_ff_b2  = (const float*)d_in[29];
    const float* dec_norm_g = (const float*)d_in[30];
    const float* dec_norm_b = (const float*)d_in[31];
    const float* gen_W      = (const float*)d_in[32];
    const float* gen_b      = (const float*)d_in[33];
    float* dout = (float*)d_out;

    // ---- workspace layout ----
    unsigned short* wt = (unsigned short*)d_ws;
    const size_t OFF_ENCQKV = 0;
    const size_t OFF_ENCO   = 1572864;
    const size_t OFF_ENCW1  = 2097152;
    const size_t OFF_ENCW2  = 4194304;
    const size_t OFF_DECSQKV= 6291456;
    const size_t OFF_DECSO  = 7864320;
    const size_t OFF_DECCQKV= 8388608;
    const size_t OFF_DECCO  = 9961472;
    const size_t OFF_DECW1  = 10485760;
    const size_t OFF_DECW2  = 12582912;
    const size_t OFF_GENW   = 14680064;
    const size_t WT_ELEMS   = 18874368;
    float* fb  = (float*)(wt + WT_ELEMS);
    float* xe  = fb;
    float* xd  = fb + 1048576;
    unsigned short* nxb   = (unsigned short*)(fb + 2097152);
    unsigned short* nxd0  = (unsigned short*)(fb + 3145728);
    unsigned short* ffb   = (unsigned short*)(fb + 4194304);  // [2048,2048] bf16
    unsigned short* nkvb0 = (unsigned short*)(fb + 6291456);  // [2048,512] bf16
    unsigned short* nkvb1 = (unsigned short*)(fb + 6815744);  // [2048,512] bf16
    unsigned short* attb  = (unsigned short*)(fb + 7340032);  // [2048,512] bf16
    unsigned short* genin   = (unsigned short*)fb;             // aliases xe (dead)
    unsigned short* logitsb = (unsigned short*)(fb + 1048576); // aliases xd.. (dead)

    // ---- single-launch prep: weight transpose + embeddings + first LN ----
    TrTable tt;
    {
        int z = 0, gi = 0;
        auto addg = [&](const float* s, unsigned short* d, int srs, int drs,
                        long so, long dof, int zc) {
            tt.zStart[gi] = z;
            tt.g[gi].src = s; tt.g[gi].dst = d;
            tt.g[gi].srcRowStride = srs; tt.g[gi].dstRowStride = drs;
            tt.g[gi].srcSliceOff = so; tt.g[gi].dstSliceOff = dof;
            ++gi; z += zc;
        };
        addg(enc_attn_W,              wt + OFF_ENCQKV,               512,  512,  262144,    262144, 3);
        addg(enc_attn_W + 4L*262144,  wt + OFF_ENCQKV + 3L*262144,   512,  512,  262144,    262144, 3);
        addg(enc_attn_W + 3L*262144,  wt + OFF_ENCO,                 512,  512,  4L*262144, 262144, 2);
        addg(enc_ff_W1,               wt + OFF_ENCW1,                2048, 512,  512,       262144, 4);
        addg(enc_ff_W1 + 1048576,     wt + OFF_ENCW1 + 1048576,      2048, 512,  512,       262144, 4);
        addg(enc_ff_W2,               wt + OFF_ENCW2,                512,  2048, 262144,    512,    4);
        addg(enc_ff_W2 + 1048576,     wt + OFF_ENCW2 + 1048576,      512,  2048, 262144,    512,    4);
        addg(dec_self_W,              wt + OFF_DECSQKV,              512,  512,  262144,    262144, 3);
        addg(dec_self_W + 4L*262144,  wt + OFF_DECSQKV + 3L*262144,  512,  512,  262144,    262144, 3);
        addg(dec_self_W + 3L*262144,  wt + OFF_DECSO,                512,  512,  4L*262144, 262144, 2);
        addg(dec_cross_W,             wt + OFF_DECCQKV,              512,  512,  262144,    262144, 3);
        addg(dec_cross_W + 4L*262144, wt + OFF_DECCQKV + 3L*262144,  512,  512,  262144,    262144, 3);
        addg(dec_cross_W + 3L*262144, wt + OFF_DECCO,                512,  512,  4L*262144, 262144, 2);
        addg(dec_ff_W1,               wt + OFF_DECW1,                2048, 512,  512,       262144, 4);
        addg(dec_ff_W1 + 1048576,     wt + OFF_DECW1 + 1048576,      2048, 512,  512,       262144, 4);
        addg(dec_ff_W2,               wt + OFF_DECW2,                512,  2048, 262144,    512,    4);
        addg(dec_ff_W2 + 1048576,     wt + OFF_DECW2 + 1048576,      512,  2048, 262144,    512,    4);
        addg(gen_W,                   wt + OFF_GENW,                 8192, 512,  512,       262144, 16);
        tt.zStart[18] = z;  // 72
    }
    prep_kernel<<<dim3(16, 16, 88), 256, 0, stream>>>(
        tt, src_tokens, tgt_tokens, src_emb, tgt_emb, xe, xd,
        enc_ln_g, enc_ln_b, dec_ln_g, dec_ln_b, nxb, nxd0);

    auto gemmK = [&](const unsigned short* A, const unsigned short* W, const float* bias,
                     const float* res, void* C, int N, int K, int ldc, bool relu, bool outbf) {
        int gx = N / 64;
        dim3 g(gx * 32);
        if (res)        gemm_bk128_kernel<false, true,  false><<<g, 256, 0, stream>>>(A, W, bias, res, C, K, ldc, gx);
        else if (relu)  gemm_bk128_kernel<true,  false, true ><<<g, 256, 0, stream>>>(A, W, bias, res, C, K, ldc, gx);
        else if (outbf) gemm_bk128_kernel<false, false, true ><<<g, 256, 0, stream>>>(A, W, bias, res, C, K, ldc, gx);
        else            gemm_bk128_kernel<false, false, false><<<g, 256, 0, stream>>>(A, W, bias, res, C, K, ldc, gx);
    };
    auto gemm128 = [&](const unsigned short* A, const unsigned short* W, const float* bias,
                       unsigned short* C, int N, int K, int ldc, bool relu) {
        dim3 g((N / 128) * 16);
        if (relu) gemm128_kernel<true ><<<g, 256, 0, stream>>>(A, W, bias, C, K, ldc);
        else      gemm128_kernel<false><<<g, 256, 0, stream>>>(A, W, bias, C, K, ldc);
    };
    auto lnb = [&](const float* x, const float* g, const float* b, unsigned short* o) {
        ln_kernel<true><<<512, 256, 0, stream>>>(x, g, b, o);
    };

    // ---- encoder ----
    for (int i = 0; i < 2; ++i) {
        if (i) lnb(xe, enc_ln_g + (size_t)(i * 2) * 512, enc_ln_b + (size_t)(i * 2) * 512, nxb);
        fattn_kernel<false, true><<<256, 512, 0, stream>>>(
            nxb, nxb, wt + OFF_ENCQKV + (size_t)i * 3 * 262144,
            enc_attn_b + (size_t)i * 4 * 512, attb);
        gemmK(attb, wt + OFF_ENCO + (size_t)i * 262144, enc_attn_b + (size_t)i * 4 * 512 + 1536,
              xe, xe, 512, 512, 512, false, false);
        lnb(xe, enc_ln_g + (size_t)(i * 2 + 1) * 512, enc_ln_b + (size_t)(i * 2 + 1) * 512, nxb);
        gemm128(nxb, wt + OFF_ENCW1 + (size_t)i * 1048576, enc_ff_b1 + (size_t)i * 2048,
                ffb, 2048, 512, 2048, true);
        gemmK(ffb, wt + OFF_ENCW2 + (size_t)i * 1048576, enc_ff_b2 + (size_t)i * 512,
              xe, xe, 512, 2048, 512, false, false);
    }
    // final enc norm + both decoder cross-LN(xe) precomputed
    ln3_kernel<<<512, 256, 0, stream>>>(
        xe, enc_norm_g, enc_norm_b,
        dec_ln_g + 512, dec_ln_b + 512,
        dec_ln_g + 4 * 512, dec_ln_b + 4 * 512,
        nkvb0, nkvb1);

    // ---- decoder ----
    for (int i = 0; i < 2; ++i) {
        const unsigned short* qsrc = (i == 0) ? nxd0 : nxb;
        if (i) lnb(xd, dec_ln_g + (size_t)(i * 3) * 512, dec_ln_b + (size_t)(i * 3) * 512, nxb);
        fattn_kernel<true, true><<<256, 512, 0, stream>>>(
            qsrc, qsrc, wt + OFF_DECSQKV + (size_t)i * 3 * 262144,
            dec_self_b + (size_t)i * 4 * 512, attb);
        gemmK(attb, wt + OFF_DECSO + (size_t)i * 262144, dec_self_b + (size_t)i * 4 * 512 + 1536,
              xd, xd, 512, 512, 512, false, false);
        lnb(xd, dec_ln_g + (size_t)(i * 3 + 1) * 512, dec_ln_b + (size_t)(i * 3 + 1) * 512, nxb);
        fattn_kernel<false, false><<<256, 512, 0, stream>>>(
            nxb, i ? nkvb1 : nkvb0, wt + OFF_DECCQKV + (size_t)i * 3 * 262144,
            dec_cross_b + (size_t)i * 4 * 512, attb);
        gemmK(attb, wt + OFF_DECCO + (size_t)i * 262144, dec_cross_b + (size_t)i * 4 * 512 + 1536,
              xd, xd, 512, 512, 512, false, false);
        lnb(xd, dec_ln_g + (size_t)(i * 3 + 2) * 512, dec_ln_b + (size_t)(i * 3 + 2) * 512, nxb);
        gemm128(nxb, wt + OFF_DECW1 + (size_t)i * 1048576, dec_ff_b1 + (size_t)i * 2048,
                ffb, 2048, 512, 2048, true);
        gemmK(ffb, wt + OFF_DECW2 + (size_t)i * 1048576, dec_ff_b2 + (size_t)i * 512,
              xd, xd, 512, 2048, 512, false, false);
    }
    lnb(xd, dec_norm_g, dec_norm_b, genin);

    // ---- generator + log_softmax ----
    gemm128(genin, wt + OFF_GENW, gen_b, logitsb, 8192, 512, 8192, false);
    logsoftmax_bf16_kernel<<<2048, 256, 0, stream>>>(logitsb, dout);
}

// Round 12
// 304.431 us; speedup vs baseline: 1.3406x; 1.0086x over previous
//
#include <hip/hip_runtime.h>

typedef __attribute__((ext_vector_type(8))) short bfx8;
typedef __attribute__((ext_vector_type(4))) float fx4;

static __device__ __forceinline__ unsigned short f2bf(float f) {
    union { float f; unsigned int u; } v; v.f = f;
    unsigned int i = v.u;
    return (unsigned short)((i + 0x7FFFu + ((i >> 16) & 1u)) >> 16);
}
static __device__ __forceinline__ float bf2f(unsigned short u) {
    union { unsigned int ui; float f; } cv;
    cv.ui = ((unsigned int)u) << 16;
    return cv.f;
}

// async global->LDS, 16B per lane; l is the WAVE-UNIFORM base (HW adds lane*16)
static __device__ __forceinline__ void gl2lds16(const unsigned short* g, unsigned short* l) {
    unsigned long long gu = (unsigned long long)g;
    unsigned int lu = (unsigned int)(unsigned long long)l;
    __builtin_amdgcn_global_load_lds(
        (const __attribute__((address_space(1))) void*)gu,
        (__attribute__((address_space(3))) void*)lu,
        16, 0, 0);
}

// ---------------- fused prep: 72 transpose slices (64x32 tiles) + 32 embed slices ----------------
struct TrGroup {
    const float* src;
    unsigned short* dst;
    int srcRowStride;
    int dstRowStride;
    long srcSliceOff;
    long dstSliceOff;
};
struct TrTable {
    TrGroup g[18];
    int zStart[19];
};

__global__ __launch_bounds__(256) void prep_kernel(
    TrTable tt,
    const int* __restrict__ tokA, const int* __restrict__ tokB,
    const float* __restrict__ embA, const float* __restrict__ embB,
    float* __restrict__ outA, float* __restrict__ outB,
    const float* __restrict__ gA, const float* __restrict__ bA,
    const float* __restrict__ gB, const float* __restrict__ bB,
    unsigned short* __restrict__ nxA, unsigned short* __restrict__ nxB)
{
    __shared__ unsigned short tile[64][37];   // k-major, pad 37: conflict-free strided read-out
    __shared__ float red[4];
    int z = blockIdx.z;
    int tid = threadIdx.x;
    if (z < 72) {
        // ---- weight transpose f32 [512k x 512n] -> bf16 [n][k], 64k x 32n tile ----
        int gi = 0;
#pragma unroll 1
        while (z >= tt.zStart[gi + 1]) ++gi;
        int zi = z - tt.zStart[gi];
        const float* s = tt.g[gi].src + (size_t)zi * tt.g[gi].srcSliceOff;
        unsigned short* d = tt.g[gi].dst + (size_t)zi * tt.g[gi].dstSliceOff;
        int srs = tt.g[gi].srcRowStride, drs = tt.g[gi].dstRowStride;
        int n0 = blockIdx.x * 32, k0 = blockIdx.y * 64;
        int kr = tid >> 3;             // 0..31
        int c4 = (tid & 7) * 4;        // 0..28
#pragma unroll
        for (int p = 0; p < 2; ++p) {
            int k = kr + p * 32;
            fx4 f = *(const fx4*)(s + (size_t)(k0 + k) * srs + n0 + c4);
#pragma unroll
            for (int j = 0; j < 4; ++j) tile[k][c4 + j] = f2bf(f[j]);
        }
        __syncthreads();
        int nr = tid >> 3;             // 0..31 output row within tile
        int kc = (tid & 7) * 8;        // 0..56
        ushort4 u0, u1;
#pragma unroll
        for (int j = 0; j < 4; ++j) ((unsigned short*)&u0)[j] = tile[kc + j][nr];
#pragma unroll
        for (int j = 0; j < 4; ++j) ((unsigned short*)&u1)[j] = tile[kc + 4 + j][nr];
        unsigned short* dp = d + (size_t)(n0 + nr) * drs + k0 + kc;
        *(ushort4*)dp = u0;
        *(ushort4*)(dp + 4) = u1;
        return;
    }
    // ---- embeddings + PE + first LN ----
    int e = (z - 72) * 128 + blockIdx.y * 16 + blockIdx.x;   // 0..4095
    int row = e & 2047;
    bool isA = e < 2048;
    const int* tok = isA ? tokA : tokB;
    const float* emb = isA ? embA : embB;
    float* out = isA ? outA : outB;
    const float* g = isA ? gA : gB;
    const float* bb = isA ? bA : bB;
    unsigned short* nx = isA ? nxA : nxB;
    int pos = row & 127;
    int t = tok[row];
    int d0 = tid, d1 = tid + 256;
    auto pe = [&](int d) {
        float ang = (float)pos * expf((float)(d & ~1) * (-9.210340371976184f / 512.0f));
        return (d & 1) ? cosf(ang) : sinf(ang);
    };
    float v0 = emb[(size_t)t * 512 + d0] * 22.627416997969522f + pe(d0);
    float v1 = emb[(size_t)t * 512 + d1] * 22.627416997969522f + pe(d1);
    out[(size_t)row * 512 + d0] = v0;
    out[(size_t)row * 512 + d1] = v1;
    int lane = tid & 63, wv = tid >> 6;
    float s = v0 + v1;
#pragma unroll
    for (int off = 32; off; off >>= 1) s += __shfl_xor(s, off);
    if (lane == 0) red[wv] = s;
    __syncthreads();
    float mu = (red[0] + red[1] + red[2] + red[3]) * (1.0f / 512.0f);
    __syncthreads();
    float q = (v0 - mu) * (v0 - mu) + (v1 - mu) * (v1 - mu);
#pragma unroll
    for (int off = 32; off; off >>= 1) q += __shfl_xor(q, off);
    if (lane == 0) red[wv] = q;
    __syncthreads();
    float rs = rsqrtf((red[0] + red[1] + red[2] + red[3]) * (1.0f / 512.0f) + 1e-5f);
    nx[(size_t)row * 512 + d0] = f2bf(g[d0] * (v0 - mu) * rs + bb[d0]);
    nx[(size_t)row * 512 + d1] = f2bf(g[d1] * (v1 - mu) * rs + bb[d1]);
}

// ---------------- layernorm row body (D=512, one wave) ----------------
static __device__ __forceinline__ void ln_row(
    const float* __restrict__ xrow, const float* __restrict__ g,
    const float* __restrict__ b, int lane, fx4& o0, fx4& o1)
{
    const fx4* xr = (const fx4*)xrow;
    fx4 a = xr[lane * 2], c = xr[lane * 2 + 1];
    float s = a[0] + a[1] + a[2] + a[3] + c[0] + c[1] + c[2] + c[3];
#pragma unroll
    for (int off = 32; off; off >>= 1) s += __shfl_xor(s, off);
    float mu = s * (1.0f / 512.0f);
    float qv = 0.f;
#pragma unroll
    for (int j = 0; j < 4; ++j) {
        float d0 = a[j] - mu; qv += d0 * d0;
        float d1 = c[j] - mu; qv += d1 * d1;
    }
#pragma unroll
    for (int off = 32; off; off >>= 1) qv += __shfl_xor(qv, off);
    float rs = rsqrtf(qv * (1.0f / 512.0f) + 1e-5f);
    const fx4* gr = (const fx4*)g;
    const fx4* br = (const fx4*)b;
    fx4 g0 = gr[lane * 2], g1 = gr[lane * 2 + 1];
    fx4 b0 = br[lane * 2], b1 = br[lane * 2 + 1];
#pragma unroll
    for (int j = 0; j < 4; ++j) {
        o0[j] = g0[j] * (a[j] - mu) * rs + b0[j];
        o1[j] = g1[j] * (c[j] - mu) * rs + b1[j];
    }
}

template<bool OUTBF>
__global__ __launch_bounds__(256) void ln_kernel(
    const float* __restrict__ x, const float* __restrict__ g,
    const float* __restrict__ b, void* __restrict__ out)
{
    int row = blockIdx.x * 4 + (threadIdx.x >> 6);
    int lane = threadIdx.x & 63;
    fx4 o0, o1;
    ln_row(x + (size_t)row * 512, g, b, lane, o0, o1);
    if (OUTBF) {
        unsigned short* orow = (unsigned short*)out + (size_t)row * 512 + lane * 8;
        ushort4 u0 = {f2bf(o0[0]), f2bf(o0[1]), f2bf(o0[2]), f2bf(o0[3])};
        ushort4 u1 = {f2bf(o1[0]), f2bf(o1[1]), f2bf(o1[2]), f2bf(o1[3])};
        *(ushort4*)orow = u0;
        *(ushort4*)(orow + 4) = u1;
    } else {
        fx4* orow = (fx4*)out + (size_t)row * 128;
        orow[lane * 2] = o0;
        orow[lane * 2 + 1] = o1;
    }
}

// fused: xe = LN(xe, enc_norm); nk0 = LN(xe', dec l0); nk1 = LN(xe', dec l1)
__global__ __launch_bounds__(256) void ln3_kernel(
    float* __restrict__ xe, const float* __restrict__ eg, const float* __restrict__ eb,
    const float* __restrict__ g0, const float* __restrict__ b0,
    const float* __restrict__ g1, const float* __restrict__ b1,
    unsigned short* __restrict__ nk0, unsigned short* __restrict__ nk1)
{
    int row = blockIdx.x * 4 + (threadIdx.x >> 6);
    int lane = threadIdx.x & 63;
    fx4 t0, t1;
    ln_row(xe + (size_t)row * 512, eg, eb, lane, t0, t1);
    fx4* orow = (fx4*)(xe + (size_t)row * 512);
    orow[lane * 2] = t0;
    orow[lane * 2 + 1] = t1;
    float s = t0[0] + t0[1] + t0[2] + t0[3] + t1[0] + t1[1] + t1[2] + t1[3];
#pragma unroll
    for (int off = 32; off; off >>= 1) s += __shfl_xor(s, off);
    float mu = s * (1.0f / 512.0f);
    float q = 0.f;
#pragma unroll
    for (int j = 0; j < 4; ++j) {
        float a = t0[j] - mu; q += a * a;
        float c = t1[j] - mu; q += c * c;
    }
#pragma unroll
    for (int off = 32; off; off >>= 1) q += __shfl_xor(q, off);
    float rs = rsqrtf(q * (1.0f / 512.0f) + 1e-5f);
    const fx4* g0r = (const fx4*)g0; const fx4* b0r = (const fx4*)b0;
    const fx4* g1r = (const fx4*)g1; const fx4* b1r = (const fx4*)b1;
    fx4 ga0 = g0r[lane * 2], ga1 = g0r[lane * 2 + 1];
    fx4 bb0 = b0r[lane * 2], bb1 = b0r[lane * 2 + 1];
    fx4 gc0 = g1r[lane * 2], gc1 = g1r[lane * 2 + 1];
    fx4 bc0 = b1r[lane * 2], bc1 = b1r[lane * 2 + 1];
    unsigned short* o0 = nk0 + (size_t)row * 512 + lane * 8;
    unsigned short* o1 = nk1 + (size_t)row * 512 + lane * 8;
    ushort4 ua0, ua1, uc0, uc1;
#pragma unroll
    for (int j = 0; j < 4; ++j) {
        float n0 = (t0[j] - mu) * rs, n1 = (t1[j] - mu) * rs;
        ((unsigned short*)&ua0)[j] = f2bf(ga0[j] * n0 + bb0[j]);
        ((unsigned short*)&ua1)[j] = f2bf(ga1[j] * n1 + bb1[j]);
        ((unsigned short*)&uc0)[j] = f2bf(gc0[j] * n0 + bc0[j]);
        ((unsigned short*)&uc1)[j] = f2bf(gc1[j] * n1 + bc1[j]);
    }
    *(ushort4*)o0 = ua0; *(ushort4*)(o0 + 4) = ua1;
    *(ushort4*)o1 = uc0; *(ushort4*)(o1 + 4) = uc1;
}

// ---------------- bf16 MFMA GEMM, 64x64 tile, BK=128 ----------------
template<bool RELU, bool RESID, bool OUTBF>
__global__ __launch_bounds__(256) void gemm_bk128_kernel(
    const unsigned short* __restrict__ A, const unsigned short* __restrict__ Wt,
    const float* __restrict__ bias, const float* __restrict__ res,
    void* __restrict__ Cv, int K, int ldc, int gx)
{
    __shared__ unsigned short smem[2][2][8192];  // [buf][A/B][64*128]
    const int tid = threadIdx.x;
    const int nwg = gridDim.x;
    const int cpx = nwg >> 3;
    const int phys = blockIdx.x;
    const int logical = (phys & 7) * cpx + (phys >> 3);
    const int bm = (logical / gx) * 64;
    const int bn = (logical % gx) * 64;
    const int lane = tid & 63;
    const int wv = tid >> 6;
    const int wr = (wv >> 1) * 32;
    const int wc = (wv & 1) * 32;
    const int lr = lane & 15;
    const int lrow4 = lane >> 4;
    const int lchk16 = lane & 15;
    fx4 acc00 = {0.f, 0.f, 0.f, 0.f}, acc01 = {0.f, 0.f, 0.f, 0.f};
    fx4 acc10 = {0.f, 0.f, 0.f, 0.f}, acc11 = {0.f, 0.f, 0.f, 0.f};

    auto stage = [&](int buf, int k0) {
#pragma unroll
        for (int j = 0; j < 4; ++j) {
            int row = wv * 16 + j * 4 + lrow4;
            int sc = (lchk16 ^ (row & 15)) * 8;
            gl2lds16(A + (size_t)(bm + row) * K + k0 + sc,
                     &smem[buf][0][(wv * 16 + j * 4) * 128]);
            gl2lds16(Wt + (size_t)(bn + row) * K + k0 + sc,
                     &smem[buf][1][(wv * 16 + j * 4) * 128]);
        }
    };

    const int nt = K >> 7;
    int cur = 0;
    stage(0, 0);
    for (int t = 0; t < nt; ++t) {
        __syncthreads();
        if (t + 1 < nt) stage(cur ^ 1, (t + 1) << 7);
        const unsigned short* bufA = &smem[cur][0][0];
        const unsigned short* bufB = &smem[cur][1][0];
        const int ra0 = wr + lr, ra1 = wr + 16 + lr;
        const int rb0 = wc + lr, rb1 = wc + 16 + lr;
        __builtin_amdgcn_s_setprio(1);
#pragma unroll
        for (int kk = 0; kk < 4; ++kk) {
            int ca = kk * 4 + (lane >> 4);
            bfx8 a0 = *(const bfx8*)&bufA[ra0 * 128 + ((ca ^ (ra0 & 15)) * 8)];
            bfx8 a1 = *(const bfx8*)&bufA[ra1 * 128 + ((ca ^ (ra1 & 15)) * 8)];
            bfx8 b0 = *(const bfx8*)&bufB[rb0 * 128 + ((ca ^ (rb0 & 15)) * 8)];
            bfx8 b1 = *(const bfx8*)&bufB[rb1 * 128 + ((ca ^ (rb1 & 15)) * 8)];
            acc00 = __builtin_amdgcn_mfma_f32_16x16x32_bf16(a0, b0, acc00, 0, 0, 0);
            acc01 = __builtin_amdgcn_mfma_f32_16x16x32_bf16(a0, b1, acc01, 0, 0, 0);
            acc10 = __builtin_amdgcn_mfma_f32_16x16x32_bf16(a1, b0, acc10, 0, 0, 0);
            acc11 = __builtin_amdgcn_mfma_f32_16x16x32_bf16(a1, b1, acc11, 0, 0, 0);
        }
        __builtin_amdgcn_s_setprio(0);
        cur ^= 1;
    }
    int rbase = bm + wr + ((lane >> 4) * 4);
    int cbase = bn + wc + lr;
#pragma unroll
    for (int m = 0; m < 2; ++m) {
        fx4 am0 = m ? acc10 : acc00;
        fx4 am1 = m ? acc11 : acc01;
#pragma unroll
        for (int r = 0; r < 4; ++r) {
            int row = rbase + m * 16 + r;
#pragma unroll
            for (int half = 0; half < 2; ++half) {
                int col = cbase + half * 16;
                float v = (half ? am1[r] : am0[r]) + bias[col];
                if (RESID) v += res[(size_t)row * ldc + col];
                if (RELU) v = fmaxf(v, 0.f);
                if (OUTBF) ((unsigned short*)Cv)[(size_t)row * ldc + col] = f2bf(v);
                else       ((float*)Cv)[(size_t)row * ldc + col] = v;
            }
        }
    }
}

// ---------------- bf16 MFMA GEMM, 128x128 tile (4 waves x 64x64), bf16 out ----------------
template<bool RELU>
__global__ __launch_bounds__(256) void gemm128_kernel(
    const unsigned short* __restrict__ A, const unsigned short* __restrict__ Wt,
    const float* __restrict__ bias, unsigned short* __restrict__ C,
    int K, int ldc)
{
    __shared__ unsigned short smem[2][2][8192];  // [buf][A/B][128*64]
    const int tid = threadIdx.x;
    const int nwg = gridDim.x;
    const int cpx = nwg >> 3;
    const int phys = blockIdx.x;
    const int logical = (phys & 7) * cpx + (phys >> 3);
    const int bm = (logical & 15) * 128;     // M = 2048 always
    const int bn = (logical >> 4) * 128;
    const int lane = tid & 63;
    const int wv = tid >> 6;
    const int wr = (wv >> 1) * 64;
    const int wc = (wv & 1) * 64;
    const int lr = lane & 15;
    const int lrow = lane >> 3;
    const int lchk = lane & 7;
    fx4 acc[4][4];
#pragma unroll
    for (int mi = 0; mi < 4; ++mi)
#pragma unroll
        for (int ni = 0; ni < 4; ++ni) acc[mi][ni] = fx4{0.f, 0.f, 0.f, 0.f};

    auto stage = [&](int buf, int k0) {
#pragma unroll
        for (int j = 0; j < 4; ++j) {
            int row = wv * 32 + j * 8 + lrow;
            int sc = lchk ^ (row & 7);
            gl2lds16(A + (size_t)(bm + row) * K + k0 + sc * 8,
                     &smem[buf][0][(wv * 32 + j * 8) * 64]);
            gl2lds16(Wt + (size_t)(bn + row) * K + k0 + sc * 8,
                     &smem[buf][1][(wv * 32 + j * 8) * 64]);
        }
    };

    const int nt = K >> 6;
    int cur = 0;
    stage(0, 0);
    for (int t = 0; t < nt; ++t) {
        __syncthreads();
        if (t + 1 < nt) stage(cur ^ 1, (t + 1) << 6);
        const unsigned short* bufA = &smem[cur][0][0];
        const unsigned short* bufB = &smem[cur][1][0];
        __builtin_amdgcn_s_setprio(1);
#pragma unroll
        for (int kk = 0; kk < 2; ++kk) {
            int ca = kk * 4 + (lane >> 4);
            bfx8 af[4], bg[4];
#pragma unroll
            for (int i = 0; i < 4; ++i) {
                int ra = wr + i * 16 + lr;
                int rb = wc + i * 16 + lr;
                af[i] = *(const bfx8*)&bufA[ra * 64 + ((ca ^ (ra & 7)) * 8)];
                bg[i] = *(const bfx8*)&bufB[rb * 64 + ((ca ^ (rb & 7)) * 8)];
            }
#pragma unroll
            for (int mi = 0; mi < 4; ++mi)
#pragma unroll
                for (int ni = 0; ni < 4; ++ni)
                    acc[mi][ni] = __builtin_amdgcn_mfma_f32_16x16x32_bf16(af[mi], bg[ni], acc[mi][ni], 0, 0, 0);
        }
        __builtin_amdgcn_s_setprio(0);
        cur ^= 1;
    }
    int rbase = bm + wr + ((lane >> 4) * 4);
    int cbase = bn + wc + lr;
#pragma unroll
    for (int mi = 0; mi < 4; ++mi)
#pragma unroll
        for (int ni = 0; ni < 4; ++ni) {
            int col = cbase + ni * 16;
            float bv = bias[col];
#pragma unroll
            for (int r = 0; r < 4; ++r) {
                int row = rbase + mi * 16 + r;
                float v = acc[mi][ni][r] + bv;
                if (RELU) v = fmaxf(v, 0.f);
                C[(size_t)row * ldc + col] = f2bf(v);
            }
        }
}

// ---------------- fused QKV-projection + attention (8 waves, region-pure proj) ----------------
template<bool CAUSAL, bool SELF>
__global__ __launch_bounds__(512) void fattn_kernel(
    const unsigned short* __restrict__ xq, const unsigned short* __restrict__ xkv,
    const unsigned short* __restrict__ Wt, const float* __restrict__ bias,
    unsigned short* __restrict__ out)
{
    constexpr int XROWS = SELF ? 128 : 192;
    constexpr int BUFB  = (XROWS + 192) * 64 * 2;
    __shared__ __align__(16) unsigned char lds[2 * BUFB + 9216 + 18432 + 17408 + 512];
    const int blk = blockIdx.x;
    const int half = blk & 1;
    const int h = (blk >> 1) & 7;
    const int b = blk >> 4;
    const int q0 = half * 64;
    const int tid = threadIdx.x;
    const int lane = tid & 63;
    const int wv = tid >> 6;
    const int lr = lane & 15;
    const int hg8 = (lane >> 4) * 8;
    const int rloc = (lane >> 4) * 4;
    const int lrow = lane >> 3;
    const int lchk = lane & 7;

    const unsigned short* gxq = xq + (size_t)(b * 128 + q0) * 512;
    const unsigned short* gkv = xkv + (size_t)(b * 128) * 512;
    const unsigned short* gw  = Wt + (size_t)(h * 64) * 512;

    auto stage = [&](int buf, int k0) {
        unsigned short* dst = (unsigned short*)(lds + buf * BUFB);
        if constexpr (SELF) {
#pragma unroll
            for (int j = 0; j < 5; ++j) {
                int start = wv * 40 + j * 8;
                int row = start + lrow;
                int sc = (lchk ^ (row & 7)) * 8;
                const unsigned short* src;
                if (start < 128) {
                    src = gkv + (size_t)row * 512 + k0 + sc;
                } else {
                    int wr_ = row - 128;
                    src = gw + ((size_t)(wr_ & 63) + (size_t)(wr_ >> 6) * 512) * 512 + k0 + sc;
                }
                gl2lds16(src, dst + start * 64);
            }
        } else {
            unsigned short* dstW = dst + XROWS * 64;
#pragma unroll
            for (int j = 0; j < 3; ++j) {
                int row = wv * 24 + j * 8 + lrow;
                int sc = (lchk ^ (row & 7)) * 8;
                const unsigned short* xs = (row < 64)
                    ? gxq + (size_t)row * 512
                    : gkv + (size_t)(row - 64) * 512;
                gl2lds16(xs + k0 + sc, dst + (wv * 24 + j * 8) * 64);
                const unsigned short* ws = gw + ((size_t)(row & 63) + (size_t)(row >> 6) * 512) * 512;
                gl2lds16(ws + k0 + sc, dstW + (wv * 24 + j * 8) * 64);
            }
        }
    };

    fx4 acc[4][4];
#pragma unroll
    for (int i = 0; i < 4; ++i)
#pragma unroll
        for (int c = 0; c < 4; ++c) acc[i][c] = fx4{0.f, 0.f, 0.f, 0.f};

    const int arowbase = (wv == 4) ? (SELF ? q0 : 0)
                                   : (SELF ? 0 : 64) + ((wv & 1) * 64);
    const int wbase = (wv == 4) ? 0 : (wv < 2 ? 64 : 128);

    stage(0, 0);
#pragma unroll 1
    for (int t = 0; t < 8; ++t) {
        __syncthreads();
        if (t < 7) stage((t + 1) & 1, (t + 1) * 64);
        const unsigned short* stX = (const unsigned short*)(lds + (t & 1) * BUFB);
        const unsigned short* stW = stX + XROWS * 64;
        if (wv < 5) {
#pragma unroll
            for (int kk = 0; kk < 2; ++kk) {
                const int ca = kk * 4 + (lane >> 4);
                auto rd = [&](const unsigned short* base, int row) -> bfx8 {
                    return *(const bfx8*)(base + row * 64 + ((ca ^ (row & 7)) * 8));
                };
                bfx8 af[4];
#pragma unroll
                for (int i = 0; i < 4; ++i) af[i] = rd(stX, arowbase + i * 16 + lr);
                __builtin_amdgcn_s_setprio(1);
#pragma unroll
                for (int c = 0; c < 4; ++c) {
                    bfx8 bf = rd(stW, wbase + c * 16 + lr);
#pragma unroll
                    for (int i = 0; i < 4; ++i)
                        acc[i][c] = __builtin_amdgcn_mfma_f32_16x16x32_bf16(af[i], bf, acc[i][c], 0, 0, 0);
                }
                __builtin_amdgcn_s_setprio(0);
            }
        }
    }
    unsigned short* sQ  = (unsigned short*)(lds + 2 * BUFB);
    unsigned short* sK  = (unsigned short*)(lds + 2 * BUFB + 9216);
    unsigned short* sVt = (unsigned short*)(lds + 2 * BUFB + 9216 + 18432);
    float* zp = (float*)(lds + 2 * BUFB + 9216 + 18432 + 17408);
    unsigned short* sP  = (unsigned short*)lds;
    if (wv == 4) {
#pragma unroll
        for (int c = 0; c < 4; ++c) {
            int col = c * 16 + lr;
            float bq_ = bias[h * 64 + col];
#pragma unroll
            for (int i = 0; i < 4; ++i)
#pragma unroll
                for (int r = 0; r < 4; ++r)
                    sQ[(i * 16 + rloc + r) * 72 + col] = f2bf(acc[i][c][r] + bq_);
        }
    } else if (wv < 2) {
        int rb = wv * 64;
#pragma unroll
        for (int c = 0; c < 4; ++c) {
            int col = c * 16 + lr;
            float bk_ = bias[512 + h * 64 + col];
#pragma unroll
            for (int i = 0; i < 4; ++i)
#pragma unroll
                for (int r = 0; r < 4; ++r)
                    sK[(rb + i * 16 + rloc + r) * 72 + col] = f2bf(acc[i][c][r] + bk_);
        }
    } else if (wv < 4) {
        int rb = (wv - 2) * 64;
#pragma unroll
        for (int c = 0; c < 4; ++c) {
            int col = c * 16 + lr;
            float bv_ = bias[1024 + h * 64 + col];
#pragma unroll
            for (int i = 0; i < 4; ++i)
#pragma unroll
                for (int r = 0; r < 4; ++r)
                    sVt[col * 136 + (rb + i * 16 + rloc + r)] = f2bf(acc[i][c][r] + bv_);
        }
    }
    __syncthreads();
    const int qb = wv >> 1;
    const int kh = wv & 1;
    fx4 sacc[4];
#pragma unroll
    for (int n = 0; n < 4; ++n) sacc[n] = fx4{0.f, 0.f, 0.f, 0.f};
#pragma unroll
    for (int kk = 0; kk < 2; ++kk) {
        bfx8 a = *(const bfx8*)(sQ + (qb * 16 + lr) * 72 + kk * 32 + hg8);
#pragma unroll
        for (int n = 0; n < 4; ++n) {
            bfx8 bb = *(const bfx8*)(sK + ((kh * 4 + n) * 16 + lr) * 72 + kk * 32 + hg8);
            sacc[n] = __builtin_amdgcn_mfma_f32_16x16x32_bf16(a, bb, sacc[n], 0, 0, 0);
        }
    }
    const int qg = q0 + qb * 16 + rloc;
#pragma unroll
    for (int r = 0; r < 4; ++r) {
        float zs = 0.f;
#pragma unroll
        for (int n = 0; n < 4; ++n) {
            float s = sacc[n][r] * 0.125f;
            s = __expf(fminf(fmaxf(s, -5.f), 5.f));
            if (CAUSAL && (kh * 64 + n * 16 + lr) > (qg + r)) s = 0.f;
            zs += s;
            sP[(qb * 16 + rloc + r) * 136 + kh * 64 + n * 16 + lr] = f2bf(s);
        }
#pragma unroll
        for (int off = 8; off; off >>= 1) zs += __shfl_xor(zs, off);
        if (lr == 0) zp[(qb * 2 + kh) * 16 + rloc + r] = zs;
    }
    __syncthreads();
    float zinv[4];
#pragma unroll
    for (int r = 0; r < 4; ++r)
        zinv[r] = 1.f / (zp[(qb * 2 + 0) * 16 + rloc + r] + zp[(qb * 2 + 1) * 16 + rloc + r]);
    const int dh = wv & 1;
    fx4 acc2[2];
    acc2[0] = fx4{0.f, 0.f, 0.f, 0.f};
    acc2[1] = fx4{0.f, 0.f, 0.f, 0.f};
#pragma unroll
    for (int kk = 0; kk < 4; ++kk) {
        bfx8 a = *(const bfx8*)(sP + (qb * 16 + lr) * 136 + kk * 32 + hg8);
#pragma unroll
        for (int dn = 0; dn < 2; ++dn) {
            bfx8 bb = *(const bfx8*)(sVt + (dh * 32 + dn * 16 + lr) * 136 + kk * 32 + hg8);
            acc2[dn] = __builtin_amdgcn_mfma_f32_16x16x32_bf16(a, bb, acc2[dn], 0, 0, 0);
        }
    }
#pragma unroll
    for (int dn = 0; dn < 2; ++dn)
#pragma unroll
        for (int r = 0; r < 4; ++r) {
            size_t row = (size_t)(b * 128 + qg + r);
            out[row * 512 + h * 64 + dh * 32 + dn * 16 + lr] = f2bf(acc2[dn][r] * zinv[r]);
        }
}

// ---------------- log_softmax: bf16 logits [2048,8192] -> f32 out ----------------
__global__ __launch_bounds__(256) void logsoftmax_bf16_kernel(
    const unsigned short* __restrict__ logits, float* __restrict__ out)
{
    __shared__ float red[4];
    int tid = threadIdx.x;
    const bfx8* lrow = (const bfx8*)(logits + (size_t)blockIdx.x * 8192);
    float* orow = out + (size_t)blockIdx.x * 8192;
    float vals[32];
    float mx = -1e30f;
#pragma unroll
    for (int i = 0; i < 4; ++i) {
        bfx8 u = lrow[i * 256 + tid];
#pragma unroll
        for (int j = 0; j < 8; ++j) {
            float f = bf2f((unsigned short)u[j]);
            vals[i * 8 + j] = f;
            mx = fmaxf(mx, f);
        }
    }
#pragma unroll
    for (int off = 32; off; off >>= 1) mx = fmaxf(mx, __shfl_xor(mx, off));
    int wid = tid >> 6;
    if ((tid & 63) == 0) red[wid] = mx;
    __syncthreads();
    mx = fmaxf(fmaxf(red[0], red[1]), fmaxf(red[2], red[3]));
    __syncthreads();
    float sum = 0.f;
#pragma unroll
    for (int i = 0; i < 32; ++i) sum += __expf(vals[i] - mx);
#pragma unroll
    for (int off = 32; off; off >>= 1) sum += __shfl_xor(sum, off);
    if ((tid & 63) == 0) red[wid] = sum;
    __syncthreads();
    sum = red[0] + red[1] + red[2] + red[3];
    float lsub = mx + logf(sum);
#pragma unroll
    for (int i = 0; i < 4; ++i) {
        fx4 o0, o1;
#pragma unroll
        for (int j = 0; j < 4; ++j) {
            o0[j] = vals[i * 8 + j] - lsub;
            o1[j] = vals[i * 8 + 4 + j] - lsub;
        }
        ((fx4*)orow)[(i * 256 + tid) * 2] = o0;
        ((fx4*)orow)[(i * 256 + tid) * 2 + 1] = o1;
    }
}

extern "C" void kernel_launch(void* const* d_in, const int* in_sizes, int n_in,
                              void* d_out, int out_size, void* d_ws, size_t ws_size,
                              hipStream_t stream) {
    (void)in_sizes; (void)n_in; (void)out_size; (void)ws_size;
    const int* src_tokens = (const int*)d_in[0];
    const int* tgt_tokens = (const int*)d_in[1];
    const float* src_emb    = (const float*)d_in[8];
    const float* tgt_emb    = (const float*)d_in[9];
    const float* enc_attn_W = (const float*)d_in[10];
    const float* enc_attn_b = (const float*)d_in[11];
    const float* enc_ln_g   = (const float*)d_in[12];
    const float* enc_ln_b   = (const float*)d_in[13];
    const float* enc_ff_W1  = (const float*)d_in[14];
    const float* enc_ff_b1  = (const float*)d_in[15];
    const float* enc_ff_W2  = (const float*)d_in[16];
    const float* enc_ff_b2  = (const float*)d_in[17];
    const float* enc_norm_g = (const float*)d_in[18];
    const float* enc_norm_b = (const float*)d_in[19];
    const float* dec_self_W = (const float*)d_in[20];
    const float* dec_self_b = (const float*)d_in[21];
    const float* dec_cross_W= (const float*)d_in[22];
    const float* dec_cross_b= (const float*)d_in[23];
    const float* dec_ln_g   = (const float*)d_in[24];
    const float* dec_ln_b   = (const float*)d_in[25];
    const float* dec_ff_W1  = (const float*)d_in[26];
    const float* dec_ff_b1  = (const float*)d_in[27];
    const float* dec_ff_W2  = (const float*)d_in[28];
    const float* dec_ff_b2  = (const float*)d_in[29];
    const float* dec_norm_g = (const float*)d_in[30];
    const float* dec_norm_b = (const float*)d_in[31];
    const float* gen_W      = (const float*)d_in[32];
    const float* gen_b      = (const float*)d_in[33];
    float* dout = (float*)d_out;

    // ---- workspace layout ----
    unsigned short* wt = (unsigned short*)d_ws;
    const size_t OFF_ENCQKV = 0;
    const size_t OFF_ENCO   = 1572864;
    const size_t OFF_ENCW1  = 2097152;
    const size_t OFF_ENCW2  = 4194304;
    const size_t OFF_DECSQKV= 6291456;
    const size_t OFF_DECSO  = 7864320;
    const size_t OFF_DECCQKV= 8388608;
    const size_t OFF_DECCO  = 9961472;
    const size_t OFF_DECW1  = 10485760;
    const size_t OFF_DECW2  = 12582912;
    const size_t OFF_GENW   = 14680064;
    const size_t WT_ELEMS   = 18874368;
    float* fb  = (float*)(wt + WT_ELEMS);
    float* xe  = fb;
    float* xd  = fb + 1048576;
    unsigned short* nxb   = (unsigned short*)(fb + 2097152);
    unsigned short* nxd0  = (unsigned short*)(fb + 3145728);
    unsigned short* ffb   = (unsigned short*)(fb + 4194304);  // [2048,2048] bf16
    unsigned short* nkvb0 = (unsigned short*)(fb + 6291456);  // [2048,512] bf16
    unsigned short* nkvb1 = (unsigned short*)(fb + 6815744);  // [2048,512] bf16
    unsigned short* attb  = (unsigned short*)(fb + 7340032);  // [2048,512] bf16
    unsigned short* genin   = (unsigned short*)fb;             // aliases xe (dead)
    unsigned short* logitsb = (unsigned short*)(fb + 1048576); // aliases xd.. (dead)

    // ---- single-launch prep: weight transpose + embeddings + first LN ----
    TrTable tt;
    {
        int z = 0, gi = 0;
        auto addg = [&](const float* s, unsigned short* d, int srs, int drs,
                        long so, long dof, int zc) {
            tt.zStart[gi] = z;
            tt.g[gi].src = s; tt.g[gi].dst = d;
            tt.g[gi].srcRowStride = srs; tt.g[gi].dstRowStride = drs;
            tt.g[gi].srcSliceOff = so; tt.g[gi].dstSliceOff = dof;
            ++gi; z += zc;
        };
        addg(enc_attn_W,              wt + OFF_ENCQKV,               512,  512,  262144,    262144, 3);
        addg(enc_attn_W + 4L*262144,  wt + OFF_ENCQKV + 3L*262144,   512,  512,  262144,    262144, 3);
        addg(enc_attn_W + 3L*262144,  wt + OFF_ENCO,                 512,  512,  4L*262144, 262144, 2);
        addg(enc_ff_W1,               wt + OFF_ENCW1,                2048, 512,  512,       262144, 4);
        addg(enc_ff_W1 + 1048576,     wt + OFF_ENCW1 + 1048576,      2048, 512,  512,       262144, 4);
        addg(enc_ff_W2,               wt + OFF_ENCW2,                512,  2048, 262144,    512,    4);
        addg(enc_ff_W2 + 1048576,     wt + OFF_ENCW2 + 1048576,      512,  2048, 262144,    512,    4);
        addg(dec_self_W,              wt + OFF_DECSQKV,              512,  512,  262144,    262144, 3);
        addg(dec_self_W + 4L*262144,  wt + OFF_DECSQKV + 3L*262144,  512,  512,  262144,    262144, 3);
        addg(dec_self_W + 3L*262144,  wt + OFF_DECSO,                512,  512,  4L*262144, 262144, 2);
        addg(dec_cross_W,             wt + OFF_DECCQKV,              512,  512,  262144,    262144, 3);
        addg(dec_cross_W + 4L*262144, wt + OFF_DECCQKV + 3L*262144,  512,  512,  262144,    262144, 3);
        addg(dec_cross_W + 3L*262144, wt + OFF_DECCO,                512,  512,  4L*262144, 262144, 2);
        addg(dec_ff_W1,               wt + OFF_DECW1,                2048, 512,  512,       262144, 4);
        addg(dec_ff_W1 + 1048576,     wt + OFF_DECW1 + 1048576,      2048, 512,  512,       262144, 4);
        addg(dec_ff_W2,               wt + OFF_DECW2,                512,  2048, 262144,    512,    4);
        addg(dec_ff_W2 + 1048576,     wt + OFF_DECW2 + 1048576,      512,  2048, 262144,    512,    4);
        addg(gen_W,                   wt + OFF_GENW,                 8192, 512,  512,       262144, 16);
        tt.zStart[18] = z;  // 72
    }
    prep_kernel<<<dim3(16, 8, 104), 256, 0, stream>>>(
        tt, src_tokens, tgt_tokens, src_emb, tgt_emb, xe, xd,
        enc_ln_g, enc_ln_b, dec_ln_g, dec_ln_b, nxb, nxd0);

    auto gemmK = [&](const unsigned short* A, const unsigned short* W, const float* bias,
                     const float* res, void* C, int N, int K, int ldc, bool relu, bool outbf) {
        int gx = N / 64;
        dim3 g(gx * 32);
        if (res)        gemm_bk128_kernel<false, true,  false><<<g, 256, 0, stream>>>(A, W, bias, res, C, K, ldc, gx);
        else if (relu)  gemm_bk128_kernel<true,  false, true ><<<g, 256, 0, stream>>>(A, W, bias, res, C, K, ldc, gx);
        else if (outbf) gemm_bk128_kernel<false, false, true ><<<g, 256, 0, stream>>>(A, W, bias, res, C, K, ldc, gx);
        else            gemm_bk128_kernel<false, false, false><<<g, 256, 0, stream>>>(A, W, bias, res, C, K, ldc, gx);
    };
    auto gemm128 = [&](const unsigned short* A, const unsigned short* W, const float* bias,
                       unsigned short* C, int N, int K, int ldc, bool relu) {
        dim3 g((N / 128) * 16);
        if (relu) gemm128_kernel<true ><<<g, 256, 0, stream>>>(A, W, bias, C, K, ldc);
        else      gemm128_kernel<false><<<g, 256, 0, stream>>>(A, W, bias, C, K, ldc);
    };
    auto lnb = [&](const float* x, const float* g, const float* b, unsigned short* o) {
        ln_kernel<true><<<512, 256, 0, stream>>>(x, g, b, o);
    };

    // ---- encoder ----
    for (int i = 0; i < 2; ++i) {
        if (i) lnb(xe, enc_ln_g + (size_t)(i * 2) * 512, enc_ln_b + (size_t)(i * 2) * 512, nxb);
        fattn_kernel<false, true><<<256, 512, 0, stream>>>(
            nxb, nxb, wt + OFF_ENCQKV + (size_t)i * 3 * 262144,
            enc_attn_b + (size_t)i * 4 * 512, attb);
        gemmK(attb, wt + OFF_ENCO + (size_t)i * 262144, enc_attn_b + (size_t)i * 4 * 512 + 1536,
              xe, xe, 512, 512, 512, false, false);
        lnb(xe, enc_ln_g + (size_t)(i * 2 + 1) * 512, enc_ln_b + (size_t)(i * 2 + 1) * 512, nxb);
        gemm128(nxb, wt + OFF_ENCW1 + (size_t)i * 1048576, enc_ff_b1 + (size_t)i * 2048,
                ffb, 2048, 512, 2048, true);
        gemmK(ffb, wt + OFF_ENCW2 + (size_t)i * 1048576, enc_ff_b2 + (size_t)i * 512,
              xe, xe, 512, 2048, 512, false, false);
    }
    // final enc norm + both decoder cross-LN(xe) precomputed
    ln3_kernel<<<512, 256, 0, stream>>>(
        xe, enc_norm_g, enc_norm_b,
        dec_ln_g + 512, dec_ln_b + 512,
        dec_ln_g + 4 * 512, dec_ln_b + 4 * 512,
        nkvb0, nkvb1);

    // ---- decoder ----
    for (int i = 0; i < 2; ++i) {
        const unsigned short* qsrc = (i == 0) ? nxd0 : nxb;
        if (i) lnb(xd, dec_ln_g + (size_t)(i * 3) * 512, dec_ln_b + (size_t)(i * 3) * 512, nxb);
        fattn_kernel<true, true><<<256, 512, 0, stream>>>(
            qsrc, qsrc, wt + OFF_DECSQKV + (size_t)i * 3 * 262144,
            dec_self_b + (size_t)i * 4 * 512, attb);
        gemmK(attb, wt + OFF_DECSO + (size_t)i * 262144, dec_self_b + (size_t)i * 4 * 512 + 1536,
              xd, xd, 512, 512, 512, false, false);
        lnb(xd, dec_ln_g + (size_t)(i * 3 + 1) * 512, dec_ln_b + (size_t)(i * 3 + 1) * 512, nxb);
        fattn_kernel<false, false><<<256, 512, 0, stream>>>(
            nxb, i ? nkvb1 : nkvb0, wt + OFF_DECCQKV + (size_t)i * 3 * 262144,
            dec_cross_b + (size_t)i * 4 * 512, attb);
        gemmK(attb, wt + OFF_DECCO + (size_t)i * 262144, dec_cross_b + (size_t)i * 4 * 512 + 1536,
              xd, xd, 512, 512, 512, false, false);
        lnb(xd, dec_ln_g + (size_t)(i * 3 + 2) * 512, dec_ln_b + (size_t)(i * 3 + 2) * 512, nxb);
        gemm128(nxb, wt + OFF_DECW1 + (size_t)i * 1048576, dec_ff_b1 + (size_t)i * 2048,
                ffb, 2048, 512, 2048, true);
        gemmK(ffb, wt + OFF_DECW2 + (size_t)i * 1048576, dec_ff_b2 + (size_t)i * 512,
              xd, xd, 512, 2048, 512, false, false);
    }
    lnb(xd, dec_norm_g, dec_norm_b, genin);

    // ---- generator + log_softmax ----
    gemm128(genin, wt + OFF_GENW, gen_b, logitsb, 8192, 512, 8192, false);
    logsoftmax_bf16_kernel<<<2048, 256, 0, stream>>>(logitsb, dout);
}

// Round 13
// 304.380 us; speedup vs baseline: 1.3408x; 1.0002x over previous
//
#include <hip/hip_runtime.h>

typedef __attribute__((ext_vector_type(8))) short bfx8;
typedef __attribute__((ext_vector_type(4))) float fx4;

static __device__ __forceinline__ unsigned short f2bf(float f) {
    union { float f; unsigned int u; } v; v.f = f;
    unsigned int i = v.u;
    return (unsigned short)((i + 0x7FFFu + ((i >> 16) & 1u)) >> 16);
}
static __device__ __forceinline__ float bf2f(unsigned short u) {
    union { unsigned int ui; float f; } cv;
    cv.ui = ((unsigned int)u) << 16;
    return cv.f;
}

// async global->LDS, 16B per lane; l is the WAVE-UNIFORM base (HW adds lane*16)
static __device__ __forceinline__ void gl2lds16(const unsigned short* g, unsigned short* l) {
    unsigned long long gu = (unsigned long long)g;
    unsigned int lu = (unsigned int)(unsigned long long)l;
    __builtin_amdgcn_global_load_lds(
        (const __attribute__((address_space(1))) void*)gu,
        (__attribute__((address_space(3))) void*)lu,
        16, 0, 0);
}

// ---------------- fused prep: 72 transpose slices (64k x 64n tiles) + 64 embed slices ----------------
struct TrGroup {
    const float* src;
    unsigned short* dst;
    int srcRowStride;
    int dstRowStride;
    long srcSliceOff;
    long dstSliceOff;
};
struct TrTable {
    TrGroup g[18];
    int zStart[19];
};

__global__ __launch_bounds__(256) void prep_kernel(
    TrTable tt,
    const int* __restrict__ tokA, const int* __restrict__ tokB,
    const float* __restrict__ embA, const float* __restrict__ embB,
    float* __restrict__ outA, float* __restrict__ outB,
    const float* __restrict__ gA, const float* __restrict__ bA,
    const float* __restrict__ gB, const float* __restrict__ bB,
    unsigned short* __restrict__ nxA, unsigned short* __restrict__ nxB)
{
    __shared__ unsigned short tile[2][64][37];   // k-major, pad 37: conflict-free strided read-out
    __shared__ float red[4];
    int z = blockIdx.z;
    int tid = threadIdx.x;
    if (z < 72) {
        // ---- weight transpose f32 [512k x 512n] -> bf16 [n][k], 64k x 64n per block ----
        int gi = 0;
#pragma unroll 1
        while (z >= tt.zStart[gi + 1]) ++gi;
        int zi = z - tt.zStart[gi];
        const float* s = tt.g[gi].src + (size_t)zi * tt.g[gi].srcSliceOff;
        unsigned short* d = tt.g[gi].dst + (size_t)zi * tt.g[gi].dstSliceOff;
        int srs = tt.g[gi].srcRowStride, drs = tt.g[gi].dstRowStride;
        int n0 = blockIdx.x * 64, k0 = blockIdx.y * 64;
        int kr = tid >> 3;             // 0..31
        int c4 = (tid & 7) * 4;        // 0..28
        // issue all 4 independent loads first (64 B in flight per thread)
        fx4 f[2][2];
#pragma unroll
        for (int p = 0; p < 2; ++p)
#pragma unroll
            for (int q = 0; q < 2; ++q)
                f[p][q] = *(const fx4*)(s + (size_t)(k0 + kr + p * 32) * srs + n0 + q * 32 + c4);
#pragma unroll
        for (int p = 0; p < 2; ++p)
#pragma unroll
            for (int q = 0; q < 2; ++q)
#pragma unroll
                for (int j = 0; j < 4; ++j)
                    tile[q][kr + p * 32][c4 + j] = f2bf(f[p][q][j]);
        __syncthreads();
        int nr = tid >> 3;             // 0..31 output row within half-tile
        int kc = (tid & 7) * 8;        // 0..56
#pragma unroll
        for (int q = 0; q < 2; ++q) {
            ushort4 u0, u1;
#pragma unroll
            for (int j = 0; j < 4; ++j) ((unsigned short*)&u0)[j] = tile[q][kc + j][nr];
#pragma unroll
            for (int j = 0; j < 4; ++j) ((unsigned short*)&u1)[j] = tile[q][kc + 4 + j][nr];
            unsigned short* dp = d + (size_t)(n0 + q * 32 + nr) * drs + k0 + kc;
            *(ushort4*)dp = u0;
            *(ushort4*)(dp + 4) = u1;
        }
        return;
    }
    // ---- embeddings + PE + first LN ----
    int e = (z - 72) * 64 + blockIdx.y * 8 + blockIdx.x;   // 0..4095
    int row = e & 2047;
    bool isA = e < 2048;
    const int* tok = isA ? tokA : tokB;
    const float* emb = isA ? embA : embB;
    float* out = isA ? outA : outB;
    const float* g = isA ? gA : gB;
    const float* bb = isA ? bA : bB;
    unsigned short* nx = isA ? nxA : nxB;
    int pos = row & 127;
    int t = tok[row];
    int d0 = tid, d1 = tid + 256;
    auto pe = [&](int d) {
        float ang = (float)pos * expf((float)(d & ~1) * (-9.210340371976184f / 512.0f));
        return (d & 1) ? cosf(ang) : sinf(ang);
    };
    float v0 = emb[(size_t)t * 512 + d0] * 22.627416997969522f + pe(d0);
    float v1 = emb[(size_t)t * 512 + d1] * 22.627416997969522f + pe(d1);
    out[(size_t)row * 512 + d0] = v0;
    out[(size_t)row * 512 + d1] = v1;
    int lane = tid & 63, wv = tid >> 6;
    float s = v0 + v1;
#pragma unroll
    for (int off = 32; off; off >>= 1) s += __shfl_xor(s, off);
    if (lane == 0) red[wv] = s;
    __syncthreads();
    float mu = (red[0] + red[1] + red[2] + red[3]) * (1.0f / 512.0f);
    __syncthreads();
    float q = (v0 - mu) * (v0 - mu) + (v1 - mu) * (v1 - mu);
#pragma unroll
    for (int off = 32; off; off >>= 1) q += __shfl_xor(q, off);
    if (lane == 0) red[wv] = q;
    __syncthreads();
    float rs = rsqrtf((red[0] + red[1] + red[2] + red[3]) * (1.0f / 512.0f) + 1e-5f);
    nx[(size_t)row * 512 + d0] = f2bf(g[d0] * (v0 - mu) * rs + bb[d0]);
    nx[(size_t)row * 512 + d1] = f2bf(g[d1] * (v1 - mu) * rs + bb[d1]);
}

// ---------------- layernorm row body (D=512, one wave) ----------------
static __device__ __forceinline__ void ln_row(
    const float* __restrict__ xrow, const float* __restrict__ g,
    const float* __restrict__ b, int lane, fx4& o0, fx4& o1)
{
    const fx4* xr = (const fx4*)xrow;
    fx4 a = xr[lane * 2], c = xr[lane * 2 + 1];
    float s = a[0] + a[1] + a[2] + a[3] + c[0] + c[1] + c[2] + c[3];
#pragma unroll
    for (int off = 32; off; off >>= 1) s += __shfl_xor(s, off);
    float mu = s * (1.0f / 512.0f);
    float qv = 0.f;
#pragma unroll
    for (int j = 0; j < 4; ++j) {
        float d0 = a[j] - mu; qv += d0 * d0;
        float d1 = c[j] - mu; qv += d1 * d1;
    }
#pragma unroll
    for (int off = 32; off; off >>= 1) qv += __shfl_xor(qv, off);
    float rs = rsqrtf(qv * (1.0f / 512.0f) + 1e-5f);
    const fx4* gr = (const fx4*)g;
    const fx4* br = (const fx4*)b;
    fx4 g0 = gr[lane * 2], g1 = gr[lane * 2 + 1];
    fx4 b0 = br[lane * 2], b1 = br[lane * 2 + 1];
#pragma unroll
    for (int j = 0; j < 4; ++j) {
        o0[j] = g0[j] * (a[j] - mu) * rs + b0[j];
        o1[j] = g1[j] * (c[j] - mu) * rs + b1[j];
    }
}

template<bool OUTBF>
__global__ __launch_bounds__(256) void ln_kernel(
    const float* __restrict__ x, const float* __restrict__ g,
    const float* __restrict__ b, void* __restrict__ out)
{
    int row = blockIdx.x * 4 + (threadIdx.x >> 6);
    int lane = threadIdx.x & 63;
    fx4 o0, o1;
    ln_row(x + (size_t)row * 512, g, b, lane, o0, o1);
    if (OUTBF) {
        unsigned short* orow = (unsigned short*)out + (size_t)row * 512 + lane * 8;
        ushort4 u0 = {f2bf(o0[0]), f2bf(o0[1]), f2bf(o0[2]), f2bf(o0[3])};
        ushort4 u1 = {f2bf(o1[0]), f2bf(o1[1]), f2bf(o1[2]), f2bf(o1[3])};
        *(ushort4*)orow = u0;
        *(ushort4*)(orow + 4) = u1;
    } else {
        fx4* orow = (fx4*)out + (size_t)row * 128;
        orow[lane * 2] = o0;
        orow[lane * 2 + 1] = o1;
    }
}

// fused: xe = LN(xe, enc_norm); nk0 = LN(xe', dec l0); nk1 = LN(xe', dec l1)
__global__ __launch_bounds__(256) void ln3_kernel(
    float* __restrict__ xe, const float* __restrict__ eg, const float* __restrict__ eb,
    const float* __restrict__ g0, const float* __restrict__ b0,
    const float* __restrict__ g1, const float* __restrict__ b1,
    unsigned short* __restrict__ nk0, unsigned short* __restrict__ nk1)
{
    int row = blockIdx.x * 4 + (threadIdx.x >> 6);
    int lane = threadIdx.x & 63;
    fx4 t0, t1;
    ln_row(xe + (size_t)row * 512, eg, eb, lane, t0, t1);
    fx4* orow = (fx4*)(xe + (size_t)row * 512);
    orow[lane * 2] = t0;
    orow[lane * 2 + 1] = t1;
    float s = t0[0] + t0[1] + t0[2] + t0[3] + t1[0] + t1[1] + t1[2] + t1[3];
#pragma unroll
    for (int off = 32; off; off >>= 1) s += __shfl_xor(s, off);
    float mu = s * (1.0f / 512.0f);
    float q = 0.f;
#pragma unroll
    for (int j = 0; j < 4; ++j) {
        float a = t0[j] - mu; q += a * a;
        float c = t1[j] - mu; q += c * c;
    }
#pragma unroll
    for (int off = 32; off; off >>= 1) q += __shfl_xor(q, off);
    float rs = rsqrtf(q * (1.0f / 512.0f) + 1e-5f);
    const fx4* g0r = (const fx4*)g0; const fx4* b0r = (const fx4*)b0;
    const fx4* g1r = (const fx4*)g1; const fx4* b1r = (const fx4*)b1;
    fx4 ga0 = g0r[lane * 2], ga1 = g0r[lane * 2 + 1];
    fx4 bb0 = b0r[lane * 2], bb1 = b0r[lane * 2 + 1];
    fx4 gc0 = g1r[lane * 2], gc1 = g1r[lane * 2 + 1];
    fx4 bc0 = b1r[lane * 2], bc1 = b1r[lane * 2 + 1];
    unsigned short* o0 = nk0 + (size_t)row * 512 + lane * 8;
    unsigned short* o1 = nk1 + (size_t)row * 512 + lane * 8;
    ushort4 ua0, ua1, uc0, uc1;
#pragma unroll
    for (int j = 0; j < 4; ++j) {
        float n0 = (t0[j] - mu) * rs, n1 = (t1[j] - mu) * rs;
        ((unsigned short*)&ua0)[j] = f2bf(ga0[j] * n0 + bb0[j]);
        ((unsigned short*)&ua1)[j] = f2bf(ga1[j] * n1 + bb1[j]);
        ((unsigned short*)&uc0)[j] = f2bf(gc0[j] * n0 + bc0[j]);
        ((unsigned short*)&uc1)[j] = f2bf(gc1[j] * n1 + bc1[j]);
    }
    *(ushort4*)o0 = ua0; *(ushort4*)(o0 + 4) = ua1;
    *(ushort4*)o1 = uc0; *(ushort4*)(o1 + 4) = uc1;
}

// ---------------- bf16 MFMA GEMM, 64x64 tile, BK=128 ----------------
template<bool RELU, bool RESID, bool OUTBF>
__global__ __launch_bounds__(256) void gemm_bk128_kernel(
    const unsigned short* __restrict__ A, const unsigned short* __restrict__ Wt,
    const float* __restrict__ bias, const float* __restrict__ res,
    void* __restrict__ Cv, int K, int ldc, int gx)
{
    __shared__ unsigned short smem[2][2][8192];  // [buf][A/B][64*128]
    const int tid = threadIdx.x;
    const int nwg = gridDim.x;
    const int cpx = nwg >> 3;
    const int phys = blockIdx.x;
    const int logical = (phys & 7) * cpx + (phys >> 3);
    const int bm = (logical / gx) * 64;
    const int bn = (logical % gx) * 64;
    const int lane = tid & 63;
    const int wv = tid >> 6;
    const int wr = (wv >> 1) * 32;
    const int wc = (wv & 1) * 32;
    const int lr = lane & 15;
    const int lrow4 = lane >> 4;
    const int lchk16 = lane & 15;
    fx4 acc00 = {0.f, 0.f, 0.f, 0.f}, acc01 = {0.f, 0.f, 0.f, 0.f};
    fx4 acc10 = {0.f, 0.f, 0.f, 0.f}, acc11 = {0.f, 0.f, 0.f, 0.f};

    auto stage = [&](int buf, int k0) {
#pragma unroll
        for (int j = 0; j < 4; ++j) {
            int row = wv * 16 + j * 4 + lrow4;
            int sc = (lchk16 ^ (row & 15)) * 8;
            gl2lds16(A + (size_t)(bm + row) * K + k0 + sc,
                     &smem[buf][0][(wv * 16 + j * 4) * 128]);
            gl2lds16(Wt + (size_t)(bn + row) * K + k0 + sc,
                     &smem[buf][1][(wv * 16 + j * 4) * 128]);
        }
    };

    const int nt = K >> 7;
    int cur = 0;
    stage(0, 0);
    for (int t = 0; t < nt; ++t) {
        __syncthreads();
        if (t + 1 < nt) stage(cur ^ 1, (t + 1) << 7);
        const unsigned short* bufA = &smem[cur][0][0];
        const unsigned short* bufB = &smem[cur][1][0];
        const int ra0 = wr + lr, ra1 = wr + 16 + lr;
        const int rb0 = wc + lr, rb1 = wc + 16 + lr;
        __builtin_amdgcn_s_setprio(1);
#pragma unroll
        for (int kk = 0; kk < 4; ++kk) {
            int ca = kk * 4 + (lane >> 4);
            bfx8 a0 = *(const bfx8*)&bufA[ra0 * 128 + ((ca ^ (ra0 & 15)) * 8)];
            bfx8 a1 = *(const bfx8*)&bufA[ra1 * 128 + ((ca ^ (ra1 & 15)) * 8)];
            bfx8 b0 = *(const bfx8*)&bufB[rb0 * 128 + ((ca ^ (rb0 & 15)) * 8)];
            bfx8 b1 = *(const bfx8*)&bufB[rb1 * 128 + ((ca ^ (rb1 & 15)) * 8)];
            acc00 = __builtin_amdgcn_mfma_f32_16x16x32_bf16(a0, b0, acc00, 0, 0, 0);
            acc01 = __builtin_amdgcn_mfma_f32_16x16x32_bf16(a0, b1, acc01, 0, 0, 0);
            acc10 = __builtin_amdgcn_mfma_f32_16x16x32_bf16(a1, b0, acc10, 0, 0, 0);
            acc11 = __builtin_amdgcn_mfma_f32_16x16x32_bf16(a1, b1, acc11, 0, 0, 0);
        }
        __builtin_amdgcn_s_setprio(0);
        cur ^= 1;
    }
    int rbase = bm + wr + ((lane >> 4) * 4);
    int cbase = bn + wc + lr;
#pragma unroll
    for (int m = 0; m < 2; ++m) {
        fx4 am0 = m ? acc10 : acc00;
        fx4 am1 = m ? acc11 : acc01;
#pragma unroll
        for (int r = 0; r < 4; ++r) {
            int row = rbase + m * 16 + r;
#pragma unroll
            for (int half = 0; half < 2; ++half) {
                int col = cbase + half * 16;
                float v = (half ? am1[r] : am0[r]) + bias[col];
                if (RESID) v += res[(size_t)row * ldc + col];
                if (RELU) v = fmaxf(v, 0.f);
                if (OUTBF) ((unsigned short*)Cv)[(size_t)row * ldc + col] = f2bf(v);
                else       ((float*)Cv)[(size_t)row * ldc + col] = v;
            }
        }
    }
}

// ---------------- bf16 MFMA GEMM, 128x128 tile (4 waves x 64x64), bf16 out ----------------
template<bool RELU>
__global__ __launch_bounds__(256) void gemm128_kernel(
    const unsigned short* __restrict__ A, const unsigned short* __restrict__ Wt,
    const float* __restrict__ bias, unsigned short* __restrict__ C,
    int K, int ldc)
{
    __shared__ unsigned short smem[2][2][8192];  // [buf][A/B][128*64]
    const int tid = threadIdx.x;
    const int nwg = gridDim.x;
    const int cpx = nwg >> 3;
    const int phys = blockIdx.x;
    const int logical = (phys & 7) * cpx + (phys >> 3);
    const int bm = (logical & 15) * 128;     // M = 2048 always
    const int bn = (logical >> 4) * 128;
    const int lane = tid & 63;
    const int wv = tid >> 6;
    const int wr = (wv >> 1) * 64;
    const int wc = (wv & 1) * 64;
    const int lr = lane & 15;
    const int lrow = lane >> 3;
    const int lchk = lane & 7;
    fx4 acc[4][4];
#pragma unroll
    for (int mi = 0; mi < 4; ++mi)
#pragma unroll
        for (int ni = 0; ni < 4; ++ni) acc[mi][ni] = fx4{0.f, 0.f, 0.f, 0.f};

    auto stage = [&](int buf, int k0) {
#pragma unroll
        for (int j = 0; j < 4; ++j) {
            int row = wv * 32 + j * 8 + lrow;
            int sc = lchk ^ (row & 7);
            gl2lds16(A + (size_t)(bm + row) * K + k0 + sc * 8,
                     &smem[buf][0][(wv * 32 + j * 8) * 64]);
            gl2lds16(Wt + (size_t)(bn + row) * K + k0 + sc * 8,
                     &smem[buf][1][(wv * 32 + j * 8) * 64]);
        }
    };

    const int nt = K >> 6;
    int cur = 0;
    stage(0, 0);
    for (int t = 0; t < nt; ++t) {
        __syncthreads();
        if (t + 1 < nt) stage(cur ^ 1, (t + 1) << 6);
        const unsigned short* bufA = &smem[cur][0][0];
        const unsigned short* bufB = &smem[cur][1][0];
        __builtin_amdgcn_s_setprio(1);
#pragma unroll
        for (int kk = 0; kk < 2; ++kk) {
            int ca = kk * 4 + (lane >> 4);
            bfx8 af[4], bg[4];
#pragma unroll
            for (int i = 0; i < 4; ++i) {
                int ra = wr + i * 16 + lr;
                int rb = wc + i * 16 + lr;
                af[i] = *(const bfx8*)&bufA[ra * 64 + ((ca ^ (ra & 7)) * 8)];
                bg[i] = *(const bfx8*)&bufB[rb * 64 + ((ca ^ (rb & 7)) * 8)];
            }
#pragma unroll
            for (int mi = 0; mi < 4; ++mi)
#pragma unroll
                for (int ni = 0; ni < 4; ++ni)
                    acc[mi][ni] = __builtin_amdgcn_mfma_f32_16x16x32_bf16(af[mi], bg[ni], acc[mi][ni], 0, 0, 0);
        }
        __builtin_amdgcn_s_setprio(0);
        cur ^= 1;
    }
    int rbase = bm + wr + ((lane >> 4) * 4);
    int cbase = bn + wc + lr;
#pragma unroll
    for (int mi = 0; mi < 4; ++mi)
#pragma unroll
        for (int ni = 0; ni < 4; ++ni) {
            int col = cbase + ni * 16;
            float bv = bias[col];
#pragma unroll
            for (int r = 0; r < 4; ++r) {
                int row = rbase + mi * 16 + r;
                float v = acc[mi][ni][r] + bv;
                if (RELU) v = fmaxf(v, 0.f);
                C[(size_t)row * ldc + col] = f2bf(v);
            }
        }
}

// ---------------- fused QKV-projection + attention (8 waves, region-pure proj) ----------------
template<bool CAUSAL, bool SELF>
__global__ __launch_bounds__(512) void fattn_kernel(
    const unsigned short* __restrict__ xq, const unsigned short* __restrict__ xkv,
    const unsigned short* __restrict__ Wt, const float* __restrict__ bias,
    unsigned short* __restrict__ out)
{
    constexpr int XROWS = SELF ? 128 : 192;
    constexpr int BUFB  = (XROWS + 192) * 64 * 2;
    __shared__ __align__(16) unsigned char lds[2 * BUFB + 9216 + 18432 + 17408 + 512];
    const int blk = blockIdx.x;
    const int half = blk & 1;
    const int h = (blk >> 1) & 7;
    const int b = blk >> 4;
    const int q0 = half * 64;
    const int tid = threadIdx.x;
    const int lane = tid & 63;
    const int wv = tid >> 6;
    const int lr = lane & 15;
    const int hg8 = (lane >> 4) * 8;
    const int rloc = (lane >> 4) * 4;
    const int lrow = lane >> 3;
    const int lchk = lane & 7;

    const unsigned short* gxq = xq + (size_t)(b * 128 + q0) * 512;
    const unsigned short* gkv = xkv + (size_t)(b * 128) * 512;
    const unsigned short* gw  = Wt + (size_t)(h * 64) * 512;

    auto stage = [&](int buf, int k0) {
        unsigned short* dst = (unsigned short*)(lds + buf * BUFB);
        if constexpr (SELF) {
#pragma unroll
            for (int j = 0; j < 5; ++j) {
                int start = wv * 40 + j * 8;
                int row = start + lrow;
                int sc = (lchk ^ (row & 7)) * 8;
                const unsigned short* src;
                if (start < 128) {
                    src = gkv + (size_t)row * 512 + k0 + sc;
                } else {
                    int wr_ = row - 128;
                    src = gw + ((size_t)(wr_ & 63) + (size_t)(wr_ >> 6) * 512) * 512 + k0 + sc;
                }
                gl2lds16(src, dst + start * 64);
            }
        } else {
            unsigned short* dstW = dst + XROWS * 64;
#pragma unroll
            for (int j = 0; j < 3; ++j) {
                int row = wv * 24 + j * 8 + lrow;
                int sc = (lchk ^ (row & 7)) * 8;
                const unsigned short* xs = (row < 64)
                    ? gxq + (size_t)row * 512
                    : gkv + (size_t)(row - 64) * 512;
                gl2lds16(xs + k0 + sc, dst + (wv * 24 + j * 8) * 64);
                const unsigned short* ws = gw + ((size_t)(row & 63) + (size_t)(row >> 6) * 512) * 512;
                gl2lds16(ws + k0 + sc, dstW + (wv * 24 + j * 8) * 64);
            }
        }
    };

    fx4 acc[4][4];
#pragma unroll
    for (int i = 0; i < 4; ++i)
#pragma unroll
        for (int c = 0; c < 4; ++c) acc[i][c] = fx4{0.f, 0.f, 0.f, 0.f};

    const int arowbase = (wv == 4) ? (SELF ? q0 : 0)
                                   : (SELF ? 0 : 64) + ((wv & 1) * 64);
    const int wbase = (wv == 4) ? 0 : (wv < 2 ? 64 : 128);

    stage(0, 0);
#pragma unroll 1
    for (int t = 0; t < 8; ++t) {
        __syncthreads();
        if (t < 7) stage((t + 1) & 1, (t + 1) * 64);
        const unsigned short* stX = (const unsigned short*)(lds + (t & 1) * BUFB);
        const unsigned short* stW = stX + XROWS * 64;
        if (wv < 5) {
#pragma unroll
            for (int kk = 0; kk < 2; ++kk) {
                const int ca = kk * 4 + (lane >> 4);
                auto rd = [&](const unsigned short* base, int row) -> bfx8 {
                    return *(const bfx8*)(base + row * 64 + ((ca ^ (row & 7)) * 8));
                };
                bfx8 af[4];
#pragma unroll
                for (int i = 0; i < 4; ++i) af[i] = rd(stX, arowbase + i * 16 + lr);
                __builtin_amdgcn_s_setprio(1);
#pragma unroll
                for (int c = 0; c < 4; ++c) {
                    bfx8 bf = rd(stW, wbase + c * 16 + lr);
#pragma unroll
                    for (int i = 0; i < 4; ++i)
                        acc[i][c] = __builtin_amdgcn_mfma_f32_16x16x32_bf16(af[i], bf, acc[i][c], 0, 0, 0);
                }
                __builtin_amdgcn_s_setprio(0);
            }
        }
    }
    unsigned short* sQ  = (unsigned short*)(lds + 2 * BUFB);
    unsigned short* sK  = (unsigned short*)(lds + 2 * BUFB + 9216);
    unsigned short* sVt = (unsigned short*)(lds + 2 * BUFB + 9216 + 18432);
    float* zp = (float*)(lds + 2 * BUFB + 9216 + 18432 + 17408);
    unsigned short* sP  = (unsigned short*)lds;
    if (wv == 4) {
#pragma unroll
        for (int c = 0; c < 4; ++c) {
            int col = c * 16 + lr;
            float bq_ = bias[h * 64 + col];
#pragma unroll
            for (int i = 0; i < 4; ++i)
#pragma unroll
                for (int r = 0; r < 4; ++r)
                    sQ[(i * 16 + rloc + r) * 72 + col] = f2bf(acc[i][c][r] + bq_);
        }
    } else if (wv < 2) {
        int rb = wv * 64;
#pragma unroll
        for (int c = 0; c < 4; ++c) {
            int col = c * 16 + lr;
            float bk_ = bias[512 + h * 64 + col];
#pragma unroll
            for (int i = 0; i < 4; ++i)
#pragma unroll
                for (int r = 0; r < 4; ++r)
                    sK[(rb + i * 16 + rloc + r) * 72 + col] = f2bf(acc[i][c][r] + bk_);
        }
    } else if (wv < 4) {
        int rb = (wv - 2) * 64;
#pragma unroll
        for (int c = 0; c < 4; ++c) {
            int col = c * 16 + lr;
            float bv_ = bias[1024 + h * 64 + col];
#pragma unroll
            for (int i = 0; i < 4; ++i)
#pragma unroll
                for (int r = 0; r < 4; ++r)
                    sVt[col * 136 + (rb + i * 16 + rloc + r)] = f2bf(acc[i][c][r] + bv_);
        }
    }
    __syncthreads();
    const int qb = wv >> 1;
    const int kh = wv & 1;
    fx4 sacc[4];
#pragma unroll
    for (int n = 0; n < 4; ++n) sacc[n] = fx4{0.f, 0.f, 0.f, 0.f};
#pragma unroll
    for (int kk = 0; kk < 2; ++kk) {
        bfx8 a = *(const bfx8*)(sQ + (qb * 16 + lr) * 72 + kk * 32 + hg8);
#pragma unroll
        for (int n = 0; n < 4; ++n) {
            bfx8 bb = *(const bfx8*)(sK + ((kh * 4 + n) * 16 + lr) * 72 + kk * 32 + hg8);
            sacc[n] = __builtin_amdgcn_mfma_f32_16x16x32_bf16(a, bb, sacc[n], 0, 0, 0);
        }
    }
    const int qg = q0 + qb * 16 + rloc;
#pragma unroll
    for (int r = 0; r < 4; ++r) {
        float zs = 0.f;
#pragma unroll
        for (int n = 0; n < 4; ++n) {
            float s = sacc[n][r] * 0.125f;
            s = __expf(fminf(fmaxf(s, -5.f), 5.f));
            if (CAUSAL && (kh * 64 + n * 16 + lr) > (qg + r)) s = 0.f;
            zs += s;
            sP[(qb * 16 + rloc + r) * 136 + kh * 64 + n * 16 + lr] = f2bf(s);
        }
#pragma unroll
        for (int off = 8; off; off >>= 1) zs += __shfl_xor(zs, off);
        if (lr == 0) zp[(qb * 2 + kh) * 16 + rloc + r] = zs;
    }
    __syncthreads();
    float zinv[4];
#pragma unroll
    for (int r = 0; r < 4; ++r)
        zinv[r] = 1.f / (zp[(qb * 2 + 0) * 16 + rloc + r] + zp[(qb * 2 + 1) * 16 + rloc + r]);
    const int dh = wv & 1;
    fx4 acc2[2];
    acc2[0] = fx4{0.f, 0.f, 0.f, 0.f};
    acc2[1] = fx4{0.f, 0.f, 0.f, 0.f};
#pragma unroll
    for (int kk = 0; kk < 4; ++kk) {
        bfx8 a = *(const bfx8*)(sP + (qb * 16 + lr) * 136 + kk * 32 + hg8);
#pragma unroll
        for (int dn = 0; dn < 2; ++dn) {
            bfx8 bb = *(const bfx8*)(sVt + (dh * 32 + dn * 16 + lr) * 136 + kk * 32 + hg8);
            acc2[dn] = __builtin_amdgcn_mfma_f32_16x16x32_bf16(a, bb, acc2[dn], 0, 0, 0);
        }
    }
#pragma unroll
    for (int dn = 0; dn < 2; ++dn)
#pragma unroll
        for (int r = 0; r < 4; ++r) {
            size_t row = (size_t)(b * 128 + qg + r);
            out[row * 512 + h * 64 + dh * 32 + dn * 16 + lr] = f2bf(acc2[dn][r] * zinv[r]);
        }
}

// ---------------- log_softmax: bf16 logits [2048,8192] -> f32 out ----------------
__global__ __launch_bounds__(256) void logsoftmax_bf16_kernel(
    const unsigned short* __restrict__ logits, float* __restrict__ out)
{
    __shared__ float red[4];
    int tid = threadIdx.x;
    const bfx8* lrow = (const bfx8*)(logits + (size_t)blockIdx.x * 8192);
    float* orow = out + (size_t)blockIdx.x * 8192;
    float vals[32];
    float mx = -1e30f;
#pragma unroll
    for (int i = 0; i < 4; ++i) {
        bfx8 u = lrow[i * 256 + tid];
#pragma unroll
        for (int j = 0; j < 8; ++j) {
            float f = bf2f((unsigned short)u[j]);
            vals[i * 8 + j] = f;
            mx = fmaxf(mx, f);
        }
    }
#pragma unroll
    for (int off = 32; off; off >>= 1) mx = fmaxf(mx, __shfl_xor(mx, off));
    int wid = tid >> 6;
    if ((tid & 63) == 0) red[wid] = mx;
    __syncthreads();
    mx = fmaxf(fmaxf(red[0], red[1]), fmaxf(red[2], red[3]));
    __syncthreads();
    float sum = 0.f;
#pragma unroll
    for (int i = 0; i < 32; ++i) sum += __expf(vals[i] - mx);
#pragma unroll
    for (int off = 32; off; off >>= 1) sum += __shfl_xor(sum, off);
    if ((tid & 63) == 0) red[wid] = sum;
    __syncthreads();
    sum = red[0] + red[1] + red[2] + red[3];
    float lsub = mx + logf(sum);
#pragma unroll
    for (int i = 0; i < 4; ++i) {
        fx4 o0, o1;
#pragma unroll
        for (int j = 0; j < 4; ++j) {
            o0[j] = vals[i * 8 + j] - lsub;
            o1[j] = vals[i * 8 + 4 + j] - lsub;
        }
        ((fx4*)orow)[(i * 256 + tid) * 2] = o0;
        ((fx4*)orow)[(i * 256 + tid) * 2 + 1] = o1;
    }
}

extern "C" void kernel_launch(void* const* d_in, const int* in_sizes, int n_in,
                              void* d_out, int out_size, void* d_ws, size_t ws_size,
                              hipStream_t stream) {
    (void)in_sizes; (void)n_in; (void)out_size; (void)ws_size;
    const int* src_tokens = (const int*)d_in[0];
    const int* tgt_tokens = (const int*)d_in[1];
    const float* src_emb    = (const float*)d_in[8];
    const float* tgt_emb    = (const float*)d_in[9];
    const float* enc_attn_W = (const float*)d_in[10];
    const float* enc_attn_b = (const float*)d_in[11];
    const float* enc_ln_g   = (const float*)d_in[12];
    const float* enc_ln_b   = (const float*)d_in[13];
    const float* enc_ff_W1  = (const float*)d_in[14];
    const float* enc_ff_b1  = (const float*)d_in[15];
    const float* enc_ff_W2  = (const float*)d_in[16];
    const float* enc_ff_b2  = (const float*)d_in[17];
    const float* enc_norm_g = (const float*)d_in[18];
    const float* enc_norm_b = (const float*)d_in[19];
    const float* dec_self_W = (const float*)d_in[20];
    const float* dec_self_b = (const float*)d_in[21];
    const float* dec_cross_W= (const float*)d_in[22];
    const float* dec_cross_b= (const float*)d_in[23];
    const float* dec_ln_g   = (const float*)d_in[24];
    const float* dec_ln_b   = (const float*)d_in[25];
    const float* dec_ff_W1  = (const float*)d_in[26];
    const float* dec_ff_b1  = (const float*)d_in[27];
    const float* dec_ff_W2  = (const float*)d_in[28];
    const float* dec_ff_b2  = (const float*)d_in[29];
    const float* dec_norm_g = (const float*)d_in[30];
    const float* dec_norm_b = (const float*)d_in[31];
    const float* gen_W      = (const float*)d_in[32];
    const float* gen_b      = (const float*)d_in[33];
    float* dout = (float*)d_out;

    // ---- workspace layout ----
    unsigned short* wt = (unsigned short*)d_ws;
    const size_t OFF_ENCQKV = 0;
    const size_t OFF_ENCO   = 1572864;
    const size_t OFF_ENCW1  = 2097152;
    const size_t OFF_ENCW2  = 4194304;
    const size_t OFF_DECSQKV= 6291456;
    const size_t OFF_DECSO  = 7864320;
    const size_t OFF_DECCQKV= 8388608;
    const size_t OFF_DECCO  = 9961472;
    const size_t OFF_DECW1  = 10485760;
    const size_t OFF_DECW2  = 12582912;
    const size_t OFF_GENW   = 14680064;
    const size_t WT_ELEMS   = 18874368;
    float* fb  = (float*)(wt + WT_ELEMS);
    float* xe  = fb;
    float* xd  = fb + 1048576;
    unsigned short* nxb   = (unsigned short*)(fb + 2097152);
    unsigned short* nxd0  = (unsigned short*)(fb + 3145728);
    unsigned short* ffb   = (unsigned short*)(fb + 4194304);  // [2048,2048] bf16
    unsigned short* nkvb0 = (unsigned short*)(fb + 6291456);  // [2048,512] bf16
    unsigned short* nkvb1 = (unsigned short*)(fb + 6815744);  // [2048,512] bf16
    unsigned short* attb  = (unsigned short*)(fb + 7340032);  // [2048,512] bf16
    unsigned short* genin   = (unsigned short*)fb;             // aliases xe (dead)
    unsigned short* logitsb = (unsigned short*)(fb + 1048576); // aliases xd.. (dead)

    // ---- single-launch prep: weight transpose + embeddings + first LN ----
    TrTable tt;
    {
        int z = 0, gi = 0;
        auto addg = [&](const float* s, unsigned short* d, int srs, int drs,
                        long so, long dof, int zc) {
            tt.zStart[gi] = z;
            tt.g[gi].src = s; tt.g[gi].dst = d;
            tt.g[gi].srcRowStride = srs; tt.g[gi].dstRowStride = drs;
            tt.g[gi].srcSliceOff = so; tt.g[gi].dstSliceOff = dof;
            ++gi; z += zc;
        };
        addg(enc_attn_W,              wt + OFF_ENCQKV,               512,  512,  262144,    262144, 3);
        addg(enc_attn_W + 4L*262144,  wt + OFF_ENCQKV + 3L*262144,   512,  512,  262144,    262144, 3);
        addg(enc_attn_W + 3L*262144,  wt + OFF_ENCO,                 512,  512,  4L*262144, 262144, 2);
        addg(enc_ff_W1,               wt + OFF_ENCW1,                2048, 512,  512,       262144, 4);
        addg(enc_ff_W1 + 1048576,     wt + OFF_ENCW1 + 1048576,      2048, 512,  512,       262144, 4);
        addg(enc_ff_W2,               wt + OFF_ENCW2,                512,  2048, 262144,    512,    4);
        addg(enc_ff_W2 + 1048576,     wt + OFF_ENCW2 + 1048576,      512,  2048, 262144,    512,    4);
        addg(dec_self_W,              wt + OFF_DECSQKV,              512,  512,  262144,    262144, 3);
        addg(dec_self_W + 4L*262144,  wt + OFF_DECSQKV + 3L*262144,  512,  512,  262144,    262144, 3);
        addg(dec_self_W + 3L*262144,  wt + OFF_DECSO,                512,  512,  4L*262144, 262144, 2);
        addg(dec_cross_W,             wt + OFF_DECCQKV,              512,  512,  262144,    262144, 3);
        addg(dec_cross_W + 4L*262144, wt + OFF_DECCQKV + 3L*262144,  512,  512,  262144,    262144, 3);
        addg(dec_cross_W + 3L*262144, wt + OFF_DECCO,                512,  512,  4L*262144, 262144, 2);
        addg(dec_ff_W1,               wt + OFF_DECW1,                2048, 512,  512,       262144, 4);
        addg(dec_ff_W1 + 1048576,     wt + OFF_DECW1 + 1048576,      2048, 512,  512,       262144, 4);
        addg(dec_ff_W2,               wt + OFF_DECW2,                512,  2048, 262144,    512,    4);
        addg(dec_ff_W2 + 1048576,     wt + OFF_DECW2 + 1048576,      512,  2048, 262144,    512,    4);
        addg(gen_W,                   wt + OFF_GENW,                 8192, 512,  512,       262144, 16);
        tt.zStart[18] = z;  // 72
    }
    prep_kernel<<<dim3(8, 8, 136), 256, 0, stream>>>(
        tt, src_tokens, tgt_tokens, src_emb, tgt_emb, xe, xd,
        enc_ln_g, enc_ln_b, dec_ln_g, dec_ln_b, nxb, nxd0);

    auto gemmK = [&](const unsigned short* A, const unsigned short* W, const float* bias,
                     const float* res, void* C, int N, int K, int ldc, bool relu, bool outbf) {
        int gx = N / 64;
        dim3 g(gx * 32);
        if (res)        gemm_bk128_kernel<false, true,  false><<<g, 256, 0, stream>>>(A, W, bias, res, C, K, ldc, gx);
        else if (relu)  gemm_bk128_kernel<true,  false, true ><<<g, 256, 0, stream>>>(A, W, bias, res, C, K, ldc, gx);
        else if (outbf) gemm_bk128_kernel<false, false, true ><<<g, 256, 0, stream>>>(A, W, bias, res, C, K, ldc, gx);
        else            gemm_bk128_kernel<false, false, false><<<g, 256, 0, stream>>>(A, W, bias, res, C, K, ldc, gx);
    };
    auto gemm128 = [&](const unsigned short* A, const unsigned short* W, const float* bias,
                       unsigned short* C, int N, int K, int ldc, bool relu) {
        dim3 g((N / 128) * 16);
        if (relu) gemm128_kernel<true ><<<g, 256, 0, stream>>>(A, W, bias, C, K, ldc);
        else      gemm128_kernel<false><<<g, 256, 0, stream>>>(A, W, bias, C, K, ldc);
    };
    auto lnb = [&](const float* x, const float* g, const float* b, unsigned short* o) {
        ln_kernel<true><<<512, 256, 0, stream>>>(x, g, b, o);
    };

    // ---- encoder ----
    for (int i = 0; i < 2; ++i) {
        if (i) lnb(xe, enc_ln_g + (size_t)(i * 2) * 512, enc_ln_b + (size_t)(i * 2) * 512, nxb);
        fattn_kernel<false, true><<<256, 512, 0, stream>>>(
            nxb, nxb, wt + OFF_ENCQKV + (size_t)i * 3 * 262144,
            enc_attn_b + (size_t)i * 4 * 512, attb);
        gemmK(attb, wt + OFF_ENCO + (size_t)i * 262144, enc_attn_b + (size_t)i * 4 * 512 + 1536,
              xe, xe, 512, 512, 512, false, false);
        lnb(xe, enc_ln_g + (size_t)(i * 2 + 1) * 512, enc_ln_b + (size_t)(i * 2 + 1) * 512, nxb);
        gemm128(nxb, wt + OFF_ENCW1 + (size_t)i * 1048576, enc_ff_b1 + (size_t)i * 2048,
                ffb, 2048, 512, 2048, true);
        gemmK(ffb, wt + OFF_ENCW2 + (size_t)i * 1048576, enc_ff_b2 + (size_t)i * 512,
              xe, xe, 512, 2048, 512, false, false);
    }
    // final enc norm + both decoder cross-LN(xe) precomputed
    ln3_kernel<<<512, 256, 0, stream>>>(
        xe, enc_norm_g, enc_norm_b,
        dec_ln_g + 512, dec_ln_b + 512,
        dec_ln_g + 4 * 512, dec_ln_b + 4 * 512,
        nkvb0, nkvb1);

    // ---- decoder ----
    for (int i = 0; i < 2; ++i) {
        const unsigned short* qsrc = (i == 0) ? nxd0 : nxb;
        if (i) lnb(xd, dec_ln_g + (size_t)(i * 3) * 512, dec_ln_b + (size_t)(i * 3) * 512, nxb);
        fattn_kernel<true, true><<<256, 512, 0, stream>>>(
            qsrc, qsrc, wt + OFF_DECSQKV + (size_t)i * 3 * 262144,
            dec_self_b + (size_t)i * 4 * 512, attb);
        gemmK(attb, wt + OFF_DECSO + (size_t)i * 262144, dec_self_b + (size_t)i * 4 * 512 + 1536,
              xd, xd, 512, 512, 512, false, false);
        lnb(xd, dec_ln_g + (size_t)(i * 3 + 1) * 512, dec_ln_b + (size_t)(i * 3 + 1) * 512, nxb);
        fattn_kernel<false, false><<<256, 512, 0, stream>>>(
            nxb, i ? nkvb1 : nkvb0, wt + OFF_DECCQKV + (size_t)i * 3 * 262144,
            dec_cross_b + (size_t)i * 4 * 512, attb);
        gemmK(attb, wt + OFF_DECCO + (size_t)i * 262144, dec_cross_b + (size_t)i * 4 * 512 + 1536,
              xd, xd, 512, 512, 512, false, false);
        lnb(xd, dec_ln_g + (size_t)(i * 3 + 2) * 512, dec_ln_b + (size_t)(i * 3 + 2) * 512, nxb);
        gemm128(nxb, wt + OFF_DECW1 + (size_t)i * 1048576, dec_ff_b1 + (size_t)i * 2048,
                ffb, 2048, 512, 2048, true);
        gemmK(ffb, wt + OFF_DECW2 + (size_t)i * 1048576, dec_ff_b2 + (size_t)i * 512,
              xd, xd, 512, 2048, 512, false, false);
    }
    lnb(xd, dec_norm_g, dec_norm_b, genin);

    // ---- generator + log_softmax ----
    gemm128(genin, wt + OFF_GENW, gen_b, logitsb, 8192, 512, 8192, false);
    logsoftmax_bf16_kernel<<<2048, 256, 0, stream>>>(logitsb, dout);
}

// Round 14
// 301.704 us; speedup vs baseline: 1.3527x; 1.0089x over previous
//
#include <hip/hip_runtime.h>

typedef __attribute__((ext_vector_type(8))) short bfx8;
typedef __attribute__((ext_vector_type(4))) float fx4;

static __device__ __forceinline__ unsigned short f2bf(float f) {
    union { float f; unsigned int u; } v; v.f = f;
    unsigned int i = v.u;
    return (unsigned short)((i + 0x7FFFu + ((i >> 16) & 1u)) >> 16);
}
static __device__ __forceinline__ float bf2f(unsigned short u) {
    union { unsigned int ui; float f; } cv;
    cv.ui = ((unsigned int)u) << 16;
    return cv.f;
}

// async global->LDS, 16B per lane; l is the WAVE-UNIFORM base (HW adds lane*16)
static __device__ __forceinline__ void gl2lds16(const unsigned short* g, unsigned short* l) {
    unsigned long long gu = (unsigned long long)g;
    unsigned int lu = (unsigned int)(unsigned long long)l;
    __builtin_amdgcn_global_load_lds(
        (const __attribute__((address_space(1))) void*)gu,
        (__attribute__((address_space(3))) void*)lu,
        16, 0, 0);
}

// ---------------- fused prep: 72 transpose slices (64k x 64n tiles) + 64 embed slices ----------------
struct TrGroup {
    const float* src;
    unsigned short* dst;
    int srcRowStride;
    int dstRowStride;
    long srcSliceOff;
    long dstSliceOff;
};
struct TrTable {
    TrGroup g[18];
    int zStart[19];
};

__global__ __launch_bounds__(256) void prep_kernel(
    TrTable tt,
    const int* __restrict__ tokA, const int* __restrict__ tokB,
    const float* __restrict__ embA, const float* __restrict__ embB,
    float* __restrict__ outA, float* __restrict__ outB,
    const float* __restrict__ gA, const float* __restrict__ bA,
    const float* __restrict__ gB, const float* __restrict__ bB,
    unsigned short* __restrict__ nxA, unsigned short* __restrict__ nxB)
{
    __shared__ unsigned short tile[2][64][37];
    __shared__ float red[4];
    int z = blockIdx.z;
    int tid = threadIdx.x;
    if (z < 72) {
        int gi = 0;
#pragma unroll 1
        while (z >= tt.zStart[gi + 1]) ++gi;
        int zi = z - tt.zStart[gi];
        const float* s = tt.g[gi].src + (size_t)zi * tt.g[gi].srcSliceOff;
        unsigned short* d = tt.g[gi].dst + (size_t)zi * tt.g[gi].dstSliceOff;
        int srs = tt.g[gi].srcRowStride, drs = tt.g[gi].dstRowStride;
        int n0 = blockIdx.x * 64, k0 = blockIdx.y * 64;
        int kr = tid >> 3;
        int c4 = (tid & 7) * 4;
        fx4 f[2][2];
#pragma unroll
        for (int p = 0; p < 2; ++p)
#pragma unroll
            for (int q = 0; q < 2; ++q)
                f[p][q] = *(const fx4*)(s + (size_t)(k0 + kr + p * 32) * srs + n0 + q * 32 + c4);
#pragma unroll
        for (int p = 0; p < 2; ++p)
#pragma unroll
            for (int q = 0; q < 2; ++q)
#pragma unroll
                for (int j = 0; j < 4; ++j)
                    tile[q][kr + p * 32][c4 + j] = f2bf(f[p][q][j]);
        __syncthreads();
        int nr = tid >> 3;
        int kc = (tid & 7) * 8;
#pragma unroll
        for (int q = 0; q < 2; ++q) {
            ushort4 u0, u1;
#pragma unroll
            for (int j = 0; j < 4; ++j) ((unsigned short*)&u0)[j] = tile[q][kc + j][nr];
#pragma unroll
            for (int j = 0; j < 4; ++j) ((unsigned short*)&u1)[j] = tile[q][kc + 4 + j][nr];
            unsigned short* dp = d + (size_t)(n0 + q * 32 + nr) * drs + k0 + kc;
            *(ushort4*)dp = u0;
            *(ushort4*)(dp + 4) = u1;
        }
        return;
    }
    int e = (z - 72) * 64 + blockIdx.y * 8 + blockIdx.x;
    int row = e & 2047;
    bool isA = e < 2048;
    const int* tok = isA ? tokA : tokB;
    const float* emb = isA ? embA : embB;
    float* out = isA ? outA : outB;
    const float* g = isA ? gA : gB;
    const float* bb = isA ? bA : bB;
    unsigned short* nx = isA ? nxA : nxB;
    int pos = row & 127;
    int t = tok[row];
    int d0 = tid, d1 = tid + 256;
    auto pe = [&](int d) {
        float ang = (float)pos * expf((float)(d & ~1) * (-9.210340371976184f / 512.0f));
        return (d & 1) ? cosf(ang) : sinf(ang);
    };
    float v0 = emb[(size_t)t * 512 + d0] * 22.627416997969522f + pe(d0);
    float v1 = emb[(size_t)t * 512 + d1] * 22.627416997969522f + pe(d1);
    out[(size_t)row * 512 + d0] = v0;
    out[(size_t)row * 512 + d1] = v1;
    int lane = tid & 63, wv = tid >> 6;
    float s = v0 + v1;
#pragma unroll
    for (int off = 32; off; off >>= 1) s += __shfl_xor(s, off);
    if (lane == 0) red[wv] = s;
    __syncthreads();
    float mu = (red[0] + red[1] + red[2] + red[3]) * (1.0f / 512.0f);
    __syncthreads();
    float q = (v0 - mu) * (v0 - mu) + (v1 - mu) * (v1 - mu);
#pragma unroll
    for (int off = 32; off; off >>= 1) q += __shfl_xor(q, off);
    if (lane == 0) red[wv] = q;
    __syncthreads();
    float rs = rsqrtf((red[0] + red[1] + red[2] + red[3]) * (1.0f / 512.0f) + 1e-5f);
    nx[(size_t)row * 512 + d0] = f2bf(g[d0] * (v0 - mu) * rs + bb[d0]);
    nx[(size_t)row * 512 + d1] = f2bf(g[d1] * (v1 - mu) * rs + bb[d1]);
}

// ---------------- layernorm row body (D=512, one wave) ----------------
static __device__ __forceinline__ void ln_row(
    const float* __restrict__ xrow, const float* __restrict__ g,
    const float* __restrict__ b, int lane, fx4& o0, fx4& o1)
{
    const fx4* xr = (const fx4*)xrow;
    fx4 a = xr[lane * 2], c = xr[lane * 2 + 1];
    float s = a[0] + a[1] + a[2] + a[3] + c[0] + c[1] + c[2] + c[3];
#pragma unroll
    for (int off = 32; off; off >>= 1) s += __shfl_xor(s, off);
    float mu = s * (1.0f / 512.0f);
    float qv = 0.f;
#pragma unroll
    for (int j = 0; j < 4; ++j) {
        float d0 = a[j] - mu; qv += d0 * d0;
        float d1 = c[j] - mu; qv += d1 * d1;
    }
#pragma unroll
    for (int off = 32; off; off >>= 1) qv += __shfl_xor(qv, off);
    float rs = rsqrtf(qv * (1.0f / 512.0f) + 1e-5f);
    const fx4* gr = (const fx4*)g;
    const fx4* br = (const fx4*)b;
    fx4 g0 = gr[lane * 2], g1 = gr[lane * 2 + 1];
    fx4 b0 = br[lane * 2], b1 = br[lane * 2 + 1];
#pragma unroll
    for (int j = 0; j < 4; ++j) {
        o0[j] = g0[j] * (a[j] - mu) * rs + b0[j];
        o1[j] = g1[j] * (c[j] - mu) * rs + b1[j];
    }
}

template<bool OUTBF>
__global__ __launch_bounds__(256) void ln_kernel(
    const float* __restrict__ x, const float* __restrict__ g,
    const float* __restrict__ b, void* __restrict__ out)
{
    int row = blockIdx.x * 4 + (threadIdx.x >> 6);
    int lane = threadIdx.x & 63;
    fx4 o0, o1;
    ln_row(x + (size_t)row * 512, g, b, lane, o0, o1);
    if (OUTBF) {
        unsigned short* orow = (unsigned short*)out + (size_t)row * 512 + lane * 8;
        ushort4 u0 = {f2bf(o0[0]), f2bf(o0[1]), f2bf(o0[2]), f2bf(o0[3])};
        ushort4 u1 = {f2bf(o1[0]), f2bf(o1[1]), f2bf(o1[2]), f2bf(o1[3])};
        *(ushort4*)orow = u0;
        *(ushort4*)(orow + 4) = u1;
    } else {
        fx4* orow = (fx4*)out + (size_t)row * 128;
        orow[lane * 2] = o0;
        orow[lane * 2 + 1] = o1;
    }
}

// fused: xe = LN(xe, enc_norm); nk0 = LN(xe', dec l0); nk1 = LN(xe', dec l1)
__global__ __launch_bounds__(256) void ln3_kernel(
    float* __restrict__ xe, const float* __restrict__ eg, const float* __restrict__ eb,
    const float* __restrict__ g0, const float* __restrict__ b0,
    const float* __restrict__ g1, const float* __restrict__ b1,
    unsigned short* __restrict__ nk0, unsigned short* __restrict__ nk1)
{
    int row = blockIdx.x * 4 + (threadIdx.x >> 6);
    int lane = threadIdx.x & 63;
    fx4 t0, t1;
    ln_row(xe + (size_t)row * 512, eg, eb, lane, t0, t1);
    fx4* orow = (fx4*)(xe + (size_t)row * 512);
    orow[lane * 2] = t0;
    orow[lane * 2 + 1] = t1;
    float s = t0[0] + t0[1] + t0[2] + t0[3] + t1[0] + t1[1] + t1[2] + t1[3];
#pragma unroll
    for (int off = 32; off; off >>= 1) s += __shfl_xor(s, off);
    float mu = s * (1.0f / 512.0f);
    float q = 0.f;
#pragma unroll
    for (int j = 0; j < 4; ++j) {
        float a = t0[j] - mu; q += a * a;
        float c = t1[j] - mu; q += c * c;
    }
#pragma unroll
    for (int off = 32; off; off >>= 1) q += __shfl_xor(q, off);
    float rs = rsqrtf(q * (1.0f / 512.0f) + 1e-5f);
    const fx4* g0r = (const fx4*)g0; const fx4* b0r = (const fx4*)b0;
    const fx4* g1r = (const fx4*)g1; const fx4* b1r = (const fx4*)b1;
    fx4 ga0 = g0r[lane * 2], ga1 = g0r[lane * 2 + 1];
    fx4 bb0 = b0r[lane * 2], bb1 = b0r[lane * 2 + 1];
    fx4 gc0 = g1r[lane * 2], gc1 = g1r[lane * 2 + 1];
    fx4 bc0 = b1r[lane * 2], bc1 = b1r[lane * 2 + 1];
    unsigned short* o0 = nk0 + (size_t)row * 512 + lane * 8;
    unsigned short* o1 = nk1 + (size_t)row * 512 + lane * 8;
    ushort4 ua0, ua1, uc0, uc1;
#pragma unroll
    for (int j = 0; j < 4; ++j) {
        float n0 = (t0[j] - mu) * rs, n1 = (t1[j] - mu) * rs;
        ((unsigned short*)&ua0)[j] = f2bf(ga0[j] * n0 + bb0[j]);
        ((unsigned short*)&ua1)[j] = f2bf(ga1[j] * n1 + bb1[j]);
        ((unsigned short*)&uc0)[j] = f2bf(gc0[j] * n0 + bc0[j]);
        ((unsigned short*)&uc1)[j] = f2bf(gc1[j] * n1 + bc1[j]);
    }
    *(ushort4*)o0 = ua0; *(ushort4*)(o0 + 4) = ua1;
    *(ushort4*)o1 = uc0; *(ushort4*)(o1 + 4) = uc1;
}

// ---------------- bf16 MFMA GEMM, 64x64 tile, BK=128 ----------------
template<bool RELU, bool RESID, bool OUTBF>
__global__ __launch_bounds__(256) void gemm_bk128_kernel(
    const unsigned short* __restrict__ A, const unsigned short* __restrict__ Wt,
    const float* __restrict__ bias, const float* __restrict__ res,
    void* __restrict__ Cv, int K, int ldc, int gx)
{
    __shared__ unsigned short smem[2][2][8192];  // [buf][A/B][64*128]
    const int tid = threadIdx.x;
    const int nwg = gridDim.x;
    const int cpx = nwg >> 3;
    const int phys = blockIdx.x;
    const int logical = (phys & 7) * cpx + (phys >> 3);
    const int bm = (logical / gx) * 64;
    const int bn = (logical % gx) * 64;
    const int lane = tid & 63;
    const int wv = tid >> 6;
    const int wr = (wv >> 1) * 32;
    const int wc = (wv & 1) * 32;
    const int lr = lane & 15;
    const int lrow4 = lane >> 4;
    const int lchk16 = lane & 15;
    fx4 acc00 = {0.f, 0.f, 0.f, 0.f}, acc01 = {0.f, 0.f, 0.f, 0.f};
    fx4 acc10 = {0.f, 0.f, 0.f, 0.f}, acc11 = {0.f, 0.f, 0.f, 0.f};

    auto stage = [&](int buf, int k0) {
#pragma unroll
        for (int j = 0; j < 4; ++j) {
            int row = wv * 16 + j * 4 + lrow4;
            int sc = (lchk16 ^ (row & 15)) * 8;
            gl2lds16(A + (size_t)(bm + row) * K + k0 + sc,
                     &smem[buf][0][(wv * 16 + j * 4) * 128]);
            gl2lds16(Wt + (size_t)(bn + row) * K + k0 + sc,
                     &smem[buf][1][(wv * 16 + j * 4) * 128]);
        }
    };

    const int nt = K >> 7;
    int cur = 0;
    stage(0, 0);
    for (int t = 0; t < nt; ++t) {
        __syncthreads();
        if (t + 1 < nt) stage(cur ^ 1, (t + 1) << 7);
        const unsigned short* bufA = &smem[cur][0][0];
        const unsigned short* bufB = &smem[cur][1][0];
        const int ra0 = wr + lr, ra1 = wr + 16 + lr;
        const int rb0 = wc + lr, rb1 = wc + 16 + lr;
        __builtin_amdgcn_s_setprio(1);
#pragma unroll
        for (int kk = 0; kk < 4; ++kk) {
            int ca = kk * 4 + (lane >> 4);
            bfx8 a0 = *(const bfx8*)&bufA[ra0 * 128 + ((ca ^ (ra0 & 15)) * 8)];
            bfx8 a1 = *(const bfx8*)&bufA[ra1 * 128 + ((ca ^ (ra1 & 15)) * 8)];
            bfx8 b0 = *(const bfx8*)&bufB[rb0 * 128 + ((ca ^ (rb0 & 15)) * 8)];
            bfx8 b1 = *(const bfx8*)&bufB[rb1 * 128 + ((ca ^ (rb1 & 15)) * 8)];
            acc00 = __builtin_amdgcn_mfma_f32_16x16x32_bf16(a0, b0, acc00, 0, 0, 0);
            acc01 = __builtin_amdgcn_mfma_f32_16x16x32_bf16(a0, b1, acc01, 0, 0, 0);
            acc10 = __builtin_amdgcn_mfma_f32_16x16x32_bf16(a1, b0, acc10, 0, 0, 0);
            acc11 = __builtin_amdgcn_mfma_f32_16x16x32_bf16(a1, b1, acc11, 0, 0, 0);
        }
        __builtin_amdgcn_s_setprio(0);
        cur ^= 1;
    }
    int rbase = bm + wr + ((lane >> 4) * 4);
    int cbase = bn + wc + lr;
#pragma unroll
    for (int m = 0; m < 2; ++m) {
        fx4 am0 = m ? acc10 : acc00;
        fx4 am1 = m ? acc11 : acc01;
#pragma unroll
        for (int r = 0; r < 4; ++r) {
            int row = rbase + m * 16 + r;
#pragma unroll
            for (int half = 0; half < 2; ++half) {
                int col = cbase + half * 16;
                float v = (half ? am1[r] : am0[r]) + bias[col];
                if (RESID) v += res[(size_t)row * ldc + col];
                if (RELU) v = fmaxf(v, 0.f);
                if (OUTBF) ((unsigned short*)Cv)[(size_t)row * ldc + col] = f2bf(v);
                else       ((float*)Cv)[(size_t)row * ldc + col] = v;
            }
        }
    }
}

// ---------------- bf16 MFMA GEMM, 128x128 tile (4 waves x 64x64), bf16 out ----------------
template<bool RELU>
__global__ __launch_bounds__(256) void gemm128_kernel(
    const unsigned short* __restrict__ A, const unsigned short* __restrict__ Wt,
    const float* __restrict__ bias, unsigned short* __restrict__ C,
    int K, int ldc)
{
    __shared__ unsigned short smem[2][2][8192];  // [buf][A/B][128*64]
    const int tid = threadIdx.x;
    const int nwg = gridDim.x;
    const int cpx = nwg >> 3;
    const int phys = blockIdx.x;
    const int logical = (phys & 7) * cpx + (phys >> 3);
    const int bm = (logical & 15) * 128;     // M = 2048 always
    const int bn = (logical >> 4) * 128;
    const int lane = tid & 63;
    const int wv = tid >> 6;
    const int wr = (wv >> 1) * 64;
    const int wc = (wv & 1) * 64;
    const int lr = lane & 15;
    const int lrow = lane >> 3;
    const int lchk = lane & 7;
    fx4 acc[4][4];
#pragma unroll
    for (int mi = 0; mi < 4; ++mi)
#pragma unroll
        for (int ni = 0; ni < 4; ++ni) acc[mi][ni] = fx4{0.f, 0.f, 0.f, 0.f};

    auto stage = [&](int buf, int k0) {
#pragma unroll
        for (int j = 0; j < 4; ++j) {
            int row = wv * 32 + j * 8 + lrow;
            int sc = lchk ^ (row & 7);
            gl2lds16(A + (size_t)(bm + row) * K + k0 + sc * 8,
                     &smem[buf][0][(wv * 32 + j * 8) * 64]);
            gl2lds16(Wt + (size_t)(bn + row) * K + k0 + sc * 8,
                     &smem[buf][1][(wv * 32 + j * 8) * 64]);
        }
    };

    const int nt = K >> 6;
    int cur = 0;
    stage(0, 0);
    for (int t = 0; t < nt; ++t) {
        __syncthreads();
        if (t + 1 < nt) stage(cur ^ 1, (t + 1) << 6);
        const unsigned short* bufA = &smem[cur][0][0];
        const unsigned short* bufB = &smem[cur][1][0];
        __builtin_amdgcn_s_setprio(1);
#pragma unroll
        for (int kk = 0; kk < 2; ++kk) {
            int ca = kk * 4 + (lane >> 4);
            bfx8 af[4], bg[4];
#pragma unroll
            for (int i = 0; i < 4; ++i) {
                int ra = wr + i * 16 + lr;
                int rb = wc + i * 16 + lr;
                af[i] = *(const bfx8*)&bufA[ra * 64 + ((ca ^ (ra & 7)) * 8)];
                bg[i] = *(const bfx8*)&bufB[rb * 64 + ((ca ^ (rb & 7)) * 8)];
            }
#pragma unroll
            for (int mi = 0; mi < 4; ++mi)
#pragma unroll
                for (int ni = 0; ni < 4; ++ni)
                    acc[mi][ni] = __builtin_amdgcn_mfma_f32_16x16x32_bf16(af[mi], bg[ni], acc[mi][ni], 0, 0, 0);
        }
        __builtin_amdgcn_s_setprio(0);
        cur ^= 1;
    }
    int rbase = bm + wr + ((lane >> 4) * 4);
    int cbase = bn + wc + lr;
#pragma unroll
    for (int mi = 0; mi < 4; ++mi)
#pragma unroll
        for (int ni = 0; ni < 4; ++ni) {
            int col = cbase + ni * 16;
            float bv = bias[col];
#pragma unroll
            for (int r = 0; r < 4; ++r) {
                int row = rbase + mi * 16 + r;
                float v = acc[mi][ni][r] + bv;
                if (RELU) v = fmaxf(v, 0.f);
                C[(size_t)row * ldc + col] = f2bf(v);
            }
        }
}

// ---------------- fused QKV-projection + attention (8 waves, SIMD-balanced proj) ----------------
// Proj roles: wv0: K rows 0-63, wv1: K 64-127, wv2: V 0-63, wv3: V 64-127 (16 MFMA/kk each),
// wv4-7: Q row-block (wv-4) (4 MFMA/kk each). Per-SIMD load = 16+4 = 20 MFMA/kk, balanced.
template<bool CAUSAL, bool SELF>
__global__ __launch_bounds__(512) void fattn_kernel(
    const unsigned short* __restrict__ xq, const unsigned short* __restrict__ xkv,
    const unsigned short* __restrict__ Wt, const float* __restrict__ bias,
    unsigned short* __restrict__ out)
{
    constexpr int XROWS = SELF ? 128 : 192;
    constexpr int BUFB  = (XROWS + 192) * 64 * 2;
    __shared__ __align__(16) unsigned char lds[2 * BUFB + 9216 + 18432 + 17408 + 512];
    const int blk = blockIdx.x;
    const int half = blk & 1;
    const int h = (blk >> 1) & 7;
    const int b = blk >> 4;
    const int q0 = half * 64;
    const int tid = threadIdx.x;
    const int lane = tid & 63;
    const int wv = tid >> 6;
    const int lr = lane & 15;
    const int hg8 = (lane >> 4) * 8;
    const int rloc = (lane >> 4) * 4;
    const int lrow = lane >> 3;
    const int lchk = lane & 7;

    const unsigned short* gxq = xq + (size_t)(b * 128 + q0) * 512;
    const unsigned short* gkv = xkv + (size_t)(b * 128) * 512;
    const unsigned short* gw  = Wt + (size_t)(h * 64) * 512;

    auto stage = [&](int buf, int k0) {
        unsigned short* dst = (unsigned short*)(lds + buf * BUFB);
        if constexpr (SELF) {
#pragma unroll
            for (int j = 0; j < 5; ++j) {
                int start = wv * 40 + j * 8;
                int row = start + lrow;
                int sc = (lchk ^ (row & 7)) * 8;
                const unsigned short* src;
                if (start < 128) {
                    src = gkv + (size_t)row * 512 + k0 + sc;
                } else {
                    int wr_ = row - 128;
                    src = gw + ((size_t)(wr_ & 63) + (size_t)(wr_ >> 6) * 512) * 512 + k0 + sc;
                }
                gl2lds16(src, dst + start * 64);
            }
        } else {
            unsigned short* dstW = dst + XROWS * 64;
#pragma unroll
            for (int j = 0; j < 3; ++j) {
                int row = wv * 24 + j * 8 + lrow;
                int sc = (lchk ^ (row & 7)) * 8;
                const unsigned short* xs = (row < 64)
                    ? gxq + (size_t)row * 512
                    : gkv + (size_t)(row - 64) * 512;
                gl2lds16(xs + k0 + sc, dst + (wv * 24 + j * 8) * 64);
                const unsigned short* ws = gw + ((size_t)(row & 63) + (size_t)(row >> 6) * 512) * 512;
                gl2lds16(ws + k0 + sc, dstW + (wv * 24 + j * 8) * 64);
            }
        }
    };

    fx4 acc[4][4];
#pragma unroll
    for (int i = 0; i < 4; ++i)
#pragma unroll
        for (int c = 0; c < 4; ++c) acc[i][c] = fx4{0.f, 0.f, 0.f, 0.f};

    const bool isQ = wv >= 4;
    // KV waves: 4 row-blocks at arowbase; Q waves: 1 row-block at arowbase
    const int arowbase = isQ ? ((SELF ? q0 : 0) + (wv - 4) * 16)
                             : (SELF ? 0 : 64) + ((wv & 1) * 64);
    const int wbase = isQ ? 0 : (wv < 2 ? 64 : 128);

    stage(0, 0);
#pragma unroll 1
    for (int t = 0; t < 8; ++t) {
        __syncthreads();
        if (t < 7) stage((t + 1) & 1, (t + 1) * 64);
        const unsigned short* stX = (const unsigned short*)(lds + (t & 1) * BUFB);
        const unsigned short* stW = stX + XROWS * 64;
#pragma unroll
        for (int kk = 0; kk < 2; ++kk) {
            const int ca = kk * 4 + (lane >> 4);
            auto rd = [&](const unsigned short* base, int row) -> bfx8 {
                return *(const bfx8*)(base + row * 64 + ((ca ^ (row & 7)) * 8));
            };
            if (!isQ) {
                bfx8 af[4];
#pragma unroll
                for (int i = 0; i < 4; ++i) af[i] = rd(stX, arowbase + i * 16 + lr);
                __builtin_amdgcn_s_setprio(1);
#pragma unroll
                for (int c = 0; c < 4; ++c) {
                    bfx8 bf = rd(stW, wbase + c * 16 + lr);
#pragma unroll
                    for (int i = 0; i < 4; ++i)
                        acc[i][c] = __builtin_amdgcn_mfma_f32_16x16x32_bf16(af[i], bf, acc[i][c], 0, 0, 0);
                }
                __builtin_amdgcn_s_setprio(0);
            } else {
                bfx8 aq = rd(stX, arowbase + lr);
                __builtin_amdgcn_s_setprio(1);
#pragma unroll
                for (int c = 0; c < 4; ++c) {
                    bfx8 bf = rd(stW, c * 16 + lr);
                    acc[0][c] = __builtin_amdgcn_mfma_f32_16x16x32_bf16(aq, bf, acc[0][c], 0, 0, 0);
                }
                __builtin_amdgcn_s_setprio(0);
            }
        }
    }
    unsigned short* sQ  = (unsigned short*)(lds + 2 * BUFB);
    unsigned short* sK  = (unsigned short*)(lds + 2 * BUFB + 9216);
    unsigned short* sVt = (unsigned short*)(lds + 2 * BUFB + 9216 + 18432);
    float* zp = (float*)(lds + 2 * BUFB + 9216 + 18432 + 17408);
    unsigned short* sP  = (unsigned short*)lds;
    // proj epilogue: D row = rowblock*16 + rloc + r, col = c*16 + lr
    if (isQ) {              // Q row-block (wv-4) -> sQ
        int rb = (wv - 4) * 16;
#pragma unroll
        for (int c = 0; c < 4; ++c) {
            int col = c * 16 + lr;
            float bq_ = bias[h * 64 + col];
#pragma unroll
            for (int r = 0; r < 4; ++r)
                sQ[(rb + rloc + r) * 72 + col] = f2bf(acc[0][c][r] + bq_);
        }
    } else if (wv < 2) {    // K -> sK
        int rb = wv * 64;
#pragma unroll
        for (int c = 0; c < 4; ++c) {
            int col = c * 16 + lr;
            float bk_ = bias[512 + h * 64 + col];
#pragma unroll
            for (int i = 0; i < 4; ++i)
#pragma unroll
                for (int r = 0; r < 4; ++r)
                    sK[(rb + i * 16 + rloc + r) * 72 + col] = f2bf(acc[i][c][r] + bk_);
        }
    } else {                // V -> sVt (transposed)
        int rb = (wv - 2) * 64;
#pragma unroll
        for (int c = 0; c < 4; ++c) {
            int col = c * 16 + lr;
            float bv_ = bias[1024 + h * 64 + col];
#pragma unroll
            for (int i = 0; i < 4; ++i)
#pragma unroll
                for (int r = 0; r < 4; ++r)
                    sVt[col * 136 + (rb + i * 16 + rloc + r)] = f2bf(acc[i][c][r] + bv_);
        }
    }
    __syncthreads();
    const int qb = wv >> 1;
    const int kh = wv & 1;
    fx4 sacc[4];
#pragma unroll
    for (int n = 0; n < 4; ++n) sacc[n] = fx4{0.f, 0.f, 0.f, 0.f};
#pragma unroll
    for (int kk = 0; kk < 2; ++kk) {
        bfx8 a = *(const bfx8*)(sQ + (qb * 16 + lr) * 72 + kk * 32 + hg8);
#pragma unroll
        for (int n = 0; n < 4; ++n) {
            bfx8 bb = *(const bfx8*)(sK + ((kh * 4 + n) * 16 + lr) * 72 + kk * 32 + hg8);
            sacc[n] = __builtin_amdgcn_mfma_f32_16x16x32_bf16(a, bb, sacc[n], 0, 0, 0);
        }
    }
    const int qg = q0 + qb * 16 + rloc;
#pragma unroll
    for (int r = 0; r < 4; ++r) {
        float zs = 0.f;
#pragma unroll
        for (int n = 0; n < 4; ++n) {
            float s = sacc[n][r] * 0.125f;
            s = __expf(fminf(fmaxf(s, -5.f), 5.f));
            if (CAUSAL && (kh * 64 + n * 16 + lr) > (qg + r)) s = 0.f;
            zs += s;
            sP[(qb * 16 + rloc + r) * 136 + kh * 64 + n * 16 + lr] = f2bf(s);
        }
#pragma unroll
        for (int off = 8; off; off >>= 1) zs += __shfl_xor(zs, off);
        if (lr == 0) zp[(qb * 2 + kh) * 16 + rloc + r] = zs;
    }
    __syncthreads();
    float zinv[4];
#pragma unroll
    for (int r = 0; r < 4; ++r)
        zinv[r] = 1.f / (zp[(qb * 2 + 0) * 16 + rloc + r] + zp[(qb * 2 + 1) * 16 + rloc + r]);
    const int dh = wv & 1;
    fx4 acc2[2];
    acc2[0] = fx4{0.f, 0.f, 0.f, 0.f};
    acc2[1] = fx4{0.f, 0.f, 0.f, 0.f};
#pragma unroll
    for (int kk = 0; kk < 4; ++kk) {
        bfx8 a = *(const bfx8*)(sP + (qb * 16 + lr) * 136 + kk * 32 + hg8);
#pragma unroll
        for (int dn = 0; dn < 2; ++dn) {
            bfx8 bb = *(const bfx8*)(sVt + (dh * 32 + dn * 16 + lr) * 136 + kk * 32 + hg8);
            acc2[dn] = __builtin_amdgcn_mfma_f32_16x16x32_bf16(a, bb, acc2[dn], 0, 0, 0);
        }
    }
#pragma unroll
    for (int dn = 0; dn < 2; ++dn)
#pragma unroll
        for (int r = 0; r < 4; ++r) {
            size_t row = (size_t)(b * 128 + qg + r);
            out[row * 512 + h * 64 + dh * 32 + dn * 16 + lr] = f2bf(acc2[dn][r] * zinv[r]);
        }
}

// ---------------- log_softmax: bf16 logits [2048,8192] -> f32 out ----------------
__global__ __launch_bounds__(256) void logsoftmax_bf16_kernel(
    const unsigned short* __restrict__ logits, float* __restrict__ out)
{
    __shared__ float red[4];
    int tid = threadIdx.x;
    const bfx8* lrow = (const bfx8*)(logits + (size_t)blockIdx.x * 8192);
    float* orow = out + (size_t)blockIdx.x * 8192;
    float vals[32];
    float mx = -1e30f;
#pragma unroll
    for (int i = 0; i < 4; ++i) {
        bfx8 u = lrow[i * 256 + tid];
#pragma unroll
        for (int j = 0; j < 8; ++j) {
            float f = bf2f((unsigned short)u[j]);
            vals[i * 8 + j] = f;
            mx = fmaxf(mx, f);
        }
    }
#pragma unroll
    for (int off = 32; off; off >>= 1) mx = fmaxf(mx, __shfl_xor(mx, off));
    int wid = tid >> 6;
    if ((tid & 63) == 0) red[wid] = mx;
    __syncthreads();
    mx = fmaxf(fmaxf(red[0], red[1]), fmaxf(red[2], red[3]));
    __syncthreads();
    float sum = 0.f;
#pragma unroll
    for (int i = 0; i < 32; ++i) sum += __expf(vals[i] - mx);
#pragma unroll
    for (int off = 32; off; off >>= 1) sum += __shfl_xor(sum, off);
    if ((tid & 63) == 0) red[wid] = sum;
    __syncthreads();
    sum = red[0] + red[1] + red[2] + red[3];
    float lsub = mx + logf(sum);
#pragma unroll
    for (int i = 0; i < 4; ++i) {
        fx4 o0, o1;
#pragma unroll
        for (int j = 0; j < 4; ++j) {
            o0[j] = vals[i * 8 + j] - lsub;
            o1[j] = vals[i * 8 + 4 + j] - lsub;
        }
        ((fx4*)orow)[(i * 256 + tid) * 2] = o0;
        ((fx4*)orow)[(i * 256 + tid) * 2 + 1] = o1;
    }
}

extern "C" void kernel_launch(void* const* d_in, const int* in_sizes, int n_in,
                              void* d_out, int out_size, void* d_ws, size_t ws_size,
                              hipStream_t stream) {
    (void)in_sizes; (void)n_in; (void)out_size; (void)ws_size;
    const int* src_tokens = (const int*)d_in[0];
    const int* tgt_tokens = (const int*)d_in[1];
    const float* src_emb    = (const float*)d_in[8];
    const float* tgt_emb    = (const float*)d_in[9];
    const float* enc_attn_W = (const float*)d_in[10];
    const float* enc_attn_b = (const float*)d_in[11];
    const float* enc_ln_g   = (const float*)d_in[12];
    const float* enc_ln_b   = (const float*)d_in[13];
    const float* enc_ff_W1  = (const float*)d_in[14];
    const float* enc_ff_b1  = (const float*)d_in[15];
    const float* enc_ff_W2  = (const float*)d_in[16];
    const float* enc_ff_b2  = (const float*)d_in[17];
    const float* enc_norm_g = (const float*)d_in[18];
    const float* enc_norm_b = (const float*)d_in[19];
    const float* dec_self_W = (const float*)d_in[20];
    const float* dec_self_b = (const float*)d_in[21];
    const float* dec_cross_W= (const float*)d_in[22];
    const float* dec_cross_b= (const float*)d_in[23];
    const float* dec_ln_g   = (const float*)d_in[24];
    const float* dec_ln_b   = (const float*)d_in[25];
    const float* dec_ff_W1  = (const float*)d_in[26];
    const float* dec_ff_b1  = (const float*)d_in[27];
    const float* dec_ff_W2  = (const float*)d_in[28];
    const float* dec_ff_b2  = (const float*)d_in[29];
    const float* dec_norm_g = (const float*)d_in[30];
    const float* dec_norm_b = (const float*)d_in[31];
    const float* gen_W      = (const float*)d_in[32];
    const float* gen_b      = (const float*)d_in[33];
    float* dout = (float*)d_out;

    // ---- workspace layout ----
    unsigned short* wt = (unsigned short*)d_ws;
    const size_t OFF_ENCQKV = 0;
    const size_t OFF_ENCO   = 1572864;
    const size_t OFF_ENCW1  = 2097152;
    const size_t OFF_ENCW2  = 4194304;
    const size_t OFF_DECSQKV= 6291456;
    const size_t OFF_DECSO  = 7864320;
    const size_t OFF_DECCQKV= 8388608;
    const size_t OFF_DECCO  = 9961472;
    const size_t OFF_DECW1  = 10485760;
    const size_t OFF_DECW2  = 12582912;
    const size_t OFF_GENW   = 14680064;
    const size_t WT_ELEMS   = 18874368;
    float* fb  = (float*)(wt + WT_ELEMS);
    float* xe  = fb;
    float* xd  = fb + 1048576;
    unsigned short* nxb   = (unsigned short*)(fb + 2097152);
    unsigned short* nxd0  = (unsigned short*)(fb + 3145728);
    unsigned short* ffb   = (unsigned short*)(fb + 4194304);  // [2048,2048] bf16
    unsigned short* nkvb0 = (unsigned short*)(fb + 6291456);  // [2048,512] bf16
    unsigned short* nkvb1 = (unsigned short*)(fb + 6815744);  // [2048,512] bf16
    unsigned short* attb  = (unsigned short*)(fb + 7340032);  // [2048,512] bf16
    unsigned short* genin   = (unsigned short*)fb;             // aliases xe (dead)
    unsigned short* logitsb = (unsigned short*)(fb + 1048576); // aliases xd.. (dead)

    // ---- single-launch prep: weight transpose + embeddings + first LN ----
    TrTable tt;
    {
        int z = 0, gi = 0;
        auto addg = [&](const float* s, unsigned short* d, int srs, int drs,
                        long so, long dof, int zc) {
            tt.zStart[gi] = z;
            tt.g[gi].src = s; tt.g[gi].dst = d;
            tt.g[gi].srcRowStride = srs; tt.g[gi].dstRowStride = drs;
            tt.g[gi].srcSliceOff = so; tt.g[gi].dstSliceOff = dof;
            ++gi; z += zc;
        };
        addg(enc_attn_W,              wt + OFF_ENCQKV,               512,  512,  262144,    262144, 3);
        addg(enc_attn_W + 4L*262144,  wt + OFF_ENCQKV + 3L*262144,   512,  512,  262144,    262144, 3);
        addg(enc_attn_W + 3L*262144,  wt + OFF_ENCO,                 512,  512,  4L*262144, 262144, 2);
        addg(enc_ff_W1,               wt + OFF_ENCW1,                2048, 512,  512,       262144, 4);
        addg(enc_ff_W1 + 1048576,     wt + OFF_ENCW1 + 1048576,      2048, 512,  512,       262144, 4);
        addg(enc_ff_W2,               wt + OFF_ENCW2,                512,  2048, 262144,    512,    4);
        addg(enc_ff_W2 + 1048576,     wt + OFF_ENCW2 + 1048576,      512,  2048, 262144,    512,    4);
        addg(dec_self_W,              wt + OFF_DECSQKV,              512,  512,  262144,    262144, 3);
        addg(dec_self_W + 4L*262144,  wt + OFF_DECSQKV + 3L*262144,  512,  512,  262144,    262144, 3);
        addg(dec_self_W + 3L*262144,  wt + OFF_DECSO,                512,  512,  4L*262144, 262144, 2);
        addg(dec_cross_W,             wt + OFF_DECCQKV,              512,  512,  262144,    262144, 3);
        addg(dec_cross_W + 4L*262144, wt + OFF_DECCQKV + 3L*262144,  512,  512,  262144,    262144, 3);
        addg(dec_cross_W + 3L*262144, wt + OFF_DECCO,                512,  512,  4L*262144, 262144, 2);
        addg(dec_ff_W1,               wt + OFF_DECW1,                2048, 512,  512,       262144, 4);
        addg(dec_ff_W1 + 1048576,     wt + OFF_DECW1 + 1048576,      2048, 512,  512,       262144, 4);
        addg(dec_ff_W2,               wt + OFF_DECW2,                512,  2048, 262144,    512,    4);
        addg(dec_ff_W2 + 1048576,     wt + OFF_DECW2 + 1048576,      512,  2048, 262144,    512,    4);
        addg(gen_W,                   wt + OFF_GENW,                 8192, 512,  512,       262144, 16);
        tt.zStart[18] = z;  // 72
    }
    prep_kernel<<<dim3(8, 8, 136), 256, 0, stream>>>(
        tt, src_tokens, tgt_tokens, src_emb, tgt_emb, xe, xd,
        enc_ln_g, enc_ln_b, dec_ln_g, dec_ln_b, nxb, nxd0);

    auto gemmK = [&](const unsigned short* A, const unsigned short* W, const float* bias,
                     const float* res, void* C, int N, int K, int ldc, bool relu, bool outbf) {
        int gx = N / 64;
        dim3 g(gx * 32);
        if (res)        gemm_bk128_kernel<false, true,  false><<<g, 256, 0, stream>>>(A, W, bias, res, C, K, ldc, gx);
        else if (relu)  gemm_bk128_kernel<true,  false, true ><<<g, 256, 0, stream>>>(A, W, bias, res, C, K, ldc, gx);
        else if (outbf) gemm_bk128_kernel<false, false, true ><<<g, 256, 0, stream>>>(A, W, bias, res, C, K, ldc, gx);
        else            gemm_bk128_kernel<false, false, false><<<g, 256, 0, stream>>>(A, W, bias, res, C, K, ldc, gx);
    };
    auto gemm128 = [&](const unsigned short* A, const unsigned short* W, const float* bias,
                       unsigned short* C, int N, int K, int ldc, bool relu) {
        dim3 g((N / 128) * 16);
        if (relu) gemm128_kernel<true ><<<g, 256, 0, stream>>>(A, W, bias, C, K, ldc);
        else      gemm128_kernel<false><<<g, 256, 0, stream>>>(A, W, bias, C, K, ldc);
    };
    auto lnb = [&](const float* x, const float* g, const float* b, unsigned short* o) {
        ln_kernel<true><<<512, 256, 0, stream>>>(x, g, b, o);
    };

    // ---- encoder ----
    for (int i = 0; i < 2; ++i) {
        if (i) lnb(xe, enc_ln_g + (size_t)(i * 2) * 512, enc_ln_b + (size_t)(i * 2) * 512, nxb);
        fattn_kernel<false, true><<<256, 512, 0, stream>>>(
            nxb, nxb, wt + OFF_ENCQKV + (size_t)i * 3 * 262144,
            enc_attn_b + (size_t)i * 4 * 512, attb);
        gemmK(attb, wt + OFF_ENCO + (size_t)i * 262144, enc_attn_b + (size_t)i * 4 * 512 + 1536,
              xe, xe, 512, 512, 512, false, false);
        lnb(xe, enc_ln_g + (size_t)(i * 2 + 1) * 512, enc_ln_b + (size_t)(i * 2 + 1) * 512, nxb);
        gemm128(nxb, wt + OFF_ENCW1 + (size_t)i * 1048576, enc_ff_b1 + (size_t)i * 2048,
                ffb, 2048, 512, 2048, true);
        gemmK(ffb, wt + OFF_ENCW2 + (size_t)i * 1048576, enc_ff_b2 + (size_t)i * 512,
              xe, xe, 512, 2048, 512, false, false);
    }
    // final enc norm + both decoder cross-LN(xe) precomputed
    ln3_kernel<<<512, 256, 0, stream>>>(
        xe, enc_norm_g, enc_norm_b,
        dec_ln_g + 512, dec_ln_b + 512,
        dec_ln_g + 4 * 512, dec_ln_b + 4 * 512,
        nkvb0, nkvb1);

    // ---- decoder ----
    for (int i = 0; i < 2; ++i) {
        const unsigned short* qsrc = (i == 0) ? nxd0 : nxb;
        if (i) lnb(xd, dec_ln_g + (size_t)(i * 3) * 512, dec_ln_b + (size_t)(i * 3) * 512, nxb);
        fattn_kernel<true, true><<<256, 512, 0, stream>>>(
            qsrc, qsrc, wt + OFF_DECSQKV + (size_t)i * 3 * 262144,
            dec_self_b + (size_t)i * 4 * 512, attb);
        gemmK(attb, wt + OFF_DECSO + (size_t)i * 262144, dec_self_b + (size_t)i * 4 * 512 + 1536,
              xd, xd, 512, 512, 512, false, false);
        lnb(xd, dec_ln_g + (size_t)(i * 3 + 1) * 512, dec_ln_b + (size_t)(i * 3 + 1) * 512, nxb);
        fattn_kernel<false, false><<<256, 512, 0, stream>>>(
            nxb, i ? nkvb1 : nkvb0, wt + OFF_DECCQKV + (size_t)i * 3 * 262144,
            dec_cross_b + (size_t)i * 4 * 512, attb);
        gemmK(attb, wt + OFF_DECCO + (size_t)i * 262144, dec_cross_b + (size_t)i * 4 * 512 + 1536,
              xd, xd, 512, 512, 512, false, false);
        lnb(xd, dec_ln_g + (size_t)(i * 3 + 2) * 512, dec_ln_b + (size_t)(i * 3 + 2) * 512, nxb);
        gemm128(nxb, wt + OFF_DECW1 + (size_t)i * 1048576, dec_ff_b1 + (size_t)i * 2048,
                ffb, 2048, 512, 2048, true);
        gemmK(ffb, wt + OFF_DECW2 + (size_t)i * 1048576, dec_ff_b2 + (size_t)i * 512,
              xd, xd, 512, 2048, 512, false, false);
    }
    lnb(xd, dec_norm_g, dec_norm_b, genin);

    // ---- generator + log_softmax ----
    gemm128(genin, wt + OFF_GENW, gen_b, logitsb, 8192, 512, 8192, false);
    logsoftmax_bf16_kernel<<<2048, 256, 0, stream>>>(logitsb, dout);
}